// Round 5
// baseline (349.257 us; speedup 1.0000x reference)
//
#include <hip/hip_runtime.h>

#define NGRAPH 256
#define NNODE  512
#define KNN    6
#define NCAND  12
#define NF     64
#define SBF    72                 // bf16 row stride in shorts (144 B, 16B-aligned)
#define NT     1024               // 16 waves: 32 tiles = 2/wave exactly; 4 waves/SIMD
#define NW     16                 // waves per block
// LDS layout (float indices):
#define PBF    18432              // hbf = 512*72 shorts = 73728 B at [0,PBF)
                                  // pbf = 512*72 shorts at [PBF, 36864)
#define CANDO  PBF                // cand: 512*12 ushort = 3072 floats (dead before convs)
#define SQO    (PBF + 3072)       // 512 floats (bf16 sq, then exact sq; dead before convs)
#define WTO    36864              // Wt bf16: 64*72 shorts = 2304 floats
#define LDS_FLOATS 39168
#define LDS_BYTES  (LDS_FLOATS*4) // 156672 B < 160 KiB
// pool/head scratch (pbf region, dead after last conv gather):
#define POOLP  PBF                // 16 chunks x 64 floats
#define POOLED (PBF + 1024)
#define Y1OFF  (PBF + 1088)
#define Y2OFF  (PBF + 1344)
#define Y3OFF  (PBF + 1600)
#define BIG 1e30f

typedef float v4f __attribute__((ext_vector_type(4)));
typedef short v8s __attribute__((ext_vector_type(8)));

struct Params {
  const float *x;
  const float *W1,*b1,*a1, *W2,*b2,*a2;
  const float *Wc0,*bc0, *Wc1,*bc1, *Wc2,*bc2, *Wc3,*bc3;
  const float *W3,*b3,*a3, *W4,*b4,*a4;
  const float *Wh1,*bh1, *Wh2,*bh2, *Wh3,*bh3, *Wh4,*bh4;
  float *out;
};

// fp32 -> bf16 (RNE) as raw 16-bit
__device__ __forceinline__ unsigned f2bf(float x) {
  union { float f; unsigned u; } cc; cc.f = x;
  unsigned u = cc.u;
  return (u + 0x7FFFu + ((u >> 16) & 1u)) >> 16;
}
__device__ __forceinline__ float bflo(unsigned u) {
  union { unsigned u; float f; } c; c.u = u << 16; return c.f;
}
__device__ __forceinline__ float bfhi(unsigned u) {
  union { unsigned u; float f; } c; c.u = u & 0xffff0000u; return c.f;
}

__device__ __forceinline__ v8s bfrag(const unsigned short* base, int row, int c0) {
  return *(const v8s*)(base + row*SBF + c0);
}

// pack filter-e with its index in the low 9 mantissa bits (|perturb| << bf16 noise;
// candidate SET is all that matters — exact fp32 re-rank decides final order)
__device__ __forceinline__ float packe(float e, int j) {
  return __uint_as_float((__float_as_uint(e) & 0xFFFFFE00u) | (unsigned)j);
}

// sorted-ascending insert via min/max propagation (2 inst/stage)
__device__ __forceinline__ void ins8(float (&b)[8], float v) {
  if (v < b[7]) {
#pragma unroll
    for (int p = 0; p < 8; ++p) {
      float lo = fminf(b[p], v);
      v = fmaxf(b[p], v);
      b[p] = lo;
    }
  }
}
__device__ __forceinline__ void ins12(float (&b)[NCAND], float v) {
  if (v < b[NCAND-1]) {
#pragma unroll
    for (int p = 0; p < NCAND; ++p) {
      float lo = fminf(b[p], v);
      v = fmaxf(b[p], v);
      b[p] = lo;
    }
  }
}

// unpack 16 bf16 (2x uint4) -> set / add into a16
__device__ __forceinline__ void set16(float (&a)[16], uint4 u0, uint4 u1) {
  a[0]=bflo(u0.x); a[1]=bfhi(u0.x); a[2]=bflo(u0.y); a[3]=bfhi(u0.y);
  a[4]=bflo(u0.z); a[5]=bfhi(u0.z); a[6]=bflo(u0.w); a[7]=bfhi(u0.w);
  a[8]=bflo(u1.x); a[9]=bfhi(u1.x); a[10]=bflo(u1.y); a[11]=bfhi(u1.y);
  a[12]=bflo(u1.z); a[13]=bfhi(u1.z); a[14]=bflo(u1.w); a[15]=bfhi(u1.w);
}
__device__ __forceinline__ void add16(float (&a)[16], uint4 u0, uint4 u1) {
  a[0]+=bflo(u0.x); a[1]+=bfhi(u0.x); a[2]+=bflo(u0.y); a[3]+=bfhi(u0.y);
  a[4]+=bflo(u0.z); a[5]+=bfhi(u0.z); a[6]+=bflo(u0.w); a[7]+=bfhi(u0.w);
  a[8]+=bflo(u1.x); a[9]+=bfhi(u1.x); a[10]+=bflo(u1.y); a[11]+=bfhi(u1.y);
  a[12]+=bflo(u1.z); a[13]+=bfhi(u1.z); a[14]+=bflo(u1.w); a[15]+=bfhi(u1.w);
}

// stage W^T as bf16 into Wt: Wt[col][k] = bf16(W[k*64+col]); tid<512 only
__device__ __forceinline__ void stage_wt(const float* W, unsigned short* wt, int tid) {
  const int col = tid >> 3, ks = (tid & 7) * 8;
  const float* wp = W + col;
  unsigned d[4];
#pragma unroll
  for (int i = 0; i < 4; ++i) {
    unsigned lo = f2bf(wp[(ks + 2*i    ) * NF]);
    unsigned hi = f2bf(wp[(ks + 2*i + 1) * NF]);
    d[i] = lo | (hi << 16);
  }
  *(uint4*)&wt[col*SBF + ks] = make_uint4(d[0], d[1], d[2], d[3]);
}

// Per-thread live sets structurally <~50 VGPRs (chunked gather, streamed
// refine, no runtime-indexed arrays) — zero scratch at any regalloc choice.
__global__ __launch_bounds__(NT) void fused_gnn(Params P) {
  extern __shared__ float lds[];
  unsigned short* hbf  = (unsigned short*)lds;
  unsigned short* pbf  = (unsigned short*)&lds[PBF];
  unsigned short* wt   = (unsigned short*)&lds[WTO];
  unsigned short* cand = (unsigned short*)&lds[CANDO];
  const int tid  = threadIdx.x;
  const int g    = blockIdx.x;
  const int lane = tid & 63;
  const int w    = tid >> 6;             // wave 0..15
  const int c    = lane & 15;
  const int qq   = lane >> 4;            // 0..3
  const int row2 = tid >> 1;             // row ownership for pair decomposition
  const int half = tid & 1;

  const float* xgp = P.x + (size_t)g * NNODE * NF;
  const float4* xg = (const float4*)xgp;

  // ---- stage x[g] as bf16 into hbf (8 iters/thread) ----
#pragma unroll 1
  for (int i = tid; i < NNODE*NF/4; i += NT) {
    float4 v = xg[i];
    int row = i >> 4, k4 = i & 15;
    unsigned lo = f2bf(v.x) | (f2bf(v.y) << 16);
    unsigned hi = f2bf(v.z) | (f2bf(v.w) << 16);
    *(uint2*)&hbf[row*SBF + 4*k4] = make_uint2(lo, hi);
  }
  __syncthreads();

  // ---- filter sq from bf16 values (b128 row reads) ----
  if (tid < 512) {
    const uint4* xr = (const uint4*)(hbf + tid*SBF);
    float s = 0.f;
#pragma unroll
    for (int k = 0; k < 8; ++k) {
      uint4 u = xr[k];
      float f;
      f = bflo(u.x); s = fmaf(f, f, s); f = bfhi(u.x); s = fmaf(f, f, s);
      f = bflo(u.y); s = fmaf(f, f, s); f = bfhi(u.y); s = fmaf(f, f, s);
      f = bflo(u.z); s = fmaf(f, f, s); f = bfhi(u.z); s = fmaf(f, f, s);
      f = bflo(u.w); s = fmaf(f, f, s); f = bfhi(u.w); s = fmaf(f, f, s);
    }
    lds[SQO + tid] = s;
  }
  __syncthreads();

  // ==== kNN filter: bf16 MFMA Gram (swapped operands -> no LDS transpose)
  //      + packed lane-local top-8; 2 tiles/wave, perfectly balanced ====
  // mfma(B_jrows, A_irows): lane (qq,c) reg r holds <x[i0+c], x[j0+qq*4+r]>.
  {
#pragma unroll 1
    for (int tt = w; tt < 32; tt += NW) {
      const int i0 = tt * 16;
      v8s A0 = bfrag(hbf, i0 + c, qq*8);
      v8s A1 = bfrag(hbf, i0 + c, 32 + qq*8);
      const int myrow = i0 + c;

      float d8[8];
#pragma unroll
      for (int m = 0; m < 8; ++m) d8[m] = BIG;

#pragma unroll 1
      for (int jt = 0; jt < 32; ++jt) {
        const int j0 = jt * 16;
        v8s B0 = bfrag(hbf, j0 + c, qq*8);
        v8s B1 = bfrag(hbf, j0 + c, 32 + qq*8);
        v4f acc = {0.f, 0.f, 0.f, 0.f};
        acc = __builtin_amdgcn_mfma_f32_16x16x32_bf16(B0, A0, acc, 0, 0, 0);
        acc = __builtin_amdgcn_mfma_f32_16x16x32_bf16(B1, A1, acc, 0, 0, 0);
        float4 sv = *(const float4*)&lds[SQO + j0 + qq*4];
        float e0 = fmaf(-2.f, acc[0], sv.x);
        float e1 = fmaf(-2.f, acc[1], sv.y);
        float e2 = fmaf(-2.f, acc[2], sv.z);
        float e3 = fmaf(-2.f, acc[3], sv.w);
        const int jb = j0 + qq*4;
        if (jb     == myrow) e0 = BIG;
        if (jb + 1 == myrow) e1 = BIG;
        if (jb + 2 == myrow) e2 = BIG;
        if (jb + 3 == myrow) e3 = BIG;
        ins8(d8, packe(e0, jb));
        ins8(d8, packe(e1, jb+1));
        ins8(d8, packe(e2, jb+2));
        ins8(d8, packe(e3, jb+3));
      }

      // merge the 4 qq-lanes sharing this row: 2 butterfly stages, capacity 12
      float cd[NCAND];
#pragma unroll
      for (int m = 0; m < 8; ++m) cd[m] = d8[m];
#pragma unroll
      for (int m = 8; m < NCAND; ++m) cd[m] = BIG;
      {
        float pd[8];
#pragma unroll
        for (int s = 0; s < 8; ++s) pd[s] = __shfl_xor(cd[s], 16);
#pragma unroll
        for (int s = 0; s < 8; ++s) ins12(cd, pd[s]);
      }
      {
        float pd[NCAND];
#pragma unroll
        for (int s = 0; s < NCAND; ++s) pd[s] = __shfl_xor(cd[s], 32);
#pragma unroll
        for (int s = 0; s < NCAND; ++s) ins12(cd, pd[s]);
      }
      if (lane < 16) {
#pragma unroll
        for (int s = 0; s < NCAND; ++s)
          cand[(i0 + lane)*NCAND + s] =
            (unsigned short)(__float_as_uint(cd[s]) & 0x1FFu);
      }
    }
  }
  __syncthreads();   // filter done; SQO safe to overwrite

  // ==== exact fp32 refine from GLOBAL x — streamed, no resident row array ====
  if (tid < 512) {
    const float4* xrow = (const float4*)(xgp + tid*NF);
    float s0 = 0.f;
#pragma unroll
    for (int k4 = 0; k4 < 16; ++k4) {
      float4 a = xrow[k4];
      s0 = fmaf(a.x,a.x,s0); s0 = fmaf(a.y,a.y,s0); s0 = fmaf(a.z,a.z,s0); s0 = fmaf(a.w,a.w,s0);
    }
    lds[SQO + tid] = s0;
  }
  __syncthreads();   // exact sq published

  // Both threads of a row-pair compute refine redundantly (deterministic,
  // latency-bound, L1/L2-hot) so nbrA stays in registers for the paired
  // gather below — no LDS handoff, no extra region.
  int nbrA[KNN];
  {
    const float4* xrow = (const float4*)(xgp + row2*NF);
    float nd[6]; int ni[6];
#pragma unroll
    for (int m = 0; m < 6; ++m) { nd[m] = BIG; ni[m] = 0x7fffffff; }
    int cnd[NCAND];
#pragma unroll
    for (int s = 0; s < NCAND; ++s) cnd[s] = cand[row2*NCAND + s];

#pragma unroll 1
    for (int s = 0; s < NCAND; ++s) {
      int j = cnd[s];
      const float4* xj = (const float4*)(xgp + j*NF);
      float4 aa = {0.f, 0.f, 0.f, 0.f};
#pragma unroll
      for (int k4 = 0; k4 < 16; ++k4) {
        float4 a = xrow[k4];
        float4 v = xj[k4];
        aa.x = fmaf(a.x, v.x, aa.x); aa.y = fmaf(a.y, v.y, aa.y);
        aa.z = fmaf(a.z, v.z, aa.z); aa.w = fmaf(a.w, v.w, aa.w);
      }
      float e = fmaf(-2.f, (aa.x+aa.y)+(aa.z+aa.w), lds[SQO + j]);
      if (e < nd[5] || (e == nd[5] && j < ni[5])) {
#pragma unroll
        for (int pp = 0; pp < 6; ++pp) {
          bool lt = (e < nd[pp]) || (e == nd[pp] && j < ni[pp]);
          float tb2 = nd[pp]; int ti = ni[pp];
          nd[pp] = lt ? e : tb2;  ni[pp] = lt ? j : ti;
          e      = lt ? tb2 : e;  j      = lt ? ti : j;
        }
      }
    }
#pragma unroll
    for (int m = 0; m < 6; ++m) nbrA[m] = ni[m];
  }

  // ==== layers: bf16 MFMA GEMMs over 16 waves (2 tiles/wave) ====
  // pointer select via uniform ternary chain (SGPR cselect) — NO stack arrays
#pragma unroll 1
  for (int L = 0; L < 8; ++L) {
    const bool isconv = (L >= 2 && L <= 5);
    const float* Wl = L==0?P.W1 : L==1?P.W2 : L==2?P.Wc0 : L==3?P.Wc1 :
                      L==4?P.Wc2 : L==5?P.Wc3 : L==6?P.W3 : P.W4;
    const float* bl = L==0?P.b1 : L==1?P.b2 : L==2?P.bc0 : L==3?P.bc1 :
                      L==4?P.bc2 : L==5?P.bc3 : L==6?P.b3 : P.b4;
    const float* al = L==0?P.a1 : L==1?P.a2 : L==6?P.a3 : P.a4;  // only read when !isconv

    __syncthreads();                   // prior h stable / prior Wt reads done / cand dead
    if (tid < 512) stage_wt(Wl, wt, tid);
    __syncthreads();                   // Wt ready

    v8s B0[4], B1[4];
#pragma unroll
    for (int n = 0; n < 4; ++n) {
      B0[n] = bfrag(wt, n*16 + c, qq*8);
      B1[n] = bfrag(wt, n*16 + c, 32 + qq*8);
    }
    float br[4], ar[4];
    if (!isconv) {
#pragma unroll
      for (int n = 0; n < 4; ++n) { br[n] = bl[n*16 + c]; ar[n] = al[n*16 + c]; }
    }

#pragma unroll 1
    for (int tt = w; tt < 32; tt += NW) {
      const int i0 = tt * 16;
      v8s A0 = bfrag(hbf, i0 + c, qq*8);
      v8s A1 = bfrag(hbf, i0 + c, 32 + qq*8);
#pragma unroll
      for (int n = 0; n < 4; ++n) {
        v4f acc = {0.f, 0.f, 0.f, 0.f};
        acc = __builtin_amdgcn_mfma_f32_16x16x32_bf16(A0, B0[n], acc, 0, 0, 0);
        acc = __builtin_amdgcn_mfma_f32_16x16x32_bf16(A1, B1[n], acc, 0, 0, 0);
        if (isconv) {
#pragma unroll
          for (int r = 0; r < 4; ++r)
            pbf[(i0 + qq*4 + r)*SBF + n*16 + c] = (unsigned short)f2bf(acc[r]);
        } else {
#pragma unroll
          for (int r = 0; r < 4; ++r) {
            float v = acc[r] + br[n];
            v = v >= 0.f ? v : ar[n]*v;
            hbf[(i0 + qq*4 + r)*SBF + n*16 + c] = (unsigned short)f2bf(v);
          }
        }
      }
    }

    if (isconv) {
      __syncthreads();                 // all p published; all h A-reads done
      {
        // gather: h_i + 6b + sum of 6 neighbor p-rows, 2 threads/row x
        // 2 chunks of 16 feats each (critical path halved vs 4-chunk).
        // Live set ~40 VGPRs; unroll 1 keeps chunks apart (no spills).
        const float4* bp = (const float4*)bl;
#pragma unroll 1
        for (int cc = 0; cc < 2; ++cc) {
          const int ch = half*2 + cc;
          const int co = ch*16;      // short offset of this chunk
          float a16[16];
          {
            const uint4* hr = (const uint4*)&hbf[row2*SBF + co];
            set16(a16, hr[0], hr[1]);
          }
          {
            float4 b0 = bp[ch*4+0], b1 = bp[ch*4+1], b2 = bp[ch*4+2], b3 = bp[ch*4+3];
            a16[0]  = fmaf(6.f, b0.x, a16[0]);  a16[1]  = fmaf(6.f, b0.y, a16[1]);
            a16[2]  = fmaf(6.f, b0.z, a16[2]);  a16[3]  = fmaf(6.f, b0.w, a16[3]);
            a16[4]  = fmaf(6.f, b1.x, a16[4]);  a16[5]  = fmaf(6.f, b1.y, a16[5]);
            a16[6]  = fmaf(6.f, b1.z, a16[6]);  a16[7]  = fmaf(6.f, b1.w, a16[7]);
            a16[8]  = fmaf(6.f, b2.x, a16[8]);  a16[9]  = fmaf(6.f, b2.y, a16[9]);
            a16[10] = fmaf(6.f, b2.z, a16[10]); a16[11] = fmaf(6.f, b2.w, a16[11]);
            a16[12] = fmaf(6.f, b3.x, a16[12]); a16[13] = fmaf(6.f, b3.y, a16[13]);
            a16[14] = fmaf(6.f, b3.z, a16[14]); a16[15] = fmaf(6.f, b3.w, a16[15]);
          }
#pragma unroll
          for (int mm = 0; mm < KNN; ++mm) {
            const uint4* pr = (const uint4*)&pbf[nbrA[mm]*SBF + co];
            add16(a16, pr[0], pr[1]);
          }
          uint4 o0, o1;
          o0.x = f2bf(a16[0])  | (f2bf(a16[1])  << 16);
          o0.y = f2bf(a16[2])  | (f2bf(a16[3])  << 16);
          o0.z = f2bf(a16[4])  | (f2bf(a16[5])  << 16);
          o0.w = f2bf(a16[6])  | (f2bf(a16[7])  << 16);
          o1.x = f2bf(a16[8])  | (f2bf(a16[9])  << 16);
          o1.y = f2bf(a16[10]) | (f2bf(a16[11]) << 16);
          o1.z = f2bf(a16[12]) | (f2bf(a16[13]) << 16);
          o1.w = f2bf(a16[14]) | (f2bf(a16[15]) << 16);
          uint4* hw = (uint4*)&hbf[row2*SBF + co];
          hw[0] = o0; hw[1] = o1;
        }
      }
      // own-row-half write only; next layer's A-reads guarded by loop-top barrier
    }
  }
  __syncthreads();   // h final

  // ---- global add pool: 16 chunks of 32 rows (all 1024 threads) ----
  {
    int f = tid & 63, cch = tid >> 6;      // cch 0..15
    int rstart = cch * 32;
    float s = 0.f;
#pragma unroll 1
    for (int r = 0; r < 32; ++r) {
      unsigned u = hbf[(rstart + r)*SBF + f];
      union { unsigned u; float ff; } cv; cv.u = u << 16;
      s += cv.ff;
    }
    lds[POOLP + cch*64 + f] = s;
  }
  __syncthreads();
  if (tid < 64) {
    float pool = 0.f;
#pragma unroll
    for (int cc = 0; cc < 16; ++cc) pool += lds[POOLP + cc*64 + tid];
    lds[POOLED + tid] = pool;
  }
  __syncthreads();

  // ---- head MLP (fp32) ----
  if (tid < 256) {
    float acc = P.bh1[tid];
#pragma unroll 4
    for (int k = 0; k < 64; ++k) acc = fmaf(lds[POOLED+k], P.Wh1[k*256 + tid], acc);
    lds[Y1OFF + tid] = acc >= 0.f ? acc : 0.2f*acc;
  }
  __syncthreads();
  if (tid < 256) {
    float acc = P.bh2[tid];
#pragma unroll 4
    for (int k = 0; k < 256; ++k) acc = fmaf(lds[Y1OFF+k], P.Wh2[k*256 + tid], acc);
    lds[Y2OFF + tid] = acc >= 0.f ? acc : 0.2f*acc;
  }
  __syncthreads();
  if (tid < 64) {
    float acc = P.bh3[tid];
#pragma unroll 4
    for (int k = 0; k < 256; ++k) acc = fmaf(lds[Y2OFF+k], P.Wh3[k*64 + tid], acc);
    lds[Y3OFF + tid] = acc >= 0.f ? acc : 0.2f*acc;
  }
  __syncthreads();
  if (tid == 0) {
    float acc = P.bh4[0];
#pragma unroll 4
    for (int k = 0; k < 64; ++k) acc = fmaf(lds[Y3OFF+k], P.Wh4[k], acc);
    P.out[g] = acc;
  }
}

extern "C" void kernel_launch(void* const* d_in, const int* in_sizes, int n_in,
                              void* d_out, int out_size, void* d_ws, size_t ws_size,
                              hipStream_t stream) {
  Params P;
  P.x   = (const float*)d_in[0];
  P.W1  = (const float*)d_in[1];  P.b1  = (const float*)d_in[2];  P.a1 = (const float*)d_in[3];
  P.W2  = (const float*)d_in[4];  P.b2  = (const float*)d_in[5];  P.a2 = (const float*)d_in[6];
  P.Wc0 = (const float*)d_in[7];  P.bc0 = (const float*)d_in[8];
  P.Wc1 = (const float*)d_in[9];  P.bc1 = (const float*)d_in[10];
  P.Wc2 = (const float*)d_in[11]; P.bc2 = (const float*)d_in[12];
  P.Wc3 = (const float*)d_in[13]; P.bc3 = (const float*)d_in[14];
  P.W3  = (const float*)d_in[15]; P.b3  = (const float*)d_in[16]; P.a3 = (const float*)d_in[17];
  P.W4  = (const float*)d_in[18]; P.b4  = (const float*)d_in[19]; P.a4 = (const float*)d_in[20];
  P.Wh1 = (const float*)d_in[21]; P.bh1 = (const float*)d_in[22];
  P.Wh2 = (const float*)d_in[23]; P.bh2 = (const float*)d_in[24];
  P.Wh3 = (const float*)d_in[25]; P.bh3 = (const float*)d_in[26];
  P.Wh4 = (const float*)d_in[27]; P.bh4 = (const float*)d_in[28];
  P.out = (float*)d_out;

  (void)hipFuncSetAttribute(reinterpret_cast<const void*>(fused_gnn),
                            hipFuncAttributeMaxDynamicSharedMemorySize, LDS_BYTES);

  fused_gnn<<<NGRAPH, NT, LDS_BYTES, stream>>>(P);
}

// Round 7
// 342.659 us; speedup vs baseline: 1.0193x; 1.0193x over previous
//
#include <hip/hip_runtime.h>

#define NGRAPH 256
#define NNODE  512
#define KNN    6
#define NCAND  12
#define NF     64
#define SBF    72                 // bf16 row stride in shorts (144 B, 16B-aligned)
#define NT     1024               // 16 waves: 32 tiles = 2/wave exactly; 4 waves/SIMD
#define NW     16                 // waves per block
// LDS layout (float indices):
#define PBF    18432              // hbf = 512*72 shorts = 73728 B at [0,PBF)
                                  // pbf = 512*72 shorts at [PBF, 36864)
#define CANDO  PBF                // cand: 512*12 ushort = 3072 floats (dead before convs)
#define SQO    (PBF + 3072)       // 512 floats (bf16 sq, then exact sq; dead before convs)
#define WTO    36864              // Wt bf16: 64*72 shorts = 2304 floats
#define NBRO   39168              // nbr handoff: 512*6 ushort = 3072 shorts = 1536 FLOATS
#define LDS_FLOATS 40704          // 39168 + 1536 (R6 bug: reserved 768 -> OOB LDS writes dropped)
#define LDS_BYTES  (LDS_FLOATS*4) // 162816 B <= 163840 B (160 KiB)
// pool/head scratch (pbf region, dead after last conv gather):
#define POOLP  PBF                // 16 chunks x 64 floats
#define POOLED (PBF + 1024)
#define Y1OFF  (PBF + 1088)
#define Y2OFF  (PBF + 1344)
#define Y3OFF  (PBF + 1600)
#define BIG 1e30f

typedef float v4f __attribute__((ext_vector_type(4)));
typedef short v8s __attribute__((ext_vector_type(8)));

struct Params {
  const float *x;
  const float *W1,*b1,*a1, *W2,*b2,*a2;
  const float *Wc0,*bc0, *Wc1,*bc1, *Wc2,*bc2, *Wc3,*bc3;
  const float *W3,*b3,*a3, *W4,*b4,*a4;
  const float *Wh1,*bh1, *Wh2,*bh2, *Wh3,*bh3, *Wh4,*bh4;
  float *out;
};

// fp32 -> bf16 (RNE) as raw 16-bit
__device__ __forceinline__ unsigned f2bf(float x) {
  union { float f; unsigned u; } cc; cc.f = x;
  unsigned u = cc.u;
  return (u + 0x7FFFu + ((u >> 16) & 1u)) >> 16;
}
__device__ __forceinline__ float bflo(unsigned u) {
  union { unsigned u; float f; } c; c.u = u << 16; return c.f;
}
__device__ __forceinline__ float bfhi(unsigned u) {
  union { unsigned u; float f; } c; c.u = u & 0xffff0000u; return c.f;
}

__device__ __forceinline__ v8s bfrag(const unsigned short* base, int row, int c0) {
  return *(const v8s*)(base + row*SBF + c0);
}

// pack filter-e with its index in the low 9 mantissa bits (|perturb| << bf16 noise;
// candidate SET is all that matters — exact fp32 re-rank decides final order)
__device__ __forceinline__ float packe(float e, int j) {
  return __uint_as_float((__float_as_uint(e) & 0xFFFFFE00u) | (unsigned)j);
}

// sorted-ascending insert via min/max propagation (2 inst/stage)
__device__ __forceinline__ void ins8(float (&b)[8], float v) {
  if (v < b[7]) {
#pragma unroll
    for (int p = 0; p < 8; ++p) {
      float lo = fminf(b[p], v);
      v = fmaxf(b[p], v);
      b[p] = lo;
    }
  }
}
__device__ __forceinline__ void ins12(float (&b)[NCAND], float v) {
  if (v < b[NCAND-1]) {
#pragma unroll
    for (int p = 0; p < NCAND; ++p) {
      float lo = fminf(b[p], v);
      v = fmaxf(b[p], v);
      b[p] = lo;
    }
  }
}

// unpack 16 bf16 (2x uint4) -> set / add into a16
__device__ __forceinline__ void set16(float (&a)[16], uint4 u0, uint4 u1) {
  a[0]=bflo(u0.x); a[1]=bfhi(u0.x); a[2]=bflo(u0.y); a[3]=bfhi(u0.y);
  a[4]=bflo(u0.z); a[5]=bfhi(u0.z); a[6]=bflo(u0.w); a[7]=bfhi(u0.w);
  a[8]=bflo(u1.x); a[9]=bfhi(u1.x); a[10]=bflo(u1.y); a[11]=bfhi(u1.y);
  a[12]=bflo(u1.z); a[13]=bfhi(u1.z); a[14]=bflo(u1.w); a[15]=bfhi(u1.w);
}
__device__ __forceinline__ void add16(float (&a)[16], uint4 u0, uint4 u1) {
  a[0]+=bflo(u0.x); a[1]+=bfhi(u0.x); a[2]+=bflo(u0.y); a[3]+=bfhi(u0.y);
  a[4]+=bflo(u0.z); a[5]+=bfhi(u0.z); a[6]+=bflo(u0.w); a[7]+=bfhi(u0.w);
  a[8]+=bflo(u1.x); a[9]+=bfhi(u1.x); a[10]+=bflo(u1.y); a[11]+=bfhi(u1.y);
  a[12]+=bflo(u1.z); a[13]+=bfhi(u1.z); a[14]+=bflo(u1.w); a[15]+=bfhi(u1.w);
}

// stage W^T as bf16 into Wt: Wt[col][k] = bf16(W[k*64+col]); tid<512 only
__device__ __forceinline__ void stage_wt(const float* W, unsigned short* wt, int tid) {
  const int col = tid >> 3, ks = (tid & 7) * 8;
  const float* wp = W + col;
  unsigned d[4];
#pragma unroll
  for (int i = 0; i < 4; ++i) {
    unsigned lo = f2bf(wp[(ks + 2*i    ) * NF]);
    unsigned hi = f2bf(wp[(ks + 2*i + 1) * NF]);
    d[i] = lo | (hi << 16);
  }
  *(uint4*)&wt[col*SBF + ks] = make_uint4(d[0], d[1], d[2], d[3]);
}

// Per-thread live sets structurally <~50 VGPRs (chunked gather, streamed
// refine, no runtime-indexed arrays) — zero scratch at any regalloc choice.
__global__ __launch_bounds__(NT) void fused_gnn(Params P) {
  extern __shared__ float lds[];
  unsigned short* hbf  = (unsigned short*)lds;
  unsigned short* pbf  = (unsigned short*)&lds[PBF];
  unsigned short* wt   = (unsigned short*)&lds[WTO];
  unsigned short* cand = (unsigned short*)&lds[CANDO];
  unsigned short* nbrs = (unsigned short*)&lds[NBRO];
  const int tid  = threadIdx.x;
  const int g    = blockIdx.x;
  const int lane = tid & 63;
  const int w    = tid >> 6;             // wave 0..15
  const int c    = lane & 15;
  const int qq   = lane >> 4;            // 0..3
  const int row2 = tid >> 1;             // row ownership for pair decomposition
  const int half = tid & 1;

  const float* xgp = P.x + (size_t)g * NNODE * NF;
  const float4* xg = (const float4*)xgp;

  // ---- stage x[g] as bf16 into hbf (8 iters/thread) ----
#pragma unroll 1
  for (int i = tid; i < NNODE*NF/4; i += NT) {
    float4 v = xg[i];
    int row = i >> 4, k4 = i & 15;
    unsigned lo = f2bf(v.x) | (f2bf(v.y) << 16);
    unsigned hi = f2bf(v.z) | (f2bf(v.w) << 16);
    *(uint2*)&hbf[row*SBF + 4*k4] = make_uint2(lo, hi);
  }
  __syncthreads();

  // ---- filter sq from bf16 values (b128 row reads) ----
  if (tid < 512) {
    const uint4* xr = (const uint4*)(hbf + tid*SBF);
    float s = 0.f;
#pragma unroll
    for (int k = 0; k < 8; ++k) {
      uint4 u = xr[k];
      float f;
      f = bflo(u.x); s = fmaf(f, f, s); f = bfhi(u.x); s = fmaf(f, f, s);
      f = bflo(u.y); s = fmaf(f, f, s); f = bfhi(u.y); s = fmaf(f, f, s);
      f = bflo(u.z); s = fmaf(f, f, s); f = bfhi(u.z); s = fmaf(f, f, s);
      f = bflo(u.w); s = fmaf(f, f, s); f = bfhi(u.w); s = fmaf(f, f, s);
    }
    lds[SQO + tid] = s;
  }
  __syncthreads();

  // ==== kNN filter: bf16 MFMA Gram (swapped operands -> no LDS transpose)
  //      + packed lane-local top-8; 2 tiles/wave, perfectly balanced ====
  // mfma(B_jrows, A_irows): lane (qq,c) reg r holds <x[i0+c], x[j0+qq*4+r]>.
  {
#pragma unroll 1
    for (int tt = w; tt < 32; tt += NW) {
      const int i0 = tt * 16;
      v8s A0 = bfrag(hbf, i0 + c, qq*8);
      v8s A1 = bfrag(hbf, i0 + c, 32 + qq*8);
      const int myrow = i0 + c;

      float d8[8];
#pragma unroll
      for (int m = 0; m < 8; ++m) d8[m] = BIG;

#pragma unroll 1
      for (int jt = 0; jt < 32; ++jt) {
        const int j0 = jt * 16;
        v8s B0 = bfrag(hbf, j0 + c, qq*8);
        v8s B1 = bfrag(hbf, j0 + c, 32 + qq*8);
        v4f acc = {0.f, 0.f, 0.f, 0.f};
        acc = __builtin_amdgcn_mfma_f32_16x16x32_bf16(B0, A0, acc, 0, 0, 0);
        acc = __builtin_amdgcn_mfma_f32_16x16x32_bf16(B1, A1, acc, 0, 0, 0);
        float4 sv = *(const float4*)&lds[SQO + j0 + qq*4];
        float e0 = fmaf(-2.f, acc[0], sv.x);
        float e1 = fmaf(-2.f, acc[1], sv.y);
        float e2 = fmaf(-2.f, acc[2], sv.z);
        float e3 = fmaf(-2.f, acc[3], sv.w);
        const int jb = j0 + qq*4;
        if (jb     == myrow) e0 = BIG;
        if (jb + 1 == myrow) e1 = BIG;
        if (jb + 2 == myrow) e2 = BIG;
        if (jb + 3 == myrow) e3 = BIG;
        ins8(d8, packe(e0, jb));
        ins8(d8, packe(e1, jb+1));
        ins8(d8, packe(e2, jb+2));
        ins8(d8, packe(e3, jb+3));
      }

      // merge the 4 qq-lanes sharing this row: 2 butterfly stages, capacity 12
      float cd[NCAND];
#pragma unroll
      for (int m = 0; m < 8; ++m) cd[m] = d8[m];
#pragma unroll
      for (int m = 8; m < NCAND; ++m) cd[m] = BIG;
      {
        float pd[8];
#pragma unroll
        for (int s = 0; s < 8; ++s) pd[s] = __shfl_xor(cd[s], 16);
#pragma unroll
        for (int s = 0; s < 8; ++s) ins12(cd, pd[s]);
      }
      {
        float pd[NCAND];
#pragma unroll
        for (int s = 0; s < NCAND; ++s) pd[s] = __shfl_xor(cd[s], 32);
#pragma unroll
        for (int s = 0; s < NCAND; ++s) ins12(cd, pd[s]);
      }
      if (lane < 16) {
#pragma unroll
        for (int s = 0; s < NCAND; ++s)
          cand[(i0 + lane)*NCAND + s] =
            (unsigned short)(__float_as_uint(cd[s]) & 0x1FFu);
      }
    }
  }
  __syncthreads();   // filter done; SQO safe to overwrite

  // ==== exact fp32 refine from GLOBAL x — streamed, no resident row array ====
  if (tid < 512) {
    const float4* xrow = (const float4*)(xgp + tid*NF);
    float s0 = 0.f;
#pragma unroll
    for (int k4 = 0; k4 < 16; ++k4) {
      float4 a = xrow[k4];
      s0 = fmaf(a.x,a.x,s0); s0 = fmaf(a.y,a.y,s0); s0 = fmaf(a.z,a.z,s0); s0 = fmaf(a.w,a.w,s0);
    }
    lds[SQO + tid] = s0;
  }
  __syncthreads();   // exact sq published

  // Refine on tid<512 ONLY (R5's pair-redundant version doubled the candidate
  // global stream: FETCH 18.8->65 MB, +8% dur). Handoff 6 indices via nbrs.
  if (tid < 512) {
    const float4* xrow = (const float4*)(xgp + tid*NF);   // L1/L2-hot re-reads
    float nd[6]; int ni[6];
#pragma unroll
    for (int m = 0; m < 6; ++m) { nd[m] = BIG; ni[m] = 0x7fffffff; }
    int cnd[NCAND];
#pragma unroll
    for (int s = 0; s < NCAND; ++s) cnd[s] = cand[tid*NCAND + s];

#pragma unroll 1
    for (int s = 0; s < NCAND; ++s) {
      int j = cnd[s];
      const float4* xj = (const float4*)(xgp + j*NF);
      float4 aa = {0.f, 0.f, 0.f, 0.f};
#pragma unroll
      for (int k4 = 0; k4 < 16; ++k4) {
        float4 a = xrow[k4];
        float4 v = xj[k4];
        aa.x = fmaf(a.x, v.x, aa.x); aa.y = fmaf(a.y, v.y, aa.y);
        aa.z = fmaf(a.z, v.z, aa.z); aa.w = fmaf(a.w, v.w, aa.w);
      }
      float e = fmaf(-2.f, (aa.x+aa.y)+(aa.z+aa.w), lds[SQO + j]);
      if (e < nd[5] || (e == nd[5] && j < ni[5])) {
#pragma unroll
        for (int pp = 0; pp < 6; ++pp) {
          bool lt = (e < nd[pp]) || (e == nd[pp] && j < ni[pp]);
          float tb2 = nd[pp]; int ti = ni[pp];
          nd[pp] = lt ? e : tb2;  ni[pp] = lt ? j : ti;
          e      = lt ? tb2 : e;  j      = lt ? ti : j;
        }
      }
    }
#pragma unroll
    for (int m = 0; m < 6; ++m) nbrs[tid*KNN + m] = (unsigned short)ni[m];
  }
  __syncthreads();   // nbr indices published

  int nbrA[KNN];
#pragma unroll
  for (int m = 0; m < KNN; ++m) nbrA[m] = nbrs[row2*KNN + m];

  // ==== layers: bf16 MFMA GEMMs over 16 waves (2 tiles/wave) ====
  // pointer select via uniform ternary chain (SGPR cselect) — NO stack arrays
#pragma unroll 1
  for (int L = 0; L < 8; ++L) {
    const bool isconv = (L >= 2 && L <= 5);
    const float* Wl = L==0?P.W1 : L==1?P.W2 : L==2?P.Wc0 : L==3?P.Wc1 :
                      L==4?P.Wc2 : L==5?P.Wc3 : L==6?P.W3 : P.W4;
    const float* bl = L==0?P.b1 : L==1?P.b2 : L==2?P.bc0 : L==3?P.bc1 :
                      L==4?P.bc2 : L==5?P.bc3 : L==6?P.b3 : P.b4;
    const float* al = L==0?P.a1 : L==1?P.a2 : L==6?P.a3 : P.a4;  // only read when !isconv

    __syncthreads();                   // prior h stable / prior Wt reads done / cand dead
    if (tid < 512) stage_wt(Wl, wt, tid);
    __syncthreads();                   // Wt ready

    v8s B0[4], B1[4];
#pragma unroll
    for (int n = 0; n < 4; ++n) {
      B0[n] = bfrag(wt, n*16 + c, qq*8);
      B1[n] = bfrag(wt, n*16 + c, 32 + qq*8);
    }
    float br[4], ar[4];
    if (!isconv) {
#pragma unroll
      for (int n = 0; n < 4; ++n) { br[n] = bl[n*16 + c]; ar[n] = al[n*16 + c]; }
    }

#pragma unroll 1
    for (int tt = w; tt < 32; tt += NW) {
      const int i0 = tt * 16;
      v8s A0 = bfrag(hbf, i0 + c, qq*8);
      v8s A1 = bfrag(hbf, i0 + c, 32 + qq*8);
#pragma unroll
      for (int n = 0; n < 4; ++n) {
        v4f acc = {0.f, 0.f, 0.f, 0.f};
        acc = __builtin_amdgcn_mfma_f32_16x16x32_bf16(A0, B0[n], acc, 0, 0, 0);
        acc = __builtin_amdgcn_mfma_f32_16x16x32_bf16(A1, B1[n], acc, 0, 0, 0);
        if (isconv) {
#pragma unroll
          for (int r = 0; r < 4; ++r)
            pbf[(i0 + qq*4 + r)*SBF + n*16 + c] = (unsigned short)f2bf(acc[r]);
        } else {
#pragma unroll
          for (int r = 0; r < 4; ++r) {
            float v = acc[r] + br[n];
            v = v >= 0.f ? v : ar[n]*v;
            hbf[(i0 + qq*4 + r)*SBF + n*16 + c] = (unsigned short)f2bf(v);
          }
        }
      }
    }

    if (isconv) {
      __syncthreads();                 // all p published; all h A-reads done
      {
        // gather: h_i + 6b + sum of 6 neighbor p-rows, 2 threads/row x
        // 2 chunks of 16 feats each. Live set ~40 VGPRs; no spills.
        const float4* bp = (const float4*)bl;
#pragma unroll 1
        for (int cc = 0; cc < 2; ++cc) {
          const int ch = half*2 + cc;
          const int co = ch*16;      // short offset of this chunk
          float a16[16];
          {
            const uint4* hr = (const uint4*)&hbf[row2*SBF + co];
            set16(a16, hr[0], hr[1]);
          }
          {
            float4 b0 = bp[ch*4+0], b1 = bp[ch*4+1], b2 = bp[ch*4+2], b3 = bp[ch*4+3];
            a16[0]  = fmaf(6.f, b0.x, a16[0]);  a16[1]  = fmaf(6.f, b0.y, a16[1]);
            a16[2]  = fmaf(6.f, b0.z, a16[2]);  a16[3]  = fmaf(6.f, b0.w, a16[3]);
            a16[4]  = fmaf(6.f, b1.x, a16[4]);  a16[5]  = fmaf(6.f, b1.y, a16[5]);
            a16[6]  = fmaf(6.f, b1.z, a16[6]);  a16[7]  = fmaf(6.f, b1.w, a16[7]);
            a16[8]  = fmaf(6.f, b2.x, a16[8]);  a16[9]  = fmaf(6.f, b2.y, a16[9]);
            a16[10] = fmaf(6.f, b2.z, a16[10]); a16[11] = fmaf(6.f, b2.w, a16[11]);
            a16[12] = fmaf(6.f, b3.x, a16[12]); a16[13] = fmaf(6.f, b3.y, a16[13]);
            a16[14] = fmaf(6.f, b3.z, a16[14]); a16[15] = fmaf(6.f, b3.w, a16[15]);
          }
#pragma unroll
          for (int mm = 0; mm < KNN; ++mm) {
            const uint4* pr = (const uint4*)&pbf[nbrA[mm]*SBF + co];
            add16(a16, pr[0], pr[1]);
          }
          uint4 o0, o1;
          o0.x = f2bf(a16[0])  | (f2bf(a16[1])  << 16);
          o0.y = f2bf(a16[2])  | (f2bf(a16[3])  << 16);
          o0.z = f2bf(a16[4])  | (f2bf(a16[5])  << 16);
          o0.w = f2bf(a16[6])  | (f2bf(a16[7])  << 16);
          o1.x = f2bf(a16[8])  | (f2bf(a16[9])  << 16);
          o1.y = f2bf(a16[10]) | (f2bf(a16[11]) << 16);
          o1.z = f2bf(a16[12]) | (f2bf(a16[13]) << 16);
          o1.w = f2bf(a16[14]) | (f2bf(a16[15]) << 16);
          uint4* hw = (uint4*)&hbf[row2*SBF + co];
          hw[0] = o0; hw[1] = o1;
        }
      }
      // own-row-half write only; next layer's A-reads guarded by loop-top barrier
    }
  }
  __syncthreads();   // h final

  // ---- global add pool: 16 chunks of 32 rows (all 1024 threads) ----
  {
    int f = tid & 63, cch = tid >> 6;      // cch 0..15
    int rstart = cch * 32;
    float s = 0.f;
#pragma unroll 1
    for (int r = 0; r < 32; ++r) {
      unsigned u = hbf[(rstart + r)*SBF + f];
      union { unsigned u; float ff; } cv; cv.u = u << 16;
      s += cv.ff;
    }
    lds[POOLP + cch*64 + f] = s;
  }
  __syncthreads();
  if (tid < 64) {
    float pool = 0.f;
#pragma unroll
    for (int cc = 0; cc < 16; ++cc) pool += lds[POOLP + cc*64 + tid];
    lds[POOLED + tid] = pool;
  }
  __syncthreads();

  // ---- head MLP (fp32) ----
  if (tid < 256) {
    float acc = P.bh1[tid];
#pragma unroll 4
    for (int k = 0; k < 64; ++k) acc = fmaf(lds[POOLED+k], P.Wh1[k*256 + tid], acc);
    lds[Y1OFF + tid] = acc >= 0.f ? acc : 0.2f*acc;
  }
  __syncthreads();
  if (tid < 256) {
    float acc = P.bh2[tid];
#pragma unroll 4
    for (int k = 0; k < 256; ++k) acc = fmaf(lds[Y1OFF+k], P.Wh2[k*256 + tid], acc);
    lds[Y2OFF + tid] = acc >= 0.f ? acc : 0.2f*acc;
  }
  __syncthreads();
  if (tid < 64) {
    float acc = P.bh3[tid];
#pragma unroll 4
    for (int k = 0; k < 256; ++k) acc = fmaf(lds[Y2OFF+k], P.Wh3[k*64 + tid], acc);
    lds[Y3OFF + tid] = acc >= 0.f ? acc : 0.2f*acc;
  }
  __syncthreads();
  if (tid == 0) {
    float acc = P.bh4[0];
#pragma unroll 4
    for (int k = 0; k < 64; ++k) acc = fmaf(lds[Y3OFF+k], P.Wh4[k], acc);
    P.out[g] = acc;
  }
}

extern "C" void kernel_launch(void* const* d_in, const int* in_sizes, int n_in,
                              void* d_out, int out_size, void* d_ws, size_t ws_size,
                              hipStream_t stream) {
  Params P;
  P.x   = (const float*)d_in[0];
  P.W1  = (const float*)d_in[1];  P.b1  = (const float*)d_in[2];  P.a1 = (const float*)d_in[3];
  P.W2  = (const float*)d_in[4];  P.b2  = (const float*)d_in[5];  P.a2 = (const float*)d_in[6];
  P.Wc0 = (const float*)d_in[7];  P.bc0 = (const float*)d_in[8];
  P.Wc1 = (const float*)d_in[9];  P.bc1 = (const float*)d_in[10];
  P.Wc2 = (const float*)d_in[11]; P.bc2 = (const float*)d_in[12];
  P.Wc3 = (const float*)d_in[13]; P.bc3 = (const float*)d_in[14];
  P.W3  = (const float*)d_in[15]; P.b3  = (const float*)d_in[16]; P.a3 = (const float*)d_in[17];
  P.W4  = (const float*)d_in[18]; P.b4  = (const float*)d_in[19]; P.a4 = (const float*)d_in[20];
  P.Wh1 = (const float*)d_in[21]; P.bh1 = (const float*)d_in[22];
  P.Wh2 = (const float*)d_in[23]; P.bh2 = (const float*)d_in[24];
  P.Wh3 = (const float*)d_in[25]; P.bh3 = (const float*)d_in[26];
  P.Wh4 = (const float*)d_in[27]; P.bh4 = (const float*)d_in[28];
  P.out = (float*)d_out;

  (void)hipFuncSetAttribute(reinterpret_cast<const void*>(fused_gnn),
                            hipFuncAttributeMaxDynamicSharedMemorySize, LDS_BYTES);

  fused_gnn<<<NGRAPH, NT, LDS_BYTES, stream>>>(P);
}

// Round 8
// 314.642 us; speedup vs baseline: 1.1100x; 1.0890x over previous
//
#include <hip/hip_runtime.h>

#define NGRAPH 256
#define NNODE  512
#define KNN    6
#define NCAND  12
#define NF     64
#define SBF    72                 // bf16 row stride in shorts (144 B, 16B-aligned)
#define NT     768                // 12 waves (R4-proven best; NT=1024 regressed: R7)
#define NW     12                 // waves per block
// LDS layout (float indices):
#define PBF    18432              // hbf = 512*72 shorts = 73728 B at [0,PBF)
                                  // pbf = 512*72 shorts at [PBF, 36864)
#define CANDO  PBF                // cand: 512*12 ushort = 3072 floats (dead before convs)
#define SQO    (PBF + 3072)       // 512 floats (bf16 sq, then exact sq; dead before convs)
#define WTO    36864              // Wt bf16: 64*72 shorts = 2304 floats
#define LDS_FLOATS 39168
#define LDS_BYTES  (LDS_FLOATS*4) // 156672 B < 160 KiB
// pool/head scratch (pbf region, dead after last conv gather):
#define POOLP  PBF                // 16 chunks x 64 floats = 1024; also YS scratch for Wh2 split
#define POOLED (PBF + 1024)
#define Y1OFF  (PBF + 1088)
#define Y2OFF  (PBF + 1344)
#define Y3OFF  (PBF + 1600)
#define BIG 1e30f

typedef float v4f __attribute__((ext_vector_type(4)));
typedef float v2f __attribute__((ext_vector_type(2)));
typedef short v8s __attribute__((ext_vector_type(8)));

struct Params {
  const float *x;
  const float *W1,*b1,*a1, *W2,*b2,*a2;
  const float *Wc0,*bc0, *Wc1,*bc1, *Wc2,*bc2, *Wc3,*bc3;
  const float *W3,*b3,*a3, *W4,*b4,*a4;
  const float *Wh1,*bh1, *Wh2,*bh2, *Wh3,*bh3, *Wh4,*bh4;
  float *out;
};

// fp32 -> bf16 (RNE) as raw 16-bit
__device__ __forceinline__ unsigned f2bf(float x) {
  union { float f; unsigned u; } cc; cc.f = x;
  unsigned u = cc.u;
  return (u + 0x7FFFu + ((u >> 16) & 1u)) >> 16;
}
__device__ __forceinline__ float bflo(unsigned u) {
  union { unsigned u; float f; } c; c.u = u << 16; return c.f;
}
__device__ __forceinline__ float bfhi(unsigned u) {
  union { unsigned u; float f; } c; c.u = u & 0xffff0000u; return c.f;
}
// bf16 pair -> packed float2 (enables v_pk_add_f32 accumulation)
__device__ __forceinline__ v2f up2(unsigned u) {
  v2f r; r.x = bflo(u); r.y = bfhi(u); return r;
}

__device__ __forceinline__ v8s bfrag(const unsigned short* base, int row, int c0) {
  return *(const v8s*)(base + row*SBF + c0);
}

// pack filter-e with its index in the low 9 mantissa bits (|perturb| << bf16 noise;
// candidate SET is all that matters — exact fp32 re-rank decides final order)
__device__ __forceinline__ float packe(float e, int j) {
  return __uint_as_float((__float_as_uint(e) & 0xFFFFFE00u) | (unsigned)j);
}

// sorted-ascending insert via min/max propagation (2 inst/stage)
__device__ __forceinline__ void ins8(float (&b)[8], float v) {
  if (v < b[7]) {
#pragma unroll
    for (int p = 0; p < 8; ++p) {
      float lo = fminf(b[p], v);
      v = fmaxf(b[p], v);
      b[p] = lo;
    }
  }
}
__device__ __forceinline__ void ins12(float (&b)[NCAND], float v) {
  if (v < b[NCAND-1]) {
#pragma unroll
    for (int p = 0; p < NCAND; ++p) {
      float lo = fminf(b[p], v);
      v = fmaxf(b[p], v);
      b[p] = lo;
    }
  }
}

// stage W^T as bf16 into Wt: Wt[col][k] = bf16(W[k*64+col]); tid<512 only
__device__ __forceinline__ void stage_wt(const float* W, unsigned short* wt, int tid) {
  const int col = tid >> 3, ks = (tid & 7) * 8;
  const float* wp = W + col;
  unsigned d[4];
#pragma unroll
  for (int i = 0; i < 4; ++i) {
    unsigned lo = f2bf(wp[(ks + 2*i    ) * NF]);
    unsigned hi = f2bf(wp[(ks + 2*i + 1) * NF]);
    d[i] = lo | (hi << 16);
  }
  *(uint4*)&wt[col*SBF + ks] = make_uint4(d[0], d[1], d[2], d[3]);
}

// Per-thread live sets structurally <~50 VGPRs (chunked gather, streamed
// refine, no runtime-indexed arrays) — zero scratch at any regalloc choice.
__global__ __launch_bounds__(NT) void fused_gnn(Params P) {
  extern __shared__ float lds[];
  unsigned short* hbf  = (unsigned short*)lds;
  unsigned short* pbf  = (unsigned short*)&lds[PBF];
  unsigned short* wt   = (unsigned short*)&lds[WTO];
  unsigned short* cand = (unsigned short*)&lds[CANDO];
  const int tid  = threadIdx.x;
  const int g    = blockIdx.x;
  const int rA   = tid;                  // row ownership for tid<512
  const int lane = tid & 63;
  const int w    = tid >> 6;             // wave 0..11
  const int c    = lane & 15;
  const int qq   = lane >> 4;            // 0..3

  const float* xgp = P.x + (size_t)g * NNODE * NF;
  const float4* xg = (const float4*)xgp;

  // ---- stage x[g] as bf16 into hbf ----
#pragma unroll 1
  for (int i = tid; i < NNODE*NF/4; i += NT) {
    float4 v = xg[i];
    int row = i >> 4, k4 = i & 15;
    unsigned lo = f2bf(v.x) | (f2bf(v.y) << 16);
    unsigned hi = f2bf(v.z) | (f2bf(v.w) << 16);
    *(uint2*)&hbf[row*SBF + 4*k4] = make_uint2(lo, hi);
  }
  __syncthreads();

  // ---- filter sq from bf16 values (b128 row reads) ----
  if (tid < 512) {
    const uint4* xr = (const uint4*)(hbf + rA*SBF);
    float s = 0.f;
#pragma unroll
    for (int k = 0; k < 8; ++k) {
      uint4 u = xr[k];
      float f;
      f = bflo(u.x); s = fmaf(f, f, s); f = bfhi(u.x); s = fmaf(f, f, s);
      f = bflo(u.y); s = fmaf(f, f, s); f = bfhi(u.y); s = fmaf(f, f, s);
      f = bflo(u.z); s = fmaf(f, f, s); f = bfhi(u.z); s = fmaf(f, f, s);
      f = bflo(u.w); s = fmaf(f, f, s); f = bfhi(u.w); s = fmaf(f, f, s);
    }
    lds[SQO + rA] = s;
  }
  __syncthreads();

  // ==== kNN filter: bf16 MFMA Gram (swapped operands -> no LDS transpose)
  //      + packed lane-local top-8 ====
  // mfma(B_jrows, A_irows): lane (qq,c) reg r holds <x[i0+c], x[j0+qq*4+r]>.
  {
#pragma unroll 1
    for (int tt = w; tt < 32; tt += NW) {
      const int i0 = tt * 16;
      v8s A0 = bfrag(hbf, i0 + c, qq*8);
      v8s A1 = bfrag(hbf, i0 + c, 32 + qq*8);
      const int myrow = i0 + c;

      float d8[8];
#pragma unroll
      for (int m = 0; m < 8; ++m) d8[m] = BIG;

      // unroll 2: overlap next iteration's LDS loads with this one's inserts
#pragma unroll 2
      for (int jt = 0; jt < 32; ++jt) {
        const int j0 = jt * 16;
        v8s B0 = bfrag(hbf, j0 + c, qq*8);
        v8s B1 = bfrag(hbf, j0 + c, 32 + qq*8);
        v4f acc = {0.f, 0.f, 0.f, 0.f};
        acc = __builtin_amdgcn_mfma_f32_16x16x32_bf16(B0, A0, acc, 0, 0, 0);
        acc = __builtin_amdgcn_mfma_f32_16x16x32_bf16(B1, A1, acc, 0, 0, 0);
        float4 sv = *(const float4*)&lds[SQO + j0 + qq*4];
        float e0 = fmaf(-2.f, acc[0], sv.x);
        float e1 = fmaf(-2.f, acc[1], sv.y);
        float e2 = fmaf(-2.f, acc[2], sv.z);
        float e3 = fmaf(-2.f, acc[3], sv.w);
        const int jb = j0 + qq*4;
        // self-exclusion only possible when the j-tile == i-tile (wave-uniform)
        if (jt == tt) {
          if (jb     == myrow) e0 = BIG;
          if (jb + 1 == myrow) e1 = BIG;
          if (jb + 2 == myrow) e2 = BIG;
          if (jb + 3 == myrow) e3 = BIG;
        }
        ins8(d8, packe(e0, jb));
        ins8(d8, packe(e1, jb+1));
        ins8(d8, packe(e2, jb+2));
        ins8(d8, packe(e3, jb+3));
      }

      // merge the 4 qq-lanes sharing this row: 2 butterfly stages, capacity 12
      float cd[NCAND];
#pragma unroll
      for (int m = 0; m < 8; ++m) cd[m] = d8[m];
#pragma unroll
      for (int m = 8; m < NCAND; ++m) cd[m] = BIG;
      {
        float pd[8];
#pragma unroll
        for (int s = 0; s < 8; ++s) pd[s] = __shfl_xor(cd[s], 16);
#pragma unroll
        for (int s = 0; s < 8; ++s) ins12(cd, pd[s]);
      }
      {
        float pd[NCAND];
#pragma unroll
        for (int s = 0; s < NCAND; ++s) pd[s] = __shfl_xor(cd[s], 32);
#pragma unroll
        for (int s = 0; s < NCAND; ++s) ins12(cd, pd[s]);
      }
      if (lane < 16) {
#pragma unroll
        for (int s = 0; s < NCAND; ++s)
          cand[(i0 + lane)*NCAND + s] =
            (unsigned short)(__float_as_uint(cd[s]) & 0x1FFu);
      }
    }
  }
  __syncthreads();   // filter done; SQO safe to overwrite

  // ==== exact fp32 refine from GLOBAL x — streamed, no resident row array ====
  if (tid < 512) {
    const float4* xrow = (const float4*)(xgp + rA*NF);
    float s0 = 0.f;
#pragma unroll
    for (int k4 = 0; k4 < 16; ++k4) {
      float4 a = xrow[k4];
      s0 = fmaf(a.x,a.x,s0); s0 = fmaf(a.y,a.y,s0); s0 = fmaf(a.z,a.z,s0); s0 = fmaf(a.w,a.w,s0);
    }
    lds[SQO + rA] = s0;
  }
  __syncthreads();   // exact sq published

  int nbrA[KNN];
  if (tid < 512) {
    const float4* xrow = (const float4*)(xgp + rA*NF);   // L1/L2-hot re-reads
    float nd[6]; int ni[6];
#pragma unroll
    for (int m = 0; m < 6; ++m) { nd[m] = BIG; ni[m] = 0x7fffffff; }
    int cnd[NCAND];
#pragma unroll
    for (int s = 0; s < NCAND; ++s) cnd[s] = cand[rA*NCAND + s];

#pragma unroll 1
    for (int s = 0; s < NCAND; ++s) {
      int j = cnd[s];
      const float4* xj = (const float4*)(xgp + j*NF);
      float4 aa = {0.f, 0.f, 0.f, 0.f};
#pragma unroll
      for (int k4 = 0; k4 < 16; ++k4) {
        float4 a = xrow[k4];
        float4 v = xj[k4];
        aa.x = fmaf(a.x, v.x, aa.x); aa.y = fmaf(a.y, v.y, aa.y);
        aa.z = fmaf(a.z, v.z, aa.z); aa.w = fmaf(a.w, v.w, aa.w);
      }
      float e = fmaf(-2.f, (aa.x+aa.y)+(aa.z+aa.w), lds[SQO + j]);
      if (e < nd[5] || (e == nd[5] && j < ni[5])) {
#pragma unroll
        for (int pp = 0; pp < 6; ++pp) {
          bool lt = (e < nd[pp]) || (e == nd[pp] && j < ni[pp]);
          float tb2 = nd[pp]; int ti = ni[pp];
          nd[pp] = lt ? e : tb2;  ni[pp] = lt ? j : ti;
          e      = lt ? tb2 : e;  j      = lt ? ti : j;
        }
      }
    }
#pragma unroll
    for (int m = 0; m < 6; ++m) nbrA[m] = ni[m];
  }

  // ==== layers: bf16 MFMA GEMMs over 12 waves ====
  // pointer select via uniform ternary chain (SGPR cselect) — NO stack arrays
#pragma unroll 1
  for (int L = 0; L < 8; ++L) {
    const bool isconv = (L >= 2 && L <= 5);
    const float* Wl = L==0?P.W1 : L==1?P.W2 : L==2?P.Wc0 : L==3?P.Wc1 :
                      L==4?P.Wc2 : L==5?P.Wc3 : L==6?P.W3 : P.W4;
    const float* bl = L==0?P.b1 : L==1?P.b2 : L==2?P.bc0 : L==3?P.bc1 :
                      L==4?P.bc2 : L==5?P.bc3 : L==6?P.b3 : P.b4;
    const float* al = L==0?P.a1 : L==1?P.a2 : L==6?P.a3 : P.a4;  // only read when !isconv

    __syncthreads();                   // prior h stable / prior Wt reads done / cand dead
    if (tid < 512) stage_wt(Wl, wt, tid);
    __syncthreads();                   // Wt ready

    v8s B0[4], B1[4];
#pragma unroll
    for (int n = 0; n < 4; ++n) {
      B0[n] = bfrag(wt, n*16 + c, qq*8);
      B1[n] = bfrag(wt, n*16 + c, 32 + qq*8);
    }
    float br[4], ar[4];
    if (!isconv) {
#pragma unroll
      for (int n = 0; n < 4; ++n) { br[n] = bl[n*16 + c]; ar[n] = al[n*16 + c]; }
    }

#pragma unroll 1
    for (int tt = w; tt < 32; tt += NW) {
      const int i0 = tt * 16;
      v8s A0 = bfrag(hbf, i0 + c, qq*8);
      v8s A1 = bfrag(hbf, i0 + c, 32 + qq*8);
#pragma unroll
      for (int n = 0; n < 4; ++n) {
        v4f acc = {0.f, 0.f, 0.f, 0.f};
        acc = __builtin_amdgcn_mfma_f32_16x16x32_bf16(A0, B0[n], acc, 0, 0, 0);
        acc = __builtin_amdgcn_mfma_f32_16x16x32_bf16(A1, B1[n], acc, 0, 0, 0);
        if (isconv) {
#pragma unroll
          for (int r = 0; r < 4; ++r)
            pbf[(i0 + qq*4 + r)*SBF + n*16 + c] = (unsigned short)f2bf(acc[r]);
        } else {
#pragma unroll
          for (int r = 0; r < 4; ++r) {
            float v = acc[r] + br[n];
            v = v >= 0.f ? v : ar[n]*v;
            hbf[(i0 + qq*4 + r)*SBF + n*16 + c] = (unsigned short)f2bf(v);
          }
        }
      }
    }

    if (isconv) {
      __syncthreads();                 // all p published; all h A-reads done
      if (tid < 512) {
        // gather: h_i + 6b + sum of 6 neighbor p-rows, CHUNKED 4x16 feats,
        // packed-float2 accumulate (v_pk_add_f32 halves the add stream).
        // Same per-component summation order as R4 (h, +6b, nbr0..5).
        const float4* bp = (const float4*)bl;
#pragma unroll 1
        for (int ch = 0; ch < 4; ++ch) {
          const int co = ch*16;      // short offset of this chunk
          v2f a2[8];
          {
            const uint4* hr = (const uint4*)&hbf[rA*SBF + co];
            uint4 u0 = hr[0], u1 = hr[1];
            a2[0]=up2(u0.x); a2[1]=up2(u0.y); a2[2]=up2(u0.z); a2[3]=up2(u0.w);
            a2[4]=up2(u1.x); a2[5]=up2(u1.y); a2[6]=up2(u1.z); a2[7]=up2(u1.w);
          }
          {
            float4 b0 = bp[ch*4+0], b1 = bp[ch*4+1], b2 = bp[ch*4+2], b3 = bp[ch*4+3];
            v2f t;
            t.x=b0.x; t.y=b0.y; a2[0] += 6.f*t;  t.x=b0.z; t.y=b0.w; a2[1] += 6.f*t;
            t.x=b1.x; t.y=b1.y; a2[2] += 6.f*t;  t.x=b1.z; t.y=b1.w; a2[3] += 6.f*t;
            t.x=b2.x; t.y=b2.y; a2[4] += 6.f*t;  t.x=b2.z; t.y=b2.w; a2[5] += 6.f*t;
            t.x=b3.x; t.y=b3.y; a2[6] += 6.f*t;  t.x=b3.z; t.y=b3.w; a2[7] += 6.f*t;
          }
#pragma unroll
          for (int mm = 0; mm < KNN; ++mm) {
            const uint4* pr = (const uint4*)&pbf[nbrA[mm]*SBF + co];
            uint4 p0 = pr[0], p1 = pr[1];
            a2[0]+=up2(p0.x); a2[1]+=up2(p0.y); a2[2]+=up2(p0.z); a2[3]+=up2(p0.w);
            a2[4]+=up2(p1.x); a2[5]+=up2(p1.y); a2[6]+=up2(p1.z); a2[7]+=up2(p1.w);
          }
          uint4 o0, o1;
          o0.x = f2bf(a2[0].x) | (f2bf(a2[0].y) << 16);
          o0.y = f2bf(a2[1].x) | (f2bf(a2[1].y) << 16);
          o0.z = f2bf(a2[2].x) | (f2bf(a2[2].y) << 16);
          o0.w = f2bf(a2[3].x) | (f2bf(a2[3].y) << 16);
          o1.x = f2bf(a2[4].x) | (f2bf(a2[4].y) << 16);
          o1.y = f2bf(a2[5].x) | (f2bf(a2[5].y) << 16);
          o1.z = f2bf(a2[6].x) | (f2bf(a2[6].y) << 16);
          o1.w = f2bf(a2[7].x) | (f2bf(a2[7].y) << 16);
          uint4* hw = (uint4*)&hbf[rA*SBF + co];
          hw[0] = o0; hw[1] = o1;
        }
      }
      // own-row write only; next layer's A-reads guarded by loop-top barrier
    }
  }
  __syncthreads();   // h final

  // ---- global add pool: 16 chunks of 32 rows, uint (bf16x2) reads + pk adds ----
  if (tid < 512) {
    int f2 = tid & 31, cch = tid >> 5;     // f2: uint col 0..31; cch 0..15
    int rstart = cch * 32;
    const unsigned* h32 = (const unsigned*)hbf;
    v2f s2; s2.x = 0.f; s2.y = 0.f;
#pragma unroll 1
    for (int r = 0; r < 32; ++r) s2 += up2(h32[(rstart + r)*(SBF/2) + f2]);
    *(float2*)&lds[POOLP + cch*64 + 2*f2] = make_float2(s2.x, s2.y);
  }
  __syncthreads();
  if (tid < 64) {
    float pool = 0.f;
#pragma unroll
    for (int cc = 0; cc < 16; ++cc) pool += lds[POOLP + cc*64 + tid];
    lds[POOLED + tid] = pool;
  }
  __syncthreads();

  // ---- head MLP (fp32) ----
  if (tid < 256) {
    float acc = P.bh1[tid];
#pragma unroll 4
    for (int k = 0; k < 64; ++k) acc = fmaf(lds[POOLED+k], P.Wh1[k*256 + tid], acc);
    lds[Y1OFF + tid] = acc >= 0.f ? acc : 0.2f*acc;
  }
  __syncthreads();
  // Wh2 (256x256): split-k x2 over 512 threads, partials in POOLP scratch (dead)
  if (tid < 512) {
    int o = tid & 255, hh = tid >> 8;
    float acc = hh ? 0.f : P.bh2[o];
    const int k0 = hh * 128;
#pragma unroll 4
    for (int k = k0; k < k0 + 128; ++k) acc = fmaf(lds[Y1OFF+k], P.Wh2[k*256 + o], acc);
    lds[POOLP + hh*256 + o] = acc;
  }
  __syncthreads();
  if (tid < 256) {
    float acc = lds[POOLP + tid] + lds[POOLP + 256 + tid];
    lds[Y2OFF + tid] = acc >= 0.f ? acc : 0.2f*acc;
  }
  __syncthreads();
  if (tid < 64) {
    float acc = P.bh3[tid];
#pragma unroll 4
    for (int k = 0; k < 256; ++k) acc = fmaf(lds[Y2OFF+k], P.Wh3[k*64 + tid], acc);
    lds[Y3OFF + tid] = acc >= 0.f ? acc : 0.2f*acc;
  }
  __syncthreads();
  if (tid == 0) {
    float acc = P.bh4[0];
#pragma unroll 4
    for (int k = 0; k < 64; ++k) acc = fmaf(lds[Y3OFF+k], P.Wh4[k], acc);
    P.out[g] = acc;
  }
}

extern "C" void kernel_launch(void* const* d_in, const int* in_sizes, int n_in,
                              void* d_out, int out_size, void* d_ws, size_t ws_size,
                              hipStream_t stream) {
  Params P;
  P.x   = (const float*)d_in[0];
  P.W1  = (const float*)d_in[1];  P.b1  = (const float*)d_in[2];  P.a1 = (const float*)d_in[3];
  P.W2  = (const float*)d_in[4];  P.b2  = (const float*)d_in[5];  P.a2 = (const float*)d_in[6];
  P.Wc0 = (const float*)d_in[7];  P.bc0 = (const float*)d_in[8];
  P.Wc1 = (const float*)d_in[9];  P.bc1 = (const float*)d_in[10];
  P.Wc2 = (const float*)d_in[11]; P.bc2 = (const float*)d_in[12];
  P.Wc3 = (const float*)d_in[13]; P.bc3 = (const float*)d_in[14];
  P.W3  = (const float*)d_in[15]; P.b3  = (const float*)d_in[16]; P.a3 = (const float*)d_in[17];
  P.W4  = (const float*)d_in[18]; P.b4  = (const float*)d_in[19]; P.a4 = (const float*)d_in[20];
  P.Wh1 = (const float*)d_in[21]; P.bh1 = (const float*)d_in[22];
  P.Wh2 = (const float*)d_in[23]; P.bh2 = (const float*)d_in[24];
  P.Wh3 = (const float*)d_in[25]; P.bh3 = (const float*)d_in[26];
  P.Wh4 = (const float*)d_in[27]; P.bh4 = (const float*)d_in[28];
  P.out = (float*)d_out;

  (void)hipFuncSetAttribute(reinterpret_cast<const void*>(fused_gnn),
                            hipFuncAttributeMaxDynamicSharedMemorySize, LDS_BYTES);

  fused_gnn<<<NGRAPH, NT, LDS_BYTES, stream>>>(P);
}

// Round 9
// 308.704 us; speedup vs baseline: 1.1314x; 1.0192x over previous
//
#include <hip/hip_runtime.h>

#define NGRAPH 256
#define NNODE  512
#define KNN    6
#define NCAND  12
#define NF     64
#define SBF    72                 // bf16 row stride in shorts (144 B, 16B-aligned)
#define NT     768                // 12 waves (R4/R8-proven best; NT=1024 regressed: R7)
#define NW     12                 // waves per block
// LDS layout (float indices):
#define PBF    18432              // hbf = 512*72 shorts = 73728 B at [0,PBF)
                                  // pbf = 512*72 shorts at [PBF, 36864)
#define CANDO  PBF                // cand: 512*12 ushort = 3072 floats (dead before convs)
#define SQO    (PBF + 3072)       // 512 floats (bf16 sq, then exact sq; dead before convs)
#define WTO    36864              // Wt bf16: 64*72 shorts = 2304 floats
#define NBRO   39168              // nbr lists: 512*6 ushort = 3072 shorts = 1536 FLOATS
#define LDS_FLOATS 40704          // 39168 + 1536
#define LDS_BYTES  (LDS_FLOATS*4) // 162816 B <= 163840 B (160 KiB)
// pool/head scratch (pbf region, dead after last conv gather):
#define POOLP  PBF                // 16x64 pool chunks; also Wh2/Wh3 split-k scratch
#define POOLED (PBF + 1024)
#define Y1OFF  (PBF + 1088)
#define Y2OFF  (PBF + 1344)
#define BIG 1e30f

typedef float v4f __attribute__((ext_vector_type(4)));
typedef float v2f __attribute__((ext_vector_type(2)));
typedef short v8s __attribute__((ext_vector_type(8)));

struct Params {
  const float *x;
  const float *W1,*b1,*a1, *W2,*b2,*a2;
  const float *Wc0,*bc0, *Wc1,*bc1, *Wc2,*bc2, *Wc3,*bc3;
  const float *W3,*b3,*a3, *W4,*b4,*a4;
  const float *Wh1,*bh1, *Wh2,*bh2, *Wh3,*bh3, *Wh4,*bh4;
  float *out;
};

// fp32 -> bf16 (RNE) as raw 16-bit
__device__ __forceinline__ unsigned f2bf(float x) {
  union { float f; unsigned u; } cc; cc.f = x;
  unsigned u = cc.u;
  return (u + 0x7FFFu + ((u >> 16) & 1u)) >> 16;
}
__device__ __forceinline__ float bflo(unsigned u) {
  union { unsigned u; float f; } c; c.u = u << 16; return c.f;
}
__device__ __forceinline__ float bfhi(unsigned u) {
  union { unsigned u; float f; } c; c.u = u & 0xffff0000u; return c.f;
}
// bf16 pair -> packed float2 (enables v_pk_add_f32 accumulation)
__device__ __forceinline__ v2f up2(unsigned u) {
  v2f r; r.x = bflo(u); r.y = bfhi(u); return r;
}

__device__ __forceinline__ v8s bfrag(const unsigned short* base, int row, int c0) {
  return *(const v8s*)(base + row*SBF + c0);
}

// pack filter-e with its index in the low 9 mantissa bits (|perturb| << bf16 noise;
// candidate SET is all that matters — exact fp32 re-rank decides final order)
__device__ __forceinline__ float packe(float e, int j) {
  return __uint_as_float((__float_as_uint(e) & 0xFFFFFE00u) | (unsigned)j);
}

// sorted-ascending insert via min/max propagation (2 inst/stage)
__device__ __forceinline__ void ins8(float (&b)[8], float v) {
  if (v < b[7]) {
#pragma unroll
    for (int p = 0; p < 8; ++p) {
      float lo = fminf(b[p], v);
      v = fmaxf(b[p], v);
      b[p] = lo;
    }
  }
}
__device__ __forceinline__ void ins12(float (&b)[NCAND], float v) {
  if (v < b[NCAND-1]) {
#pragma unroll
    for (int p = 0; p < NCAND; ++p) {
      float lo = fminf(b[p], v);
      v = fmaxf(b[p], v);
      b[p] = lo;
    }
  }
}

// stage W^T as bf16 into Wt: Wt[col][k] = bf16(W[k*64+col]); tid<512 only
__device__ __forceinline__ void stage_wt(const float* W, unsigned short* wt, int tid) {
  const int col = tid >> 3, ks = (tid & 7) * 8;
  const float* wp = W + col;
  unsigned d[4];
#pragma unroll
  for (int i = 0; i < 4; ++i) {
    unsigned lo = f2bf(wp[(ks + 2*i    ) * NF]);
    unsigned hi = f2bf(wp[(ks + 2*i + 1) * NF]);
    d[i] = lo | (hi << 16);
  }
  *(uint4*)&wt[col*SBF + ks] = make_uint4(d[0], d[1], d[2], d[3]);
}

// Multi-tile filter: one wave processes NTILE output tiles simultaneously.
// B-fragments and sq vector are SHARED across tiles; the NTILE independent
// insert chains interleave -> hides the serial min/max latency that starves
// the SIMD in the 1-tile version. All tile indexing compile-time (rule #20).
template<int NTILE>
__device__ __forceinline__ void filter_tiles(const unsigned short* hbf,
                                             const float* ldsf,
                                             unsigned short* cand,
                                             const int (&tts)[NTILE],
                                             int lane, int c, int qq) {
  v8s A0[NTILE], A1[NTILE];
  float d8[NTILE][8];
  int i0[NTILE];
#pragma unroll
  for (int k = 0; k < NTILE; ++k) {
    i0[k] = tts[k] * 16;
    A0[k] = bfrag(hbf, i0[k] + c, qq*8);
    A1[k] = bfrag(hbf, i0[k] + c, 32 + qq*8);
#pragma unroll
    for (int m = 0; m < 8; ++m) d8[k][m] = BIG;
  }
#pragma unroll 1
  for (int jt = 0; jt < 32; ++jt) {
    const int j0 = jt * 16;
    v8s B0 = bfrag(hbf, j0 + c, qq*8);
    v8s B1 = bfrag(hbf, j0 + c, 32 + qq*8);
    float4 sv = *(const float4*)&ldsf[SQO + j0 + qq*4];
    const int jb = j0 + qq*4;
#pragma unroll
    for (int k = 0; k < NTILE; ++k) {
      v4f acc = {0.f, 0.f, 0.f, 0.f};
      acc = __builtin_amdgcn_mfma_f32_16x16x32_bf16(B0, A0[k], acc, 0, 0, 0);
      acc = __builtin_amdgcn_mfma_f32_16x16x32_bf16(B1, A1[k], acc, 0, 0, 0);
      float e0 = fmaf(-2.f, acc[0], sv.x);
      float e1 = fmaf(-2.f, acc[1], sv.y);
      float e2 = fmaf(-2.f, acc[2], sv.z);
      float e3 = fmaf(-2.f, acc[3], sv.w);
      if (jt == tts[k]) {               // self-exclusion tile (wave-uniform)
        const int myrow = i0[k] + c;
        if (jb     == myrow) e0 = BIG;
        if (jb + 1 == myrow) e1 = BIG;
        if (jb + 2 == myrow) e2 = BIG;
        if (jb + 3 == myrow) e3 = BIG;
      }
      ins8(d8[k], packe(e0, jb));
      ins8(d8[k], packe(e1, jb+1));
      ins8(d8[k], packe(e2, jb+2));
      ins8(d8[k], packe(e3, jb+3));
    }
  }
  // merge the 4 qq-lanes per row: 2 butterfly stages, capacity 12 (per tile)
#pragma unroll
  for (int k = 0; k < NTILE; ++k) {
    float cd[NCAND];
#pragma unroll
    for (int m = 0; m < 8; ++m) cd[m] = d8[k][m];
#pragma unroll
    for (int m = 8; m < NCAND; ++m) cd[m] = BIG;
    {
      float pd[8];
#pragma unroll
      for (int s = 0; s < 8; ++s) pd[s] = __shfl_xor(cd[s], 16);
#pragma unroll
      for (int s = 0; s < 8; ++s) ins12(cd, pd[s]);
    }
    {
      float pd[NCAND];
#pragma unroll
      for (int s = 0; s < NCAND; ++s) pd[s] = __shfl_xor(cd[s], 32);
#pragma unroll
      for (int s = 0; s < NCAND; ++s) ins12(cd, pd[s]);
    }
    if (lane < 16) {
#pragma unroll
      for (int s = 0; s < NCAND; ++s)
        cand[(i0[k] + lane)*NCAND + s] =
          (unsigned short)(__float_as_uint(cd[s]) & 0x1FFu);
    }
  }
}

__global__ __launch_bounds__(NT) void fused_gnn(Params P) {
  extern __shared__ float lds[];
  unsigned short* hbf  = (unsigned short*)lds;
  unsigned short* pbf  = (unsigned short*)&lds[PBF];
  unsigned short* wt   = (unsigned short*)&lds[WTO];
  unsigned short* cand = (unsigned short*)&lds[CANDO];
  unsigned short* nbrs = (unsigned short*)&lds[NBRO];
  const int tid  = threadIdx.x;
  const int g    = blockIdx.x;
  const int rA   = tid;                  // row ownership for tid<512
  const int lane = tid & 63;
  const int w    = tid >> 6;             // wave 0..11
  const int c    = lane & 15;
  const int qq   = lane >> 4;            // 0..3

  const float* xgp = P.x + (size_t)g * NNODE * NF;
  const float4* xg = (const float4*)xgp;

  // ---- stage x[g] as bf16 into hbf ----
#pragma unroll 1
  for (int i = tid; i < NNODE*NF/4; i += NT) {
    float4 v = xg[i];
    int row = i >> 4, k4 = i & 15;
    unsigned lo = f2bf(v.x) | (f2bf(v.y) << 16);
    unsigned hi = f2bf(v.z) | (f2bf(v.w) << 16);
    *(uint2*)&hbf[row*SBF + 4*k4] = make_uint2(lo, hi);
  }
  __syncthreads();

  // ---- filter sq from bf16 values (b128 row reads) ----
  if (tid < 512) {
    const uint4* xr = (const uint4*)(hbf + rA*SBF);
    float s = 0.f;
#pragma unroll
    for (int k = 0; k < 8; ++k) {
      uint4 u = xr[k];
      float f;
      f = bflo(u.x); s = fmaf(f, f, s); f = bfhi(u.x); s = fmaf(f, f, s);
      f = bflo(u.y); s = fmaf(f, f, s); f = bfhi(u.y); s = fmaf(f, f, s);
      f = bflo(u.z); s = fmaf(f, f, s); f = bfhi(u.z); s = fmaf(f, f, s);
      f = bflo(u.w); s = fmaf(f, f, s); f = bfhi(u.w); s = fmaf(f, f, s);
    }
    lds[SQO + rA] = s;
  }
  __syncthreads();

  // ==== kNN filter: MFMA Gram, multi-tile per wave ====
  // tile cover: w<8 -> {w, w+8, w+16} (0..23); w>=8 -> {w+16, w+20} (24..31)
  if (w < 8) {
    int tts[3] = {w, w + 8, w + 16};
    filter_tiles<3>(hbf, lds, cand, tts, lane, c, qq);
  } else {
    int tts[2] = {w + 16, w + 20};
    filter_tiles<2>(hbf, lds, cand, tts, lane, c, qq);
  }
  __syncthreads();   // filter done; SQO safe to overwrite

  // ==== exact fp32 refine from GLOBAL x — streamed, no resident row array ====
  if (tid < 512) {
    const float4* xrow = (const float4*)(xgp + rA*NF);
    float s0 = 0.f;
#pragma unroll
    for (int k4 = 0; k4 < 16; ++k4) {
      float4 a = xrow[k4];
      s0 = fmaf(a.x,a.x,s0); s0 = fmaf(a.y,a.y,s0); s0 = fmaf(a.z,a.z,s0); s0 = fmaf(a.w,a.w,s0);
    }
    lds[SQO + rA] = s0;
  }
  __syncthreads();   // exact sq published

  if (tid < 512) {
    const float4* xrow = (const float4*)(xgp + rA*NF);   // L1/L2-hot re-reads
    float nd[6]; int ni[6];
#pragma unroll
    for (int m = 0; m < 6; ++m) { nd[m] = BIG; ni[m] = 0x7fffffff; }
    int cnd[NCAND];
#pragma unroll
    for (int s = 0; s < NCAND; ++s) cnd[s] = cand[rA*NCAND + s];

#pragma unroll 1
    for (int s = 0; s < NCAND; ++s) {
      int j = cnd[s];
      const float4* xj = (const float4*)(xgp + j*NF);
      float4 aa = {0.f, 0.f, 0.f, 0.f};
#pragma unroll
      for (int k4 = 0; k4 < 16; ++k4) {
        float4 a = xrow[k4];
        float4 v = xj[k4];
        aa.x = fmaf(a.x, v.x, aa.x); aa.y = fmaf(a.y, v.y, aa.y);
        aa.z = fmaf(a.z, v.z, aa.z); aa.w = fmaf(a.w, v.w, aa.w);
      }
      float e = fmaf(-2.f, (aa.x+aa.y)+(aa.z+aa.w), lds[SQO + j]);
      if (e < nd[5] || (e == nd[5] && j < ni[5])) {
#pragma unroll
        for (int pp = 0; pp < 6; ++pp) {
          bool lt = (e < nd[pp]) || (e == nd[pp] && j < ni[pp]);
          float tb2 = nd[pp]; int ti = ni[pp];
          nd[pp] = lt ? e : tb2;  ni[pp] = lt ? j : ti;
          e      = lt ? tb2 : e;  j      = lt ? ti : j;
        }
      }
    }
    // publish neighbor lists for the wave-cooperative gather (512*6 ushort)
#pragma unroll
    for (int m = 0; m < 6; ++m) nbrs[rA*KNN + m] = (unsigned short)ni[m];
  }
  // next barrier (layer-loop top) guards nbrs visibility

  // ==== layers: bf16 MFMA GEMMs over 12 waves ====
  // pointer select via uniform ternary chain (SGPR cselect) — NO stack arrays
#pragma unroll 1
  for (int L = 0; L < 8; ++L) {
    const bool isconv = (L >= 2 && L <= 5);
    const float* Wl = L==0?P.W1 : L==1?P.W2 : L==2?P.Wc0 : L==3?P.Wc1 :
                      L==4?P.Wc2 : L==5?P.Wc3 : L==6?P.W3 : P.W4;
    const float* bl = L==0?P.b1 : L==1?P.b2 : L==2?P.bc0 : L==3?P.bc1 :
                      L==4?P.bc2 : L==5?P.bc3 : L==6?P.b3 : P.b4;
    const float* al = L==0?P.a1 : L==1?P.a2 : L==6?P.a3 : P.a4;  // only read when !isconv

    __syncthreads();                   // prior h stable / prior Wt reads done / nbrs ready
    if (tid < 512) stage_wt(Wl, wt, tid);
    __syncthreads();                   // Wt ready

    v8s B0[4], B1[4];
#pragma unroll
    for (int n = 0; n < 4; ++n) {
      B0[n] = bfrag(wt, n*16 + c, qq*8);
      B1[n] = bfrag(wt, n*16 + c, 32 + qq*8);
    }
    float br[4], ar[4];
    if (!isconv) {
#pragma unroll
      for (int n = 0; n < 4; ++n) { br[n] = bl[n*16 + c]; ar[n] = al[n*16 + c]; }
    }

#pragma unroll 1
    for (int tt = w; tt < 32; tt += NW) {
      const int i0 = tt * 16;
      v8s A0 = bfrag(hbf, i0 + c, qq*8);
      v8s A1 = bfrag(hbf, i0 + c, 32 + qq*8);
#pragma unroll
      for (int n = 0; n < 4; ++n) {
        v4f acc = {0.f, 0.f, 0.f, 0.f};
        acc = __builtin_amdgcn_mfma_f32_16x16x32_bf16(A0, B0[n], acc, 0, 0, 0);
        acc = __builtin_amdgcn_mfma_f32_16x16x32_bf16(A1, B1[n], acc, 0, 0, 0);
        if (isconv) {
#pragma unroll
          for (int r = 0; r < 4; ++r)
            pbf[(i0 + qq*4 + r)*SBF + n*16 + c] = (unsigned short)f2bf(acc[r]);
        } else {
#pragma unroll
          for (int r = 0; r < 4; ++r) {
            float v = acc[r] + br[n];
            v = v >= 0.f ? v : ar[n]*v;
            hbf[(i0 + qq*4 + r)*SBF + n*16 + c] = (unsigned short)f2bf(v);
          }
        }
      }
    }

    if (isconv) {
      __syncthreads();                 // all p published; all h A-reads done
      {
        // wave-cooperative gather: 8 lanes serve one row (lane = row-grp x chunk s).
        // Each b128 nbr-read instruction covers s=0..7 for each of 8 rows ->
        // bank classes (nbr+s) mod 8 EXACTLY balanced for ANY nbr values
        // (the old row-per-thread layout was ~8-way conflicted: 26K cyc/block).
        // Per-feat accumulation order unchanged: own, +6*b, nbr0..nbr5.
        const int s = tid & 7;                 // b128 chunk (8 feats)
        const float* bls = bl + 8*s;
        float4 bv0 = *(const float4*)(bls);
        float4 bv1 = *(const float4*)(bls + 4);
#pragma unroll 1
        for (int r = tid >> 3; r < NNODE; r += NT/8) {
          const unsigned short* nb = &nbrs[r*KNN];
          uint4 own = *(const uint4*)&hbf[r*SBF + 8*s];
          v2f a0 = up2(own.x), a1 = up2(own.y), a2 = up2(own.z), a3 = up2(own.w);
          v2f t;
          t.x = bv0.x; t.y = bv0.y; a0 += 6.f*t;
          t.x = bv0.z; t.y = bv0.w; a1 += 6.f*t;
          t.x = bv1.x; t.y = bv1.y; a2 += 6.f*t;
          t.x = bv1.z; t.y = bv1.w; a3 += 6.f*t;
#pragma unroll
          for (int mm = 0; mm < KNN; ++mm) {
            int nbr = nb[mm];
            uint4 p = *(const uint4*)&pbf[nbr*SBF + 8*s];
            a0 += up2(p.x); a1 += up2(p.y); a2 += up2(p.z); a3 += up2(p.w);
          }
          uint4 o;
          o.x = f2bf(a0.x) | (f2bf(a0.y) << 16);
          o.y = f2bf(a1.x) | (f2bf(a1.y) << 16);
          o.z = f2bf(a2.x) | (f2bf(a2.y) << 16);
          o.w = f2bf(a3.x) | (f2bf(a3.y) << 16);
          *(uint4*)&hbf[r*SBF + 8*s] = o;
        }
      }
      // own-row-chunk write only; next layer's A-reads guarded by loop-top barrier
    }
  }
  __syncthreads();   // h final

  // ---- global add pool: 16 chunks of 32 rows, uint (bf16x2) reads + pk adds ----
  if (tid < 512) {
    int f2 = tid & 31, cch = tid >> 5;     // f2: uint col 0..31; cch 0..15
    int rstart = cch * 32;
    const unsigned* h32 = (const unsigned*)hbf;
    v2f s2; s2.x = 0.f; s2.y = 0.f;
#pragma unroll 1
    for (int r = 0; r < 32; ++r) s2 += up2(h32[(rstart + r)*(SBF/2) + f2]);
    *(float2*)&lds[POOLP + cch*64 + 2*f2] = make_float2(s2.x, s2.y);
  }
  __syncthreads();
  if (tid < 64) {
    float pool = 0.f;
#pragma unroll
    for (int cc = 0; cc < 16; ++cc) pool += lds[POOLP + cc*64 + tid];
    lds[POOLED + tid] = pool;
  }
  __syncthreads();

  // ---- head MLP (fp32) ----
  if (tid < 256) {
    float acc = P.bh1[tid];
#pragma unroll 4
    for (int k = 0; k < 64; ++k) acc = fmaf(lds[POOLED+k], P.Wh1[k*256 + tid], acc);
    lds[Y1OFF + tid] = acc >= 0.f ? acc : 0.2f*acc;
  }
  __syncthreads();
  // Wh2 (256x256): split-k x2 over 512 threads, partials in POOLP scratch
  if (tid < 512) {
    int o = tid & 255, hh = tid >> 8;
    float acc = hh ? 0.f : P.bh2[o];
    const int k0 = hh * 128;
#pragma unroll 4
    for (int k = k0; k < k0 + 128; ++k) acc = fmaf(lds[Y1OFF+k], P.Wh2[k*256 + o], acc);
    lds[POOLP + hh*256 + o] = acc;
  }
  __syncthreads();
  if (tid < 256) {
    float acc = lds[POOLP + tid] + lds[POOLP + 256 + tid];
    lds[Y2OFF + tid] = acc >= 0.f ? acc : 0.2f*acc;
  }
  __syncthreads();
  // Wh3 (256x64): split-k x4 over 256 threads (was 64 threads x 256 serial k)
  if (tid < 256) {
    int o = tid & 63, hh = tid >> 6;
    float acc = 0.f;
    const int k0 = hh * 64;
#pragma unroll 4
    for (int k = k0; k < k0 + 64; ++k) acc = fmaf(lds[Y2OFF+k], P.Wh3[k*64 + o], acc);
    lds[POOLP + hh*64 + o] = acc;
  }
  __syncthreads();
  // y3 + Wh4 dot: fused in wave 0 (shuffle reduce, no extra barrier)
  if (tid < 64) {
    float acc = P.bh3[tid] + lds[POOLP + tid] + lds[POOLP + 64 + tid]
              + lds[POOLP + 128 + tid] + lds[POOLP + 192 + tid];
    float y3 = acc >= 0.f ? acc : 0.2f*acc;
    float v = y3 * P.Wh4[tid];
#pragma unroll
    for (int off = 32; off >= 1; off >>= 1) v += __shfl_down(v, off);
    if (tid == 0) P.out[g] = v + P.bh4[0];
  }
}

extern "C" void kernel_launch(void* const* d_in, const int* in_sizes, int n_in,
                              void* d_out, int out_size, void* d_ws, size_t ws_size,
                              hipStream_t stream) {
  Params P;
  P.x   = (const float*)d_in[0];
  P.W1  = (const float*)d_in[1];  P.b1  = (const float*)d_in[2];  P.a1 = (const float*)d_in[3];
  P.W2  = (const float*)d_in[4];  P.b2  = (const float*)d_in[5];  P.a2 = (const float*)d_in[6];
  P.Wc0 = (const float*)d_in[7];  P.bc0 = (const float*)d_in[8];
  P.Wc1 = (const float*)d_in[9];  P.bc1 = (const float*)d_in[10];
  P.Wc2 = (const float*)d_in[11]; P.bc2 = (const float*)d_in[12];
  P.Wc3 = (const float*)d_in[13]; P.bc3 = (const float*)d_in[14];
  P.W3  = (const float*)d_in[15]; P.b3  = (const float*)d_in[16]; P.a3 = (const float*)d_in[17];
  P.W4  = (const float*)d_in[18]; P.b4  = (const float*)d_in[19]; P.a4 = (const float*)d_in[20];
  P.Wh1 = (const float*)d_in[21]; P.bh1 = (const float*)d_in[22];
  P.Wh2 = (const float*)d_in[23]; P.bh2 = (const float*)d_in[24];
  P.Wh3 = (const float*)d_in[25]; P.bh3 = (const float*)d_in[26];
  P.Wh4 = (const float*)d_in[27]; P.bh4 = (const float*)d_in[28];
  P.out = (float*)d_out;

  (void)hipFuncSetAttribute(reinterpret_cast<const void*>(fused_gnn),
                            hipFuncAttributeMaxDynamicSharedMemorySize, LDS_BYTES);

  fused_gnn<<<NGRAPH, NT, LDS_BYTES, stream>>>(P);
}

// Round 10
// 301.423 us; speedup vs baseline: 1.1587x; 1.0242x over previous
//
#include <hip/hip_runtime.h>

#define NGRAPH 256
#define NNODE  512
#define KNN    6
#define NCAND  12
#define NF     64
#define SBF    72                 // bf16 row stride in shorts (144 B, 16B-aligned)
#define NT     768                // 12 waves (R4/R8-proven best; NT=1024 regressed: R7)
#define NW     12                 // waves per block
// LDS layout (float indices):
#define PBF    18432              // hbf = 512*72 shorts = 73728 B at [0,PBF)
                                  // pbf = 512*72 shorts at [PBF, 36864)
#define CANDO  PBF                // cand: 512*12 ushort = 3072 floats (dead before convs)
#define SQO    (PBF + 3072)       // 512 floats (bf16 sq, then exact sq; dead before convs)
#define WTO    36864              // Wt bf16: 64*72 shorts = 2304 floats
#define NBRO   39168              // nbr lists: 512*6 ushort = 3072 shorts = 1536 FLOATS
#define LDS_FLOATS 40704          // 39168 + 1536
#define LDS_BYTES  (LDS_FLOATS*4) // 162816 B <= 163840 B (160 KiB)
// pool/head scratch (pbf region, dead after last conv gather):
#define POOLP  PBF                // 16x64 pool chunks; also Wh2/Wh3 split-k scratch
#define POOLED (PBF + 1024)
#define Y1OFF  (PBF + 1088)
#define Y2OFF  (PBF + 1344)
#define BIG 1e30f

typedef float v4f __attribute__((ext_vector_type(4)));
typedef float v2f __attribute__((ext_vector_type(2)));
typedef short v8s __attribute__((ext_vector_type(8)));

struct Params {
  const float *x;
  const float *W1,*b1,*a1, *W2,*b2,*a2;
  const float *Wc0,*bc0, *Wc1,*bc1, *Wc2,*bc2, *Wc3,*bc3;
  const float *W3,*b3,*a3, *W4,*b4,*a4;
  const float *Wh1,*bh1, *Wh2,*bh2, *Wh3,*bh3, *Wh4,*bh4;
  float *out;
};

// fp32 -> bf16 (RNE) as raw 16-bit
__device__ __forceinline__ unsigned f2bf(float x) {
  union { float f; unsigned u; } cc; cc.f = x;
  unsigned u = cc.u;
  return (u + 0x7FFFu + ((u >> 16) & 1u)) >> 16;
}
__device__ __forceinline__ float bflo(unsigned u) {
  union { unsigned u; float f; } c; c.u = u << 16; return c.f;
}
__device__ __forceinline__ float bfhi(unsigned u) {
  union { unsigned u; float f; } c; c.u = u & 0xffff0000u; return c.f;
}
// bf16 pair -> packed float2 (enables v_pk_add_f32 accumulation)
__device__ __forceinline__ v2f up2(unsigned u) {
  v2f r; r.x = bflo(u); r.y = bfhi(u); return r;
}

__device__ __forceinline__ v8s bfrag(const unsigned short* base, int row, int c0) {
  return *(const v8s*)(base + row*SBF + c0);
}

// pack filter-e with its index in the low 9 mantissa bits (|perturb| << bf16 noise;
// candidate SET is all that matters — exact fp32 re-rank decides final order)
__device__ __forceinline__ float packe(float e, int j) {
  return __uint_as_float((__float_as_uint(e) & 0xFFFFFE00u) | (unsigned)j);
}

// sorted-ascending insert via min/max propagation (2 inst/stage)
__device__ __forceinline__ void ins8(float (&b)[8], float v) {
  if (v < b[7]) {
#pragma unroll
    for (int p = 0; p < 8; ++p) {
      float lo = fminf(b[p], v);
      v = fmaxf(b[p], v);
      b[p] = lo;
    }
  }
}
__device__ __forceinline__ void ins12(float (&b)[NCAND], float v) {
  if (v < b[NCAND-1]) {
#pragma unroll
    for (int p = 0; p < NCAND; ++p) {
      float lo = fminf(b[p], v);
      v = fmaxf(b[p], v);
      b[p] = lo;
    }
  }
}

// T14 split Wt staging: issue the 8 strided loads EARLY (hidden under the
// previous layer's MFMA/gather), convert+write LATE at the wt-write point.
__device__ __forceinline__ void ld8(const float* W, float (&wf)[8], int tid) {
  const int col = tid >> 3, ks = (tid & 7) * 8;
  const float* wp = W + col;
#pragma unroll
  for (int i = 0; i < 8; ++i) wf[i] = wp[(ks + i) * NF];
}
__device__ __forceinline__ void wt_write(const float (&wf)[8], unsigned short* wt, int tid) {
  const int col = tid >> 3, ks = (tid & 7) * 8;
  unsigned d[4];
#pragma unroll
  for (int i = 0; i < 4; ++i)
    d[i] = f2bf(wf[2*i]) | (f2bf(wf[2*i+1]) << 16);
  *(uint4*)&wt[col*SBF + ks] = make_uint4(d[0], d[1], d[2], d[3]);
}

// Multi-tile filter: one wave processes NTILE output tiles simultaneously.
// B-fragments and sq vector are SHARED across tiles; the NTILE independent
// insert chains interleave -> hides the serial min/max latency.
template<int NTILE>
__device__ __forceinline__ void filter_tiles(const unsigned short* hbf,
                                             const float* ldsf,
                                             unsigned short* cand,
                                             const int (&tts)[NTILE],
                                             int lane, int c, int qq) {
  v8s A0[NTILE], A1[NTILE];
  float d8[NTILE][8];
  int i0[NTILE];
#pragma unroll
  for (int k = 0; k < NTILE; ++k) {
    i0[k] = tts[k] * 16;
    A0[k] = bfrag(hbf, i0[k] + c, qq*8);
    A1[k] = bfrag(hbf, i0[k] + c, 32 + qq*8);
#pragma unroll
    for (int m = 0; m < 8; ++m) d8[k][m] = BIG;
  }
#pragma unroll 1
  for (int jt = 0; jt < 32; ++jt) {
    const int j0 = jt * 16;
    v8s B0 = bfrag(hbf, j0 + c, qq*8);
    v8s B1 = bfrag(hbf, j0 + c, 32 + qq*8);
    float4 sv = *(const float4*)&ldsf[SQO + j0 + qq*4];
    const int jb = j0 + qq*4;
#pragma unroll
    for (int k = 0; k < NTILE; ++k) {
      v4f acc = {0.f, 0.f, 0.f, 0.f};
      acc = __builtin_amdgcn_mfma_f32_16x16x32_bf16(B0, A0[k], acc, 0, 0, 0);
      acc = __builtin_amdgcn_mfma_f32_16x16x32_bf16(B1, A1[k], acc, 0, 0, 0);
      float e0 = fmaf(-2.f, acc[0], sv.x);
      float e1 = fmaf(-2.f, acc[1], sv.y);
      float e2 = fmaf(-2.f, acc[2], sv.z);
      float e3 = fmaf(-2.f, acc[3], sv.w);
      if (jt == tts[k]) {               // self-exclusion tile (wave-uniform)
        const int myrow = i0[k] + c;
        if (jb     == myrow) e0 = BIG;
        if (jb + 1 == myrow) e1 = BIG;
        if (jb + 2 == myrow) e2 = BIG;
        if (jb + 3 == myrow) e3 = BIG;
      }
      ins8(d8[k], packe(e0, jb));
      ins8(d8[k], packe(e1, jb+1));
      ins8(d8[k], packe(e2, jb+2));
      ins8(d8[k], packe(e3, jb+3));
    }
  }
  // merge the 4 qq-lanes per row: 2 butterfly stages, capacity 12 (per tile)
#pragma unroll
  for (int k = 0; k < NTILE; ++k) {
    float cd[NCAND];
#pragma unroll
    for (int m = 0; m < 8; ++m) cd[m] = d8[k][m];
#pragma unroll
    for (int m = 8; m < NCAND; ++m) cd[m] = BIG;
    {
      float pd[8];
#pragma unroll
      for (int s = 0; s < 8; ++s) pd[s] = __shfl_xor(cd[s], 16);
#pragma unroll
      for (int s = 0; s < 8; ++s) ins12(cd, pd[s]);
    }
    {
      float pd[NCAND];
#pragma unroll
      for (int s = 0; s < NCAND; ++s) pd[s] = __shfl_xor(cd[s], 32);
#pragma unroll
      for (int s = 0; s < NCAND; ++s) ins12(cd, pd[s]);
    }
    if (lane < 16) {
#pragma unroll
      for (int s = 0; s < NCAND; ++s)
        cand[(i0[k] + lane)*NCAND + s] =
          (unsigned short)(__float_as_uint(cd[s]) & 0x1FFu);
    }
  }
}

__global__ __launch_bounds__(NT) void fused_gnn(Params P) {
  extern __shared__ float lds[];
  unsigned short* hbf  = (unsigned short*)lds;
  unsigned short* pbf  = (unsigned short*)&lds[PBF];
  unsigned short* wt   = (unsigned short*)&lds[WTO];
  unsigned short* cand = (unsigned short*)&lds[CANDO];
  unsigned short* nbrs = (unsigned short*)&lds[NBRO];
  const int tid  = threadIdx.x;
  const int g    = blockIdx.x;
  const int rA   = tid;                  // row ownership for tid<512
  const int lane = tid & 63;
  const int w    = tid >> 6;             // wave 0..11
  const int c    = lane & 15;
  const int qq   = lane >> 4;            // 0..3

  const float* xgp = P.x + (size_t)g * NNODE * NF;
  const float4* xg = (const float4*)xgp;

  // ---- stage x[g] as bf16 into hbf ----
#pragma unroll 1
  for (int i = tid; i < NNODE*NF/4; i += NT) {
    float4 v = xg[i];
    int row = i >> 4, k4 = i & 15;
    unsigned lo = f2bf(v.x) | (f2bf(v.y) << 16);
    unsigned hi = f2bf(v.z) | (f2bf(v.w) << 16);
    *(uint2*)&hbf[row*SBF + 4*k4] = make_uint2(lo, hi);
  }
  __syncthreads();

  // ---- filter sq from bf16 values (b128 row reads) ----
  if (tid < 512) {
    const uint4* xr = (const uint4*)(hbf + rA*SBF);
    float s = 0.f;
#pragma unroll
    for (int k = 0; k < 8; ++k) {
      uint4 u = xr[k];
      float f;
      f = bflo(u.x); s = fmaf(f, f, s); f = bfhi(u.x); s = fmaf(f, f, s);
      f = bflo(u.y); s = fmaf(f, f, s); f = bfhi(u.y); s = fmaf(f, f, s);
      f = bflo(u.z); s = fmaf(f, f, s); f = bfhi(u.z); s = fmaf(f, f, s);
      f = bflo(u.w); s = fmaf(f, f, s); f = bfhi(u.w); s = fmaf(f, f, s);
    }
    lds[SQO + rA] = s;
  }
  __syncthreads();

  // ==== kNN filter: MFMA Gram, multi-tile per wave ====
  // tile cover: w<8 -> {w, w+8, w+16} (0..23); w>=8 -> {w+16, w+20} (24..31)
  if (w < 8) {
    int tts[3] = {w, w + 8, w + 16};
    filter_tiles<3>(hbf, lds, cand, tts, lane, c, qq);
  } else {
    int tts[2] = {w + 16, w + 20};
    filter_tiles<2>(hbf, lds, cand, tts, lane, c, qq);
  }
  __syncthreads();   // filter done; SQO safe to overwrite

  // ==== exact fp32 refine: own row resident in registers (R4-proven) ====
  float4 xr16[16];
  if (tid < 512) {
    const float4* xrow = (const float4*)(xgp + rA*NF);
#pragma unroll
    for (int k4 = 0; k4 < 16; ++k4) xr16[k4] = xrow[k4];
    float s0 = 0.f;
#pragma unroll
    for (int k4 = 0; k4 < 16; ++k4) {
      float4 a = xr16[k4];
      s0 = fmaf(a.x,a.x,s0); s0 = fmaf(a.y,a.y,s0); s0 = fmaf(a.z,a.z,s0); s0 = fmaf(a.w,a.w,s0);
    }
    lds[SQO + rA] = s0;
  }
  __syncthreads();   // exact sq published

  if (tid < 512) {
    float nd[6]; int ni[6];
#pragma unroll
    for (int m = 0; m < 6; ++m) { nd[m] = BIG; ni[m] = 0x7fffffff; }
    int cnd[NCAND];
#pragma unroll
    for (int s = 0; s < NCAND; ++s) cnd[s] = cand[rA*NCAND + s];

#pragma unroll 1
    for (int s = 0; s < NCAND; ++s) {
      int j = cnd[s];
      const float4* xj = (const float4*)(xgp + j*NF);
      float4 aa = {0.f, 0.f, 0.f, 0.f};
#pragma unroll
      for (int k4 = 0; k4 < 16; ++k4) {
        float4 v = xj[k4];
        aa.x = fmaf(xr16[k4].x, v.x, aa.x); aa.y = fmaf(xr16[k4].y, v.y, aa.y);
        aa.z = fmaf(xr16[k4].z, v.z, aa.z); aa.w = fmaf(xr16[k4].w, v.w, aa.w);
      }
      float e = fmaf(-2.f, (aa.x+aa.y)+(aa.z+aa.w), lds[SQO + j]);
      if (e < nd[5] || (e == nd[5] && j < ni[5])) {
#pragma unroll
        for (int pp = 0; pp < 6; ++pp) {
          bool lt = (e < nd[pp]) || (e == nd[pp] && j < ni[pp]);
          float tb2 = nd[pp]; int ti = ni[pp];
          nd[pp] = lt ? e : tb2;  ni[pp] = lt ? j : ti;
          e      = lt ? tb2 : e;  j      = lt ? ti : j;
        }
      }
    }
    // publish neighbor lists for the wave-cooperative gather (512*6 ushort)
#pragma unroll
    for (int m = 0; m < 6; ++m) nbrs[rA*KNN + m] = (unsigned short)ni[m];
  }

  // ==== layers: bf16 MFMA GEMMs, 2 barriers/layer, pipelined Wt staging ====
  float wf[8];
  if (tid < 512) ld8(P.W1, wf, tid);     // loads for L0 (xr16 dead; wf live)
  __syncthreads();                        // S0: nbrs published
  if (tid < 512) { wt_write(wf, wt, tid); ld8(P.W2, wf, tid); }  // wt<-W1; load L1
  __syncthreads();                        // S1: wt(L0) ready

#pragma unroll 1
  for (int L = 0; L < 8; ++L) {
    const bool isconv = (L >= 2 && L <= 5);
    const float* bl = L==0?P.b1 : L==1?P.b2 : L==2?P.bc0 : L==3?P.bc1 :
                      L==4?P.bc2 : L==5?P.bc3 : L==6?P.b3 : P.b4;
    const float* al = L==0?P.a1 : L==1?P.a2 : L==6?P.a3 : P.a4;  // read only if !isconv

    // B fragments + bias from current wt (written before the last barrier)
    v8s B0[4], B1[4];
#pragma unroll
    for (int n = 0; n < 4; ++n) {
      B0[n] = bfrag(wt, n*16 + c, qq*8);
      B1[n] = bfrag(wt, n*16 + c, 32 + qq*8);
    }
    float br[4], ar[4];
    if (!isconv) {
#pragma unroll
      for (int n = 0; n < 4; ++n) { br[n] = bl[n*16 + c]; ar[n] = al[n*16 + c]; }
    }
    __syncthreads();                     // B(L): all frags secured; wt reusable

    if (tid < 512 && L < 7) {
      wt_write(wf, wt, tid);             // wt <- W(L+1) (regs loaded during L-1)
      if (L < 6) {
        const float* Wn2 = L==0?P.Wc0 : L==1?P.Wc1 : L==2?P.Wc2 :
                           L==3?P.Wc3 : L==4?P.W3 : P.W4;   // W(L+2)
        ld8(Wn2, wf, tid);               // latency hides under this layer's MFMA
      }
    }

#pragma unroll 1
    for (int tt = w; tt < 32; tt += NW) {
      const int i0 = tt * 16;
      v8s A0 = bfrag(hbf, i0 + c, qq*8);
      v8s A1 = bfrag(hbf, i0 + c, 32 + qq*8);
#pragma unroll
      for (int n = 0; n < 4; ++n) {
        v4f acc = {0.f, 0.f, 0.f, 0.f};
        acc = __builtin_amdgcn_mfma_f32_16x16x32_bf16(A0, B0[n], acc, 0, 0, 0);
        acc = __builtin_amdgcn_mfma_f32_16x16x32_bf16(A1, B1[n], acc, 0, 0, 0);
        if (isconv) {
#pragma unroll
          for (int r = 0; r < 4; ++r)
            pbf[(i0 + qq*4 + r)*SBF + n*16 + c] = (unsigned short)f2bf(acc[r]);
        } else {
#pragma unroll
          for (int r = 0; r < 4; ++r) {
            float v = acc[r] + br[n];
            v = v >= 0.f ? v : ar[n]*v;
            hbf[(i0 + qq*4 + r)*SBF + n*16 + c] = (unsigned short)f2bf(v);
          }
        }
      }
    }
    __syncthreads();                     // C(L): p/h stable + wt(L+1) ready

    if (isconv) {
      // wave-cooperative gather: 8 lanes serve one row; bank classes
      // (nbr+s) mod 8 exactly balanced for any nbr values.
      // Per-feat accumulation order: own, +6*b, nbr0..nbr5.
      const int s = tid & 7;                 // b128 chunk (8 feats)
      const float* bls = bl + 8*s;
      float4 bv0 = *(const float4*)(bls);
      float4 bv1 = *(const float4*)(bls + 4);
#pragma unroll 1
      for (int r = tid >> 3; r < NNODE; r += NT/8) {
        const unsigned short* nb = &nbrs[r*KNN];
        uint4 own = *(const uint4*)&hbf[r*SBF + 8*s];
        v2f a0 = up2(own.x), a1 = up2(own.y), a2 = up2(own.z), a3 = up2(own.w);
        v2f t;
        t.x = bv0.x; t.y = bv0.y; a0 += 6.f*t;
        t.x = bv0.z; t.y = bv0.w; a1 += 6.f*t;
        t.x = bv1.x; t.y = bv1.y; a2 += 6.f*t;
        t.x = bv1.z; t.y = bv1.w; a3 += 6.f*t;
#pragma unroll
        for (int mm = 0; mm < KNN; ++mm) {
          int nbr = nb[mm];
          uint4 p = *(const uint4*)&pbf[nbr*SBF + 8*s];
          a0 += up2(p.x); a1 += up2(p.y); a2 += up2(p.z); a3 += up2(p.w);
        }
        uint4 o;
        o.x = f2bf(a0.x) | (f2bf(a0.y) << 16);
        o.y = f2bf(a1.x) | (f2bf(a1.y) << 16);
        o.z = f2bf(a2.x) | (f2bf(a2.y) << 16);
        o.w = f2bf(a3.x) | (f2bf(a3.y) << 16);
        *(uint4*)&hbf[r*SBF + 8*s] = o;
      }
      // writes guarded by next layer's B(L+1) barrier before any hbf read
    }
  }
  __syncthreads();   // h final (gather of L5 + dense L6/L7 writes)

  // ---- global add pool: 16 chunks of 32 rows, uint (bf16x2) reads + pk adds ----
  if (tid < 512) {
    int f2 = tid & 31, cch = tid >> 5;     // f2: uint col 0..31; cch 0..15
    int rstart = cch * 32;
    const unsigned* h32 = (const unsigned*)hbf;
    v2f s2; s2.x = 0.f; s2.y = 0.f;
#pragma unroll 1
    for (int r = 0; r < 32; ++r) s2 += up2(h32[(rstart + r)*(SBF/2) + f2]);
    *(float2*)&lds[POOLP + cch*64 + 2*f2] = make_float2(s2.x, s2.y);
  }
  __syncthreads();
  if (tid < 64) {
    float pool = 0.f;
#pragma unroll
    for (int cc = 0; cc < 16; ++cc) pool += lds[POOLP + cc*64 + tid];
    lds[POOLED + tid] = pool;
  }
  __syncthreads();

  // ---- head MLP (fp32) ----
  if (tid < 256) {
    float acc = P.bh1[tid];
#pragma unroll 4
    for (int k = 0; k < 64; ++k) acc = fmaf(lds[POOLED+k], P.Wh1[k*256 + tid], acc);
    lds[Y1OFF + tid] = acc >= 0.f ? acc : 0.2f*acc;
  }
  __syncthreads();
  // Wh2 (256x256): split-k x2 over 512 threads, partials in POOLP scratch
  if (tid < 512) {
    int o = tid & 255, hh = tid >> 8;
    float acc = hh ? 0.f : P.bh2[o];
    const int k0 = hh * 128;
#pragma unroll 4
    for (int k = k0; k < k0 + 128; ++k) acc = fmaf(lds[Y1OFF+k], P.Wh2[k*256 + o], acc);
    lds[POOLP + hh*256 + o] = acc;
  }
  __syncthreads();
  if (tid < 256) {
    float acc = lds[POOLP + tid] + lds[POOLP + 256 + tid];
    lds[Y2OFF + tid] = acc >= 0.f ? acc : 0.2f*acc;
  }
  __syncthreads();
  // Wh3 (256x64): split-k x4 over 256 threads
  if (tid < 256) {
    int o = tid & 63, hh = tid >> 6;
    float acc = 0.f;
    const int k0 = hh * 64;
#pragma unroll 4
    for (int k = k0; k < k0 + 64; ++k) acc = fmaf(lds[Y2OFF+k], P.Wh3[k*64 + o], acc);
    lds[POOLP + hh*64 + o] = acc;
  }
  __syncthreads();
  // y3 + Wh4 dot: fused in wave 0 (shuffle reduce, no extra barrier)
  if (tid < 64) {
    float acc = P.bh3[tid] + lds[POOLP + tid] + lds[POOLP + 64 + tid]
              + lds[POOLP + 128 + tid] + lds[POOLP + 192 + tid];
    float y3 = acc >= 0.f ? acc : 0.2f*acc;
    float v = y3 * P.Wh4[tid];
#pragma unroll
    for (int off = 32; off >= 1; off >>= 1) v += __shfl_down(v, off);
    if (tid == 0) P.out[g] = v + P.bh4[0];
  }
}

extern "C" void kernel_launch(void* const* d_in, const int* in_sizes, int n_in,
                              void* d_out, int out_size, void* d_ws, size_t ws_size,
                              hipStream_t stream) {
  Params P;
  P.x   = (const float*)d_in[0];
  P.W1  = (const float*)d_in[1];  P.b1  = (const float*)d_in[2];  P.a1 = (const float*)d_in[3];
  P.W2  = (const float*)d_in[4];  P.b2  = (const float*)d_in[5];  P.a2 = (const float*)d_in[6];
  P.Wc0 = (const float*)d_in[7];  P.bc0 = (const float*)d_in[8];
  P.Wc1 = (const float*)d_in[9];  P.bc1 = (const float*)d_in[10];
  P.Wc2 = (const float*)d_in[11]; P.bc2 = (const float*)d_in[12];
  P.Wc3 = (const float*)d_in[13]; P.bc3 = (const float*)d_in[14];
  P.W3  = (const float*)d_in[15]; P.b3  = (const float*)d_in[16]; P.a3 = (const float*)d_in[17];
  P.W4  = (const float*)d_in[18]; P.b4  = (const float*)d_in[19]; P.a4 = (const float*)d_in[20];
  P.Wh1 = (const float*)d_in[21]; P.bh1 = (const float*)d_in[22];
  P.Wh2 = (const float*)d_in[23]; P.bh2 = (const float*)d_in[24];
  P.Wh3 = (const float*)d_in[25]; P.bh3 = (const float*)d_in[26];
  P.Wh4 = (const float*)d_in[27]; P.bh4 = (const float*)d_in[28];
  P.out = (float*)d_out;

  (void)hipFuncSetAttribute(reinterpret_cast<const void*>(fused_gnn),
                            hipFuncAttributeMaxDynamicSharedMemorySize, LDS_BYTES);

  fused_gnn<<<NGRAPH, NT, LDS_BYTES, stream>>>(P);
}

// Round 11
// 297.333 us; speedup vs baseline: 1.1746x; 1.0138x over previous
//
#include <hip/hip_runtime.h>

#define NGRAPH 256
#define NNODE  512
#define KNN    6
#define NCAND  12
#define NF     64
#define SBF    72                 // bf16 row stride in shorts (144 B, 16B-aligned)
#define NT     768                // 12 waves (R4/R8-proven best; NT=1024 regressed: R7)
#define NW     12                 // waves per block
// LDS layout (float indices):
#define PBF    18432              // hbf = 512*72 shorts = 73728 B at [0,PBF)
                                  // pbf = 512*72 shorts at [PBF, 36864)
#define CANDO  PBF                // cand: 512*12 ushort = 3072 floats (dead before convs)
#define SQO    (PBF + 3072)       // 512 floats (bf16 sq, then exact sq; dead before convs)
#define WTO    36864              // Wt bf16: 64*72 shorts = 2304 floats
#define NBRO   39168              // nbr lists: 512*6 ushort = 3072 shorts = 1536 FLOATS
#define LDS_FLOATS 40704          // 39168 + 1536
#define LDS_BYTES  (LDS_FLOATS*4) // 162816 B <= 163840 B (160 KiB)
// pool/head scratch (pbf region, dead after last conv gather):
#define POOLP  PBF                // 12 waves x 64 pool partials; also Wh2/Wh3 split-k scratch
#define POOLED (PBF + 1024)
#define Y1OFF  (PBF + 1088)
#define Y2OFF  (PBF + 1344)
#define BIG 1e30f

typedef float v4f __attribute__((ext_vector_type(4)));
typedef float v2f __attribute__((ext_vector_type(2)));
typedef short v8s __attribute__((ext_vector_type(8)));

struct Params {
  const float *x;
  const float *W1,*b1,*a1, *W2,*b2,*a2;
  const float *Wc0,*bc0, *Wc1,*bc1, *Wc2,*bc2, *Wc3,*bc3;
  const float *W3,*b3,*a3, *W4,*b4,*a4;
  const float *Wh1,*bh1, *Wh2,*bh2, *Wh3,*bh3, *Wh4,*bh4;
  float *out;
};

// fp32 -> bf16 (RNE) as raw 16-bit
__device__ __forceinline__ unsigned f2bf(float x) {
  union { float f; unsigned u; } cc; cc.f = x;
  unsigned u = cc.u;
  return (u + 0x7FFFu + ((u >> 16) & 1u)) >> 16;
}
__device__ __forceinline__ float bflo(unsigned u) {
  union { unsigned u; float f; } c; c.u = u << 16; return c.f;
}
__device__ __forceinline__ float bfhi(unsigned u) {
  union { unsigned u; float f; } c; c.u = u & 0xffff0000u; return c.f;
}
// bf16 pair -> packed float2 (enables v_pk_add_f32 accumulation)
__device__ __forceinline__ v2f up2(unsigned u) {
  v2f r; r.x = bflo(u); r.y = bfhi(u); return r;
}

__device__ __forceinline__ v8s bfrag(const unsigned short* base, int row, int c0) {
  return *(const v8s*)(base + row*SBF + c0);
}

// pack filter-e with its index in the low 9 mantissa bits (|perturb| << bf16 noise;
// candidate SET is all that matters — exact fp32 re-rank decides final order)
__device__ __forceinline__ float packe(float e, int j) {
  return __uint_as_float((__float_as_uint(e) & 0xFFFFFE00u) | (unsigned)j);
}

// sorted-ascending insert via min/max propagation (2 inst/stage)
__device__ __forceinline__ void ins8(float (&b)[8], float v) {
  if (v < b[7]) {
#pragma unroll
    for (int p = 0; p < 8; ++p) {
      float lo = fminf(b[p], v);
      v = fmaxf(b[p], v);
      b[p] = lo;
    }
  }
}
__device__ __forceinline__ void ins12(float (&b)[NCAND], float v) {
  if (v < b[NCAND-1]) {
#pragma unroll
    for (int p = 0; p < NCAND; ++p) {
      float lo = fminf(b[p], v);
      v = fmaxf(b[p], v);
      b[p] = lo;
    }
  }
}

// T14 split Wt staging: issue the 8 strided loads EARLY (hidden under the
// previous layer's MFMA/gather), convert+write LATE at the wt-write point.
__device__ __forceinline__ void ld8(const float* W, float (&wf)[8], int tid) {
  const int col = tid >> 3, ks = (tid & 7) * 8;
  const float* wp = W + col;
#pragma unroll
  for (int i = 0; i < 8; ++i) wf[i] = wp[(ks + i) * NF];
}
__device__ __forceinline__ void wt_write(const float (&wf)[8], unsigned short* wt, int tid) {
  const int col = tid >> 3, ks = (tid & 7) * 8;
  unsigned d[4];
#pragma unroll
  for (int i = 0; i < 4; ++i)
    d[i] = f2bf(wf[2*i]) | (f2bf(wf[2*i+1]) << 16);
  *(uint4*)&wt[col*SBF + ks] = make_uint4(d[0], d[1], d[2], d[3]);
}

// Multi-tile filter: one wave processes NTILE output tiles simultaneously.
// B-fragments and sq vector are SHARED across tiles; the NTILE independent
// insert chains interleave -> hides the serial min/max latency.
template<int NTILE>
__device__ __forceinline__ void filter_tiles(const unsigned short* hbf,
                                             const float* ldsf,
                                             unsigned short* cand,
                                             const int (&tts)[NTILE],
                                             int lane, int c, int qq) {
  v8s A0[NTILE], A1[NTILE];
  float d8[NTILE][8];
  int i0[NTILE];
#pragma unroll
  for (int k = 0; k < NTILE; ++k) {
    i0[k] = tts[k] * 16;
    A0[k] = bfrag(hbf, i0[k] + c, qq*8);
    A1[k] = bfrag(hbf, i0[k] + c, 32 + qq*8);
#pragma unroll
    for (int m = 0; m < 8; ++m) d8[k][m] = BIG;
  }
#pragma unroll 1
  for (int jt = 0; jt < 32; ++jt) {
    const int j0 = jt * 16;
    v8s B0 = bfrag(hbf, j0 + c, qq*8);
    v8s B1 = bfrag(hbf, j0 + c, 32 + qq*8);
    float4 sv = *(const float4*)&ldsf[SQO + j0 + qq*4];
    const int jb = j0 + qq*4;
#pragma unroll
    for (int k = 0; k < NTILE; ++k) {
      v4f acc = {0.f, 0.f, 0.f, 0.f};
      acc = __builtin_amdgcn_mfma_f32_16x16x32_bf16(B0, A0[k], acc, 0, 0, 0);
      acc = __builtin_amdgcn_mfma_f32_16x16x32_bf16(B1, A1[k], acc, 0, 0, 0);
      float e0 = fmaf(-2.f, acc[0], sv.x);
      float e1 = fmaf(-2.f, acc[1], sv.y);
      float e2 = fmaf(-2.f, acc[2], sv.z);
      float e3 = fmaf(-2.f, acc[3], sv.w);
      if (jt == tts[k]) {               // self-exclusion tile (wave-uniform)
        const int myrow = i0[k] + c;
        if (jb     == myrow) e0 = BIG;
        if (jb + 1 == myrow) e1 = BIG;
        if (jb + 2 == myrow) e2 = BIG;
        if (jb + 3 == myrow) e3 = BIG;
      }
      ins8(d8[k], packe(e0, jb));
      ins8(d8[k], packe(e1, jb+1));
      ins8(d8[k], packe(e2, jb+2));
      ins8(d8[k], packe(e3, jb+3));
    }
  }
  // merge the 4 qq-lanes per row: 2 butterfly stages, capacity 12 (per tile)
#pragma unroll
  for (int k = 0; k < NTILE; ++k) {
    float cd[NCAND];
#pragma unroll
    for (int m = 0; m < 8; ++m) cd[m] = d8[k][m];
#pragma unroll
    for (int m = 8; m < NCAND; ++m) cd[m] = BIG;
    {
      float pd[8];
#pragma unroll
      for (int s = 0; s < 8; ++s) pd[s] = __shfl_xor(cd[s], 16);
#pragma unroll
      for (int s = 0; s < 8; ++s) ins12(cd, pd[s]);
    }
    {
      float pd[NCAND];
#pragma unroll
      for (int s = 0; s < NCAND; ++s) pd[s] = __shfl_xor(cd[s], 32);
#pragma unroll
      for (int s = 0; s < NCAND; ++s) ins12(cd, pd[s]);
    }
    if (lane < 16) {
#pragma unroll
      for (int s = 0; s < NCAND; ++s)
        cand[(i0[k] + lane)*NCAND + s] =
          (unsigned short)(__float_as_uint(cd[s]) & 0x1FFu);
    }
  }
}

__global__ __launch_bounds__(NT) void fused_gnn(Params P) {
  extern __shared__ float lds[];
  unsigned short* hbf  = (unsigned short*)lds;
  unsigned short* pbf  = (unsigned short*)&lds[PBF];
  unsigned short* wt   = (unsigned short*)&lds[WTO];
  unsigned short* cand = (unsigned short*)&lds[CANDO];
  unsigned short* nbrs = (unsigned short*)&lds[NBRO];
  const int tid  = threadIdx.x;
  const int g    = blockIdx.x;
  const int rA   = tid;                  // row ownership for tid<512
  const int lane = tid & 63;
  const int w    = tid >> 6;             // wave 0..11
  const int c    = lane & 15;
  const int qq   = lane >> 4;            // 0..3

  const float* xgp = P.x + (size_t)g * NNODE * NF;
  const float4* xg = (const float4*)xgp;

  // ---- stage x[g] as bf16 into hbf ----
#pragma unroll 1
  for (int i = tid; i < NNODE*NF/4; i += NT) {
    float4 v = xg[i];
    int row = i >> 4, k4 = i & 15;
    unsigned lo = f2bf(v.x) | (f2bf(v.y) << 16);
    unsigned hi = f2bf(v.z) | (f2bf(v.w) << 16);
    *(uint2*)&hbf[row*SBF + 4*k4] = make_uint2(lo, hi);
  }
  __syncthreads();

  // ---- filter sq from bf16 values (b128 row reads) ----
  if (tid < 512) {
    const uint4* xr = (const uint4*)(hbf + rA*SBF);
    float s = 0.f;
#pragma unroll
    for (int k = 0; k < 8; ++k) {
      uint4 u = xr[k];
      float f;
      f = bflo(u.x); s = fmaf(f, f, s); f = bfhi(u.x); s = fmaf(f, f, s);
      f = bflo(u.y); s = fmaf(f, f, s); f = bfhi(u.y); s = fmaf(f, f, s);
      f = bflo(u.z); s = fmaf(f, f, s); f = bfhi(u.z); s = fmaf(f, f, s);
      f = bflo(u.w); s = fmaf(f, f, s); f = bfhi(u.w); s = fmaf(f, f, s);
    }
    lds[SQO + rA] = s;
  }
  __syncthreads();

  // ==== kNN filter: MFMA Gram, multi-tile per wave ====
  // tile cover: w<8 -> {w, w+8, w+16} (0..23); w>=8 -> {w+16, w+20} (24..31)
  if (w < 8) {
    int tts[3] = {w, w + 8, w + 16};
    filter_tiles<3>(hbf, lds, cand, tts, lane, c, qq);
  } else {
    int tts[2] = {w + 16, w + 20};
    filter_tiles<2>(hbf, lds, cand, tts, lane, c, qq);
  }
  __syncthreads();   // filter done; SQO safe to overwrite

  // ==== exact fp32 refine: own row resident in registers (R4-proven) ====
  float4 xr16[16];
  if (tid < 512) {
    const float4* xrow = (const float4*)(xgp + rA*NF);
#pragma unroll
    for (int k4 = 0; k4 < 16; ++k4) xr16[k4] = xrow[k4];
    float s0 = 0.f;
#pragma unroll
    for (int k4 = 0; k4 < 16; ++k4) {
      float4 a = xr16[k4];
      s0 = fmaf(a.x,a.x,s0); s0 = fmaf(a.y,a.y,s0); s0 = fmaf(a.z,a.z,s0); s0 = fmaf(a.w,a.w,s0);
    }
    lds[SQO + rA] = s0;
  }
  __syncthreads();   // exact sq published

  if (tid < 512) {
    float nd[6]; int ni[6];
#pragma unroll
    for (int m = 0; m < 6; ++m) { nd[m] = BIG; ni[m] = 0x7fffffff; }
    int cnd[NCAND];
#pragma unroll
    for (int s = 0; s < NCAND; ++s) cnd[s] = cand[rA*NCAND + s];

#pragma unroll 1
    for (int s = 0; s < NCAND; ++s) {
      int j = cnd[s];
      const float4* xj = (const float4*)(xgp + j*NF);
      float4 aa = {0.f, 0.f, 0.f, 0.f};
#pragma unroll
      for (int k4 = 0; k4 < 16; ++k4) {
        float4 v = xj[k4];
        aa.x = fmaf(xr16[k4].x, v.x, aa.x); aa.y = fmaf(xr16[k4].y, v.y, aa.y);
        aa.z = fmaf(xr16[k4].z, v.z, aa.z); aa.w = fmaf(xr16[k4].w, v.w, aa.w);
      }
      float e = fmaf(-2.f, (aa.x+aa.y)+(aa.z+aa.w), lds[SQO + j]);
      if (e < nd[5] || (e == nd[5] && j < ni[5])) {
#pragma unroll
        for (int pp = 0; pp < 6; ++pp) {
          bool lt = (e < nd[pp]) || (e == nd[pp] && j < ni[pp]);
          float tb2 = nd[pp]; int ti = ni[pp];
          nd[pp] = lt ? e : tb2;  ni[pp] = lt ? j : ti;
          e      = lt ? tb2 : e;  j      = lt ? ti : j;
        }
      }
    }
    // publish neighbor lists for the wave-cooperative gather (512*6 ushort)
#pragma unroll
    for (int m = 0; m < 6; ++m) nbrs[rA*KNN + m] = (unsigned short)ni[m];
  }

  // ==== layers 0..6: bf16 MFMA GEMMs, 2 barriers/layer, pipelined Wt staging ====
  float wf[8];
  if (tid < 512) ld8(P.W1, wf, tid);     // loads for L0 (xr16 dead; wf live)
  __syncthreads();                        // S0: nbrs published
  if (tid < 512) { wt_write(wf, wt, tid); ld8(P.W2, wf, tid); }  // wt<-W1; load L1
  __syncthreads();                        // S1: wt(L0) ready

#pragma unroll 1
  for (int L = 0; L < 7; ++L) {
    const bool isconv = (L >= 2 && L <= 5);
    const float* bl = L==0?P.b1 : L==1?P.b2 : L==2?P.bc0 : L==3?P.bc1 :
                      L==4?P.bc2 : L==5?P.bc3 : P.b3;
    const float* al = L==0?P.a1 : L==1?P.a2 : P.a3;  // read only if !isconv

    // B fragments + bias from current wt (written before the last barrier)
    v8s B0[4], B1[4];
#pragma unroll
    for (int n = 0; n < 4; ++n) {
      B0[n] = bfrag(wt, n*16 + c, qq*8);
      B1[n] = bfrag(wt, n*16 + c, 32 + qq*8);
    }
    float br[4], ar[4];
    if (!isconv) {
#pragma unroll
      for (int n = 0; n < 4; ++n) { br[n] = bl[n*16 + c]; ar[n] = al[n*16 + c]; }
    }
    __syncthreads();                     // B(L): all frags secured; wt reusable

    if (tid < 512) {
      wt_write(wf, wt, tid);             // wt <- W(L+1) (regs loaded during L-1)
      if (L < 6) {
        const float* Wn2 = L==0?P.Wc0 : L==1?P.Wc1 : L==2?P.Wc2 :
                           L==3?P.Wc3 : L==4?P.W3 : P.W4;   // W(L+2)
        ld8(Wn2, wf, tid);               // latency hides under this layer's MFMA
      }
    }

#pragma unroll 1
    for (int tt = w; tt < 32; tt += NW) {
      const int i0 = tt * 16;
      v8s A0 = bfrag(hbf, i0 + c, qq*8);
      v8s A1 = bfrag(hbf, i0 + c, 32 + qq*8);
#pragma unroll
      for (int n = 0; n < 4; ++n) {
        v4f acc = {0.f, 0.f, 0.f, 0.f};
        acc = __builtin_amdgcn_mfma_f32_16x16x32_bf16(A0, B0[n], acc, 0, 0, 0);
        acc = __builtin_amdgcn_mfma_f32_16x16x32_bf16(A1, B1[n], acc, 0, 0, 0);
        if (isconv) {
#pragma unroll
          for (int r = 0; r < 4; ++r)
            pbf[(i0 + qq*4 + r)*SBF + n*16 + c] = (unsigned short)f2bf(acc[r]);
        } else {
#pragma unroll
          for (int r = 0; r < 4; ++r) {
            float v = acc[r] + br[n];
            v = v >= 0.f ? v : ar[n]*v;
            hbf[(i0 + qq*4 + r)*SBF + n*16 + c] = (unsigned short)f2bf(v);
          }
        }
      }
    }
    __syncthreads();                     // C(L): p/h stable + wt(L+1) ready

    if (isconv) {
      // wave-cooperative gather: 8 lanes serve one row; bank classes
      // (nbr+s) mod 8 exactly balanced for any nbr values.
      // Per-feat accumulation order: own, +6*b, nbr0..nbr5.
      const int s = tid & 7;                 // b128 chunk (8 feats)
      const float* bls = bl + 8*s;
      float4 bv0 = *(const float4*)(bls);
      float4 bv1 = *(const float4*)(bls + 4);
#pragma unroll 1
      for (int r = tid >> 3; r < NNODE; r += NT/8) {
        const unsigned short* nb = &nbrs[r*KNN];
        uint4 own = *(const uint4*)&hbf[r*SBF + 8*s];
        v2f a0 = up2(own.x), a1 = up2(own.y), a2 = up2(own.z), a3 = up2(own.w);
        v2f t;
        t.x = bv0.x; t.y = bv0.y; a0 += 6.f*t;
        t.x = bv0.z; t.y = bv0.w; a1 += 6.f*t;
        t.x = bv1.x; t.y = bv1.y; a2 += 6.f*t;
        t.x = bv1.z; t.y = bv1.w; a3 += 6.f*t;
#pragma unroll
        for (int mm = 0; mm < KNN; ++mm) {
          int nbr = nb[mm];
          uint4 p = *(const uint4*)&pbf[nbr*SBF + 8*s];
          a0 += up2(p.x); a1 += up2(p.y); a2 += up2(p.z); a3 += up2(p.w);
        }
        uint4 o;
        o.x = f2bf(a0.x) | (f2bf(a0.y) << 16);
        o.y = f2bf(a1.x) | (f2bf(a1.y) << 16);
        o.z = f2bf(a2.x) | (f2bf(a2.y) << 16);
        o.w = f2bf(a3.x) | (f2bf(a3.y) << 16);
        *(uint4*)&hbf[r*SBF + 8*s] = o;
      }
      // writes guarded by next layer's B(L+1) barrier before any hbf read
    }
  }

  // ==== L7 peeled: MFMA + bias/PReLU + REGISTER pooling ====
  // h after L7 is consumed ONLY by global_add_pool -> never materialize it.
  // wt holds W4 (written at L6's wt_write, guarded by C(6)). No B(7) barrier
  // needed (wt is not overwritten again). Saves L7's 48 b16-stores/wave-tile,
  // the 16K-word pool re-read pass, and 2 barriers.
  {
    v8s B0[4], B1[4];
#pragma unroll
    for (int n = 0; n < 4; ++n) {
      B0[n] = bfrag(wt, n*16 + c, qq*8);
      B1[n] = bfrag(wt, n*16 + c, 32 + qq*8);
    }
    float br[4], ar[4];
#pragma unroll
    for (int n = 0; n < 4; ++n) { br[n] = P.b4[n*16 + c]; ar[n] = P.a4[n*16 + c]; }

    float ps[4] = {0.f, 0.f, 0.f, 0.f};   // pool partial for col n*16+c
#pragma unroll 1
    for (int tt = w; tt < 32; tt += NW) {
      const int i0 = tt * 16;
      v8s A0 = bfrag(hbf, i0 + c, qq*8);
      v8s A1 = bfrag(hbf, i0 + c, 32 + qq*8);
#pragma unroll
      for (int n = 0; n < 4; ++n) {
        v4f acc = {0.f, 0.f, 0.f, 0.f};
        acc = __builtin_amdgcn_mfma_f32_16x16x32_bf16(A0, B0[n], acc, 0, 0, 0);
        acc = __builtin_amdgcn_mfma_f32_16x16x32_bf16(A1, B1[n], acc, 0, 0, 0);
#pragma unroll
        for (int r = 0; r < 4; ++r) {
          float v = acc[r] + br[n];
          v = v >= 0.f ? v : ar[n]*v;
          ps[n] += v;                    // sum over this tile's 4 qq-rows
        }
      }
    }
    // sum the 4 qq-groups (rows) per column: col index c is invariant
    // under lane^16 / lane^32 exchanges
#pragma unroll
    for (int n = 0; n < 4; ++n) {
      ps[n] += __shfl_xor(ps[n], 16);
      ps[n] += __shfl_xor(ps[n], 32);
    }
    if (lane < 16) {
#pragma unroll
      for (int n = 0; n < 4; ++n) lds[POOLP + w*64 + n*16 + c] = ps[n];
    }
  }
  __syncthreads();   // all wave partials published

  if (tid < 64) {
    float pool = 0.f;
#pragma unroll
    for (int cc = 0; cc < NW; ++cc) pool += lds[POOLP + cc*64 + tid];
    lds[POOLED + tid] = pool;
  }
  __syncthreads();

  // ---- head MLP (fp32) ----
  if (tid < 256) {
    float acc = P.bh1[tid];
#pragma unroll 4
    for (int k = 0; k < 64; ++k) acc = fmaf(lds[POOLED+k], P.Wh1[k*256 + tid], acc);
    lds[Y1OFF + tid] = acc >= 0.f ? acc : 0.2f*acc;
  }
  __syncthreads();
  // Wh2 (256x256): split-k x2 over 512 threads, partials in POOLP scratch
  if (tid < 512) {
    int o = tid & 255, hh = tid >> 8;
    float acc = hh ? 0.f : P.bh2[o];
    const int k0 = hh * 128;
#pragma unroll 4
    for (int k = k0; k < k0 + 128; ++k) acc = fmaf(lds[Y1OFF+k], P.Wh2[k*256 + o], acc);
    lds[POOLP + hh*256 + o] = acc;
  }
  __syncthreads();
  if (tid < 256) {
    float acc = lds[POOLP + tid] + lds[POOLP + 256 + tid];
    lds[Y2OFF + tid] = acc >= 0.f ? acc : 0.2f*acc;
  }
  __syncthreads();
  // Wh3 (256x64): split-k x4 over 256 threads
  if (tid < 256) {
    int o = tid & 63, hh = tid >> 6;
    float acc = 0.f;
    const int k0 = hh * 64;
#pragma unroll 4
    for (int k = k0; k < k0 + 64; ++k) acc = fmaf(lds[Y2OFF+k], P.Wh3[k*64 + o], acc);
    lds[POOLP + hh*64 + o] = acc;
  }
  __syncthreads();
  // y3 + Wh4 dot: fused in wave 0 (shuffle reduce, no extra barrier)
  if (tid < 64) {
    float acc = P.bh3[tid] + lds[POOLP + tid] + lds[POOLP + 64 + tid]
              + lds[POOLP + 128 + tid] + lds[POOLP + 192 + tid];
    float y3 = acc >= 0.f ? acc : 0.2f*acc;
    float v = y3 * P.Wh4[tid];
#pragma unroll
    for (int off = 32; off >= 1; off >>= 1) v += __shfl_down(v, off);
    if (tid == 0) P.out[g] = v + P.bh4[0];
  }
}

extern "C" void kernel_launch(void* const* d_in, const int* in_sizes, int n_in,
                              void* d_out, int out_size, void* d_ws, size_t ws_size,
                              hipStream_t stream) {
  Params P;
  P.x   = (const float*)d_in[0];
  P.W1  = (const float*)d_in[1];  P.b1  = (const float*)d_in[2];  P.a1 = (const float*)d_in[3];
  P.W2  = (const float*)d_in[4];  P.b2  = (const float*)d_in[5];  P.a2 = (const float*)d_in[6];
  P.Wc0 = (const float*)d_in[7];  P.bc0 = (const float*)d_in[8];
  P.Wc1 = (const float*)d_in[9];  P.bc1 = (const float*)d_in[10];
  P.Wc2 = (const float*)d_in[11]; P.bc2 = (const float*)d_in[12];
  P.Wc3 = (const float*)d_in[13]; P.bc3 = (const float*)d_in[14];
  P.W3  = (const float*)d_in[15]; P.b3  = (const float*)d_in[16]; P.a3 = (const float*)d_in[17];
  P.W4  = (const float*)d_in[18]; P.b4  = (const float*)d_in[19]; P.a4 = (const float*)d_in[20];
  P.Wh1 = (const float*)d_in[21]; P.bh1 = (const float*)d_in[22];
  P.Wh2 = (const float*)d_in[23]; P.bh2 = (const float*)d_in[24];
  P.Wh3 = (const float*)d_in[25]; P.bh3 = (const float*)d_in[26];
  P.Wh4 = (const float*)d_in[27]; P.bh4 = (const float*)d_in[28];
  P.out = (float*)d_out;

  (void)hipFuncSetAttribute(reinterpret_cast<const void*>(fused_gnn),
                            hipFuncAttributeMaxDynamicSharedMemorySize, LDS_BYTES);

  fused_gnn<<<NGRAPH, NT, LDS_BYTES, stream>>>(P);
}

// Round 13
// 293.262 us; speedup vs baseline: 1.1909x; 1.0139x over previous
//
#include <hip/hip_runtime.h>

#define NGRAPH 256
#define NNODE  512
#define KNN    6
#define NCAND  12
#define NF     64
#define SBF    72                 // bf16 row stride in shorts (144 B, 16B-aligned)
#define NT     768                // 12 waves (R4/R8-proven best; NT=1024 regressed: R7)
#define NW     12                 // waves per block
// LDS layout (float indices):
#define PBF    18432              // hbf = 512*72 shorts = 73728 B at [0,PBF)
                                  // pbf = 512*72 shorts at [PBF, 36864)
#define CANDO  PBF                // cand: 512*12 ushort = 3072 floats (dead before convs)
#define SQO    (PBF + 3072)       // 512 floats (bf16 sq, then exact sq; dead before convs)
#define WTO    36864              // Wt bf16: 64*72 shorts = 2304 floats
#define NBRO   39168              // nbr lists: 512*6 ushort = 3072 shorts = 1536 FLOATS
#define LDS_FLOATS 40704          // 39168 + 1536
#define LDS_BYTES  (LDS_FLOATS*4) // 162816 B <= 163840 B (160 KiB)
// pool/head scratch (pbf region, dead after last conv gather):
#define POOLP  PBF                // 12 waves x 64 pool partials; also Wh2/Wh3 split-k scratch
#define POOLED (PBF + 1024)
#define Y1OFF  (PBF + 1088)
#define Y2OFF  (PBF + 1344)
#define BIG 1e30f

typedef float v4f __attribute__((ext_vector_type(4)));
typedef float v2f __attribute__((ext_vector_type(2)));
typedef short v8s __attribute__((ext_vector_type(8)));

struct Params {
  const float *x;
  const float *W1,*b1,*a1, *W2,*b2,*a2;
  const float *Wc0,*bc0, *Wc1,*bc1, *Wc2,*bc2, *Wc3,*bc3;
  const float *W3,*b3,*a3, *W4,*b4,*a4;
  const float *Wh1,*bh1, *Wh2,*bh2, *Wh3,*bh3, *Wh4,*bh4;
  float *out;
};

// fp32 -> bf16 (RNE) as raw 16-bit
__device__ __forceinline__ unsigned f2bf(float x) {
  union { float f; unsigned u; } cc; cc.f = x;
  unsigned u = cc.u;
  return (u + 0x7FFFu + ((u >> 16) & 1u)) >> 16;
}
__device__ __forceinline__ float bflo(unsigned u) {
  union { unsigned u; float f; } c; c.u = u << 16; return c.f;
}
__device__ __forceinline__ float bfhi(unsigned u) {
  union { unsigned u; float f; } c; c.u = u & 0xffff0000u; return c.f;
}
// bf16 pair -> packed float2 (enables v_pk_add_f32 accumulation)
__device__ __forceinline__ v2f up2(unsigned u) {
  v2f r; r.x = bflo(u); r.y = bfhi(u); return r;
}

__device__ __forceinline__ v8s bfrag(const unsigned short* base, int row, int c0) {
  return *(const v8s*)(base + row*SBF + c0);
}

// pack filter-e with its index in the low 9 mantissa bits (|perturb| << bf16 noise;
// candidate SET is all that matters — exact fp32 re-rank decides final order)
__device__ __forceinline__ float packe(float e, int j) {
  return __uint_as_float((__float_as_uint(e) & 0xFFFFFE00u) | (unsigned)j);
}

// sorted-ascending insert via min/max propagation (2 inst/stage)
__device__ __forceinline__ void ins8(float (&b)[8], float v) {
  if (v < b[7]) {
#pragma unroll
    for (int p = 0; p < 8; ++p) {
      float lo = fminf(b[p], v);
      v = fmaxf(b[p], v);
      b[p] = lo;
    }
  }
}
__device__ __forceinline__ void ins12(float (&b)[NCAND], float v) {
  if (v < b[NCAND-1]) {
#pragma unroll
    for (int p = 0; p < NCAND; ++p) {
      float lo = fminf(b[p], v);
      v = fmaxf(b[p], v);
      b[p] = lo;
    }
  }
}

// T14 split Wt staging: issue the 8 strided loads EARLY, write LATE.
__device__ __forceinline__ void ld8(const float* W, float (&wf)[8], int tid) {
  const int col = tid >> 3, ks = (tid & 7) * 8;
  const float* wp = W + col;
#pragma unroll
  for (int i = 0; i < 8; ++i) wf[i] = wp[(ks + i) * NF];
}
__device__ __forceinline__ void wt_write(const float (&wf)[8], unsigned short* wt, int tid) {
  const int col = tid >> 3, ks = (tid & 7) * 8;
  unsigned d[4];
#pragma unroll
  for (int i = 0; i < 4; ++i)
    d[i] = f2bf(wf[2*i]) | (f2bf(wf[2*i+1]) << 16);
  *(uint4*)&wt[col*SBF + ks] = make_uint4(d[0], d[1], d[2], d[3]);
}

// Multi-tile filter: one wave processes NTILE output tiles simultaneously.
// B-fragments and sq vector are SHARED across tiles; the NTILE independent
// insert chains interleave -> hides the serial min/max latency.
template<int NTILE>
__device__ __forceinline__ void filter_tiles(const unsigned short* hbf,
                                             const float* ldsf,
                                             unsigned short* cand,
                                             const int (&tts)[NTILE],
                                             int lane, int c, int qq) {
  v8s A0[NTILE], A1[NTILE];
  float d8[NTILE][8];
  int i0[NTILE];
#pragma unroll
  for (int k = 0; k < NTILE; ++k) {
    i0[k] = tts[k] * 16;
    A0[k] = bfrag(hbf, i0[k] + c, qq*8);
    A1[k] = bfrag(hbf, i0[k] + c, 32 + qq*8);
#pragma unroll
    for (int m = 0; m < 8; ++m) d8[k][m] = BIG;
  }
#pragma unroll 1
  for (int jt = 0; jt < 32; ++jt) {
    const int j0 = jt * 16;
    v8s B0 = bfrag(hbf, j0 + c, qq*8);
    v8s B1 = bfrag(hbf, j0 + c, 32 + qq*8);
    float4 sv = *(const float4*)&ldsf[SQO + j0 + qq*4];
    const int jb = j0 + qq*4;
#pragma unroll
    for (int k = 0; k < NTILE; ++k) {
      v4f acc = {0.f, 0.f, 0.f, 0.f};
      acc = __builtin_amdgcn_mfma_f32_16x16x32_bf16(B0, A0[k], acc, 0, 0, 0);
      acc = __builtin_amdgcn_mfma_f32_16x16x32_bf16(B1, A1[k], acc, 0, 0, 0);
      float e0 = fmaf(-2.f, acc[0], sv.x);
      float e1 = fmaf(-2.f, acc[1], sv.y);
      float e2 = fmaf(-2.f, acc[2], sv.z);
      float e3 = fmaf(-2.f, acc[3], sv.w);
      if (jt == tts[k]) {               // self-exclusion tile (wave-uniform)
        const int myrow = i0[k] + c;
        if (jb     == myrow) e0 = BIG;
        if (jb + 1 == myrow) e1 = BIG;
        if (jb + 2 == myrow) e2 = BIG;
        if (jb + 3 == myrow) e3 = BIG;
      }
      ins8(d8[k], packe(e0, jb));
      ins8(d8[k], packe(e1, jb+1));
      ins8(d8[k], packe(e2, jb+2));
      ins8(d8[k], packe(e3, jb+3));
    }
  }
  // merge the 4 qq-lanes per row: 2 butterfly stages, capacity 12 (per tile)
#pragma unroll
  for (int k = 0; k < NTILE; ++k) {
    float cd[NCAND];
#pragma unroll
    for (int m = 0; m < 8; ++m) cd[m] = d8[k][m];
#pragma unroll
    for (int m = 8; m < NCAND; ++m) cd[m] = BIG;
    {
      float pd[8];
#pragma unroll
      for (int s = 0; s < 8; ++s) pd[s] = __shfl_xor(cd[s], 16);
#pragma unroll
      for (int s = 0; s < 8; ++s) ins12(cd, pd[s]);
    }
    {
      float pd[NCAND];
#pragma unroll
      for (int s = 0; s < NCAND; ++s) pd[s] = __shfl_xor(cd[s], 32);
#pragma unroll
      for (int s = 0; s < NCAND; ++s) ins12(cd, pd[s]);
    }
    if (lane < 16) {
#pragma unroll
      for (int s = 0; s < NCAND; ++s)
        cand[(i0[k] + lane)*NCAND + s] =
          (unsigned short)(__float_as_uint(cd[s]) & 0x1FFu);
    }
  }
}

__global__ __launch_bounds__(NT) void fused_gnn(Params P) {
  extern __shared__ float lds[];
  unsigned short* hbf  = (unsigned short*)lds;
  unsigned short* pbf  = (unsigned short*)&lds[PBF];
  unsigned short* wt   = (unsigned short*)&lds[WTO];
  unsigned short* cand = (unsigned short*)&lds[CANDO];
  unsigned short* nbrs = (unsigned short*)&lds[NBRO];
  const int tid  = threadIdx.x;
  const int g    = blockIdx.x;
  const int rA   = tid;                  // row ownership for tid<512
  const int lane = tid & 63;
  const int w    = tid >> 6;             // wave 0..11
  const int c    = lane & 15;
  const int qq   = lane >> 4;            // 0..3

  const float* xgp = P.x + (size_t)g * NNODE * NF;
  const float4* xg = (const float4*)xgp;

  // ---- stage x[g] as bf16 into hbf ----
#pragma unroll 1
  for (int i = tid; i < NNODE*NF/4; i += NT) {
    float4 v = xg[i];
    int row = i >> 4, k4 = i & 15;
    unsigned lo = f2bf(v.x) | (f2bf(v.y) << 16);
    unsigned hi = f2bf(v.z) | (f2bf(v.w) << 16);
    *(uint2*)&hbf[row*SBF + 4*k4] = make_uint2(lo, hi);
  }
  __syncthreads();

  // ---- filter sq from bf16 values (b128 row reads) ----
  if (tid < 512) {
    const uint4* xr = (const uint4*)(hbf + rA*SBF);
    float s = 0.f;
#pragma unroll
    for (int k = 0; k < 8; ++k) {
      uint4 u = xr[k];
      float f;
      f = bflo(u.x); s = fmaf(f, f, s); f = bfhi(u.x); s = fmaf(f, f, s);
      f = bflo(u.y); s = fmaf(f, f, s); f = bfhi(u.y); s = fmaf(f, f, s);
      f = bflo(u.z); s = fmaf(f, f, s); f = bfhi(u.z); s = fmaf(f, f, s);
      f = bflo(u.w); s = fmaf(f, f, s); f = bfhi(u.w); s = fmaf(f, f, s);
    }
    lds[SQO + rA] = s;
  }
  __syncthreads();

  // ==== kNN filter: MFMA Gram, multi-tile per wave ====
  // tile cover: w<8 -> {w, w+8, w+16} (0..23); w>=8 -> {w+16, w+20} (24..31)
  if (w < 8) {
    int tts[3] = {w, w + 8, w + 16};
    filter_tiles<3>(hbf, lds, cand, tts, lane, c, qq);
  } else {
    int tts[2] = {w + 16, w + 20};
    filter_tiles<2>(hbf, lds, cand, tts, lane, c, qq);
  }
  // stage wt(W1) inside the filter phase (wt region untouched by filter);
  // one-time ~300cy exposed ld latency, amortized by filter tail skew
  float wf[8];
  if (tid < 512) { ld8(P.W1, wf, tid); wt_write(wf, wt, tid); }
  __syncthreads();   // filter done; SQO reusable; wt=W1 visible

  // ==== exact fp32 refine sq (waves 0-7) ∥ L0 frag pre-read (waves 8-11) ====
  float4 xr16[16];
  v8s LB0[4], LB1[4];
  float lbr[4], lar[4];
  if (tid < 512) {
    const float4* xrow = (const float4*)(xgp + rA*NF);
#pragma unroll
    for (int k4 = 0; k4 < 16; ++k4) xr16[k4] = xrow[k4];
    float s0 = 0.f;
#pragma unroll
    for (int k4 = 0; k4 < 16; ++k4) {
      float4 a = xr16[k4];
      s0 = fmaf(a.x,a.x,s0); s0 = fmaf(a.y,a.y,s0); s0 = fmaf(a.z,a.z,s0); s0 = fmaf(a.w,a.w,s0);
    }
    lds[SQO + rA] = s0;
  } else {
    // waves 8-11: pre-read L0 B-frags (wt=W1, stable across the next barrier)
#pragma unroll
    for (int n = 0; n < 4; ++n) {
      LB0[n] = bfrag(wt, n*16 + c, qq*8);
      LB1[n] = bfrag(wt, n*16 + c, 32 + qq*8);
      lbr[n] = P.b1[n*16 + c];
      lar[n] = P.a1[n*16 + c];
    }
  }
  __syncthreads();   // exact sq published

  // ==== SPLIT: refine (waves 0-7) ∥ L0 dense GEMM (waves 8-11) ====
  // Disjoint: refine reads global x/cand/SQO, writes nbrs; L0 reads hbf/wt(regs),
  // writes hbf in place (disjoint tile rows). wt(W1) reads completed pre-barrier,
  // so the refine tail's wt_write(W2) cannot race.
  if (tid < 512) {
    float nd[6]; int ni[6];
#pragma unroll
    for (int m = 0; m < 6; ++m) { nd[m] = BIG; ni[m] = 0x7fffffff; }
    int cnd[NCAND];
#pragma unroll
    for (int s = 0; s < NCAND; ++s) cnd[s] = cand[rA*NCAND + s];

#pragma unroll 2
    for (int s = 0; s < NCAND; ++s) {
      int j = cnd[s];
      const float4* xj = (const float4*)(xgp + j*NF);
      float4 aa = {0.f, 0.f, 0.f, 0.f};
#pragma unroll
      for (int k4 = 0; k4 < 16; ++k4) {
        float4 v = xj[k4];
        aa.x = fmaf(xr16[k4].x, v.x, aa.x); aa.y = fmaf(xr16[k4].y, v.y, aa.y);
        aa.z = fmaf(xr16[k4].z, v.z, aa.z); aa.w = fmaf(xr16[k4].w, v.w, aa.w);
      }
      float e = fmaf(-2.f, (aa.x+aa.y)+(aa.z+aa.w), lds[SQO + j]);
      if (e < nd[5] || (e == nd[5] && j < ni[5])) {
#pragma unroll
        for (int pp = 0; pp < 6; ++pp) {
          bool lt = (e < nd[pp]) || (e == nd[pp] && j < ni[pp]);
          float tb2 = nd[pp]; int ti = ni[pp];
          nd[pp] = lt ? e : tb2;  ni[pp] = lt ? j : ti;
          e      = lt ? tb2 : e;  j      = lt ? ti : j;
        }
      }
    }
#pragma unroll
    for (int m = 0; m < 6; ++m) nbrs[rA*KNN + m] = (unsigned short)ni[m];
    // pipeline tail: wt <- W2 (L1), preload Wc0 (L2)
    ld8(P.W2, wf, tid);
    wt_write(wf, wt, tid);
    ld8(P.Wc0, wf, tid);
  } else {
    // L0 dense on waves 8-11: 8 tiles each, in-place h = prelu(x@W1+b1)
#pragma unroll 1
    for (int tt = w - 8; tt < 32; tt += 4) {
      const int i0 = tt * 16;
      v8s A0 = bfrag(hbf, i0 + c, qq*8);
      v8s A1 = bfrag(hbf, i0 + c, 32 + qq*8);
#pragma unroll
      for (int n = 0; n < 4; ++n) {
        v4f acc = {0.f, 0.f, 0.f, 0.f};
        acc = __builtin_amdgcn_mfma_f32_16x16x32_bf16(A0, LB0[n], acc, 0, 0, 0);
        acc = __builtin_amdgcn_mfma_f32_16x16x32_bf16(A1, LB1[n], acc, 0, 0, 0);
#pragma unroll
        for (int r = 0; r < 4; ++r) {
          float v = acc[r] + lbr[n];
          v = v >= 0.f ? v : lar[n]*v;
          hbf[(i0 + qq*4 + r)*SBF + n*16 + c] = (unsigned short)f2bf(v);
        }
      }
    }
  }
  __syncthreads();   // join: nbrs + h(L0) + wt(W2) all ready

  // ==== layers 1..6: bf16 MFMA GEMMs, 2 barriers/layer, pipelined Wt ====
#pragma unroll 1
  for (int L = 1; L < 7; ++L) {
    const bool isconv = (L >= 2 && L <= 5);
    const float* bl = L==1?P.b2 : L==2?P.bc0 : L==3?P.bc1 :
                      L==4?P.bc2 : L==5?P.bc3 : P.b3;
    const float* al = L==1?P.a2 : P.a3;   // read only at L==1, L==6

    // B fragments + bias from current wt (written before the last barrier)
    v8s B0[4], B1[4];
#pragma unroll
    for (int n = 0; n < 4; ++n) {
      B0[n] = bfrag(wt, n*16 + c, qq*8);
      B1[n] = bfrag(wt, n*16 + c, 32 + qq*8);
    }
    float br[4], ar[4];
    if (!isconv) {
#pragma unroll
      for (int n = 0; n < 4; ++n) { br[n] = bl[n*16 + c]; ar[n] = al[n*16 + c]; }
    }
    __syncthreads();                     // B(L): all frags secured; wt reusable

    if (tid < 512) {
      wt_write(wf, wt, tid);             // wt <- W(L+1) (regs loaded during L-1)
      if (L < 6) {
        const float* Wn2 = L==1?P.Wc1 : L==2?P.Wc2 : L==3?P.Wc3 :
                           L==4?P.W3 : P.W4;   // W(L+2)
        ld8(Wn2, wf, tid);               // latency hides under this layer's MFMA
      }
    }

#pragma unroll 1
    for (int tt = w; tt < 32; tt += NW) {
      const int i0 = tt * 16;
      v8s A0 = bfrag(hbf, i0 + c, qq*8);
      v8s A1 = bfrag(hbf, i0 + c, 32 + qq*8);
#pragma unroll
      for (int n = 0; n < 4; ++n) {
        v4f acc = {0.f, 0.f, 0.f, 0.f};
        acc = __builtin_amdgcn_mfma_f32_16x16x32_bf16(A0, B0[n], acc, 0, 0, 0);
        acc = __builtin_amdgcn_mfma_f32_16x16x32_bf16(A1, B1[n], acc, 0, 0, 0);
        if (isconv) {
#pragma unroll
          for (int r = 0; r < 4; ++r)
            pbf[(i0 + qq*4 + r)*SBF + n*16 + c] = (unsigned short)f2bf(acc[r]);
        } else {
#pragma unroll
          for (int r = 0; r < 4; ++r) {
            float v = acc[r] + br[n];
            v = v >= 0.f ? v : ar[n]*v;
            hbf[(i0 + qq*4 + r)*SBF + n*16 + c] = (unsigned short)f2bf(v);
          }
        }
      }
    }
    __syncthreads();                     // C(L): p/h stable + wt(L+1) ready

    if (isconv) {
      // wave-cooperative gather: 8 lanes serve one row; bank classes
      // (nbr+s) mod 8 exactly balanced for any nbr values.
      // Per-feat accumulation order: own, +6*b, nbr0..nbr5.
      const int s = tid & 7;                 // b128 chunk (8 feats)
      const float* bls = bl + 8*s;
      float4 bv0 = *(const float4*)(bls);
      float4 bv1 = *(const float4*)(bls + 4);
#pragma unroll 1
      for (int r = tid >> 3; r < NNODE; r += NT/8) {
        const unsigned short* nb = &nbrs[r*KNN];
        uint4 own = *(const uint4*)&hbf[r*SBF + 8*s];
        v2f a0 = up2(own.x), a1 = up2(own.y), a2 = up2(own.z), a3 = up2(own.w);
        v2f t;
        t.x = bv0.x; t.y = bv0.y; a0 += 6.f*t;
        t.x = bv0.z; t.y = bv0.w; a1 += 6.f*t;
        t.x = bv1.x; t.y = bv1.y; a2 += 6.f*t;
        t.x = bv1.z; t.y = bv1.w; a3 += 6.f*t;
#pragma unroll
        for (int mm = 0; mm < KNN; ++mm) {
          int nbr = nb[mm];
          uint4 p = *(const uint4*)&pbf[nbr*SBF + 8*s];
          a0 += up2(p.x); a1 += up2(p.y); a2 += up2(p.z); a3 += up2(p.w);
        }
        uint4 o;
        o.x = f2bf(a0.x) | (f2bf(a0.y) << 16);
        o.y = f2bf(a1.x) | (f2bf(a1.y) << 16);
        o.z = f2bf(a2.x) | (f2bf(a2.y) << 16);
        o.w = f2bf(a3.x) | (f2bf(a3.y) << 16);
        *(uint4*)&hbf[r*SBF + 8*s] = o;
      }
      // writes guarded by next layer's B(L+1) barrier before any hbf read
    }
  }

  // ==== L7 peeled: MFMA + bias/PReLU + REGISTER pooling ====
  // wt holds W4 (L6's wt_write, guarded by C(6)). No B(7) barrier needed.
  {
    v8s B0[4], B1[4];
#pragma unroll
    for (int n = 0; n < 4; ++n) {
      B0[n] = bfrag(wt, n*16 + c, qq*8);
      B1[n] = bfrag(wt, n*16 + c, 32 + qq*8);
    }
    float br[4], ar[4];
#pragma unroll
    for (int n = 0; n < 4; ++n) { br[n] = P.b4[n*16 + c]; ar[n] = P.a4[n*16 + c]; }

    float ps[4] = {0.f, 0.f, 0.f, 0.f};   // pool partial for col n*16+c
#pragma unroll 1
    for (int tt = w; tt < 32; tt += NW) {
      const int i0 = tt * 16;
      v8s A0 = bfrag(hbf, i0 + c, qq*8);
      v8s A1 = bfrag(hbf, i0 + c, 32 + qq*8);
#pragma unroll
      for (int n = 0; n < 4; ++n) {
        v4f acc = {0.f, 0.f, 0.f, 0.f};
        acc = __builtin_amdgcn_mfma_f32_16x16x32_bf16(A0, B0[n], acc, 0, 0, 0);
        acc = __builtin_amdgcn_mfma_f32_16x16x32_bf16(A1, B1[n], acc, 0, 0, 0);
#pragma unroll
        for (int r = 0; r < 4; ++r) {
          float v = acc[r] + br[n];
          v = v >= 0.f ? v : ar[n]*v;
          ps[n] += v;                    // sum over this tile's 4 qq-rows
        }
      }
    }
    // sum the 4 qq-groups (rows) per column: col index c invariant under ^16/^32
#pragma unroll
    for (int n = 0; n < 4; ++n) {
      ps[n] += __shfl_xor(ps[n], 16);
      ps[n] += __shfl_xor(ps[n], 32);
    }
    if (lane < 16) {
#pragma unroll
      for (int n = 0; n < 4; ++n) lds[POOLP + w*64 + n*16 + c] = ps[n];
    }
  }
  __syncthreads();   // all wave partials published

  if (tid < 64) {
    float pool = 0.f;
#pragma unroll
    for (int cc = 0; cc < NW; ++cc) pool += lds[POOLP + cc*64 + tid];
    lds[POOLED + tid] = pool;
  }
  __syncthreads();

  // ---- head MLP (fp32) ----
  if (tid < 256) {
    float acc = P.bh1[tid];
#pragma unroll 4
    for (int k = 0; k < 64; ++k) acc = fmaf(lds[POOLED+k], P.Wh1[k*256 + tid], acc);
    lds[Y1OFF + tid] = acc >= 0.f ? acc : 0.2f*acc;
  }
  __syncthreads();
  // Wh2 (256x256): split-k x2 over 512 threads, partials in POOLP scratch
  if (tid < 512) {
    int o = tid & 255, hh = tid >> 8;
    float acc = hh ? 0.f : P.bh2[o];
    const int k0 = hh * 128;
#pragma unroll 4
    for (int k = k0; k < k0 + 128; ++k) acc = fmaf(lds[Y1OFF+k], P.Wh2[k*256 + o], acc);
    lds[POOLP + hh*256 + o] = acc;
  }
  __syncthreads();
  if (tid < 256) {
    float acc = lds[POOLP + tid] + lds[POOLP + 256 + tid];
    lds[Y2OFF + tid] = acc >= 0.f ? acc : 0.2f*acc;
  }
  __syncthreads();
  // Wh3 (256x64): split-k x4 over 256 threads
  if (tid < 256) {
    int o = tid & 63, hh = tid >> 6;
    float acc = 0.f;
    const int k0 = hh * 64;
#pragma unroll 4
    for (int k = k0; k < k0 + 64; ++k) acc = fmaf(lds[Y2OFF+k], P.Wh3[k*64 + o], acc);
    lds[POOLP + hh*64 + o] = acc;
  }
  __syncthreads();
  // y3 + Wh4 dot: fused in wave 0 (shuffle reduce, no extra barrier)
  if (tid < 64) {
    float acc = P.bh3[tid] + lds[POOLP + tid] + lds[POOLP + 64 + tid]
              + lds[POOLP + 128 + tid] + lds[POOLP + 192 + tid];
    float y3 = acc >= 0.f ? acc : 0.2f*acc;
    float v = y3 * P.Wh4[tid];
#pragma unroll
    for (int off = 32; off >= 1; off >>= 1) v += __shfl_down(v, off);
    if (tid == 0) P.out[g] = v + P.bh4[0];
  }
}

extern "C" void kernel_launch(void* const* d_in, const int* in_sizes, int n_in,
                              void* d_out, int out_size, void* d_ws, size_t ws_size,
                              hipStream_t stream) {
  Params P;
  P.x   = (const float*)d_in[0];
  P.W1  = (const float*)d_in[1];  P.b1  = (const float*)d_in[2];  P.a1 = (const float*)d_in[3];
  P.W2  = (const float*)d_in[4];  P.b2  = (const float*)d_in[5];  P.a2 = (const float*)d_in[6];
  P.Wc0 = (const float*)d_in[7];  P.bc0 = (const float*)d_in[8];
  P.Wc1 = (const float*)d_in[9];  P.bc1 = (const float*)d_in[10];
  P.Wc2 = (const float*)d_in[11]; P.bc2 = (const float*)d_in[12];
  P.Wc3 = (const float*)d_in[13]; P.bc3 = (const float*)d_in[14];
  P.W3  = (const float*)d_in[15]; P.b3  = (const float*)d_in[16]; P.a3 = (const float*)d_in[17];
  P.W4  = (const float*)d_in[18]; P.b4  = (const float*)d_in[19]; P.a4 = (const float*)d_in[20];
  P.Wh1 = (const float*)d_in[21]; P.bh1 = (const float*)d_in[22];
  P.Wh2 = (const float*)d_in[23]; P.bh2 = (const float*)d_in[24];
  P.Wh3 = (const float*)d_in[25]; P.bh3 = (const float*)d_in[26];
  P.Wh4 = (const float*)d_in[27]; P.bh4 = (const float*)d_in[28];
  P.out = (float*)d_out;

  (void)hipFuncSetAttribute(reinterpret_cast<const void*>(fused_gnn),
                            hipFuncAttributeMaxDynamicSharedMemorySize, LDS_BYTES);

  fused_gnn<<<NGRAPH, NT, LDS_BYTES, stream>>>(P);
}

// Round 14
// 286.986 us; speedup vs baseline: 1.2170x; 1.0219x over previous
//
#include <hip/hip_runtime.h>

#define NGRAPH 256
#define NNODE  512
#define KNN    6
#define NCAND  12
#define NF     64
#define SBF    72                 // bf16 row stride in shorts (144 B, 16B-aligned)
#define NT     768                // 12 waves (R4/R8-proven best; NT=1024 regressed: R7)
#define NW     12                 // waves per block
// LDS layout (float indices):
#define PBF    18432              // hbf = 512*72 shorts = 73728 B at [0,PBF)
                                  // pbf = 512*72 shorts at [PBF, 36864)
#define CANDO  PBF                // cand: 512*12 ushort = 3072 floats (dead before convs)
#define SQO    (PBF + 3072)       // 512 floats (bf16 sq, then exact sq; dead before convs)
#define WTO    36864              // Wt bf16: 64*72 shorts = 2304 floats
#define NBRO   39168              // nbr lists: 512*6 ushort = 3072 shorts = 1536 FLOATS
#define LDS_FLOATS 40704          // 39168 + 1536
#define LDS_BYTES  (LDS_FLOATS*4) // 162816 B <= 163840 B (160 KiB)
// pool/head scratch (pbf region, dead after last conv gather):
#define POOLP  PBF                // 12 waves x 64 pool partials; also Wh2/Wh3 split-k scratch
#define POOLED (PBF + 1024)
#define Y1OFF  (PBF + 1088)
#define Y2OFF  (PBF + 1344)
#define BIG 1e30f

typedef float v4f __attribute__((ext_vector_type(4)));
typedef float v2f __attribute__((ext_vector_type(2)));
typedef short v8s __attribute__((ext_vector_type(8)));

struct Params {
  const float *x;
  const float *W1,*b1,*a1, *W2,*b2,*a2;
  const float *Wc0,*bc0, *Wc1,*bc1, *Wc2,*bc2, *Wc3,*bc3;
  const float *W3,*b3,*a3, *W4,*b4,*a4;
  const float *Wh1,*bh1, *Wh2,*bh2, *Wh3,*bh3, *Wh4,*bh4;
  float *out;
};

// fp32 -> bf16 (RNE) as raw 16-bit
__device__ __forceinline__ unsigned f2bf(float x) {
  union { float f; unsigned u; } cc; cc.f = x;
  unsigned u = cc.u;
  return (u + 0x7FFFu + ((u >> 16) & 1u)) >> 16;
}
__device__ __forceinline__ float bflo(unsigned u) {
  union { unsigned u; float f; } c; c.u = u << 16; return c.f;
}
__device__ __forceinline__ float bfhi(unsigned u) {
  union { unsigned u; float f; } c; c.u = u & 0xffff0000u; return c.f;
}
// bf16 pair -> packed float2 (enables v_pk_add_f32 accumulation)
__device__ __forceinline__ v2f up2(unsigned u) {
  v2f r; r.x = bflo(u); r.y = bfhi(u); return r;
}

__device__ __forceinline__ v8s bfrag(const unsigned short* base, int row, int c0) {
  return *(const v8s*)(base + row*SBF + c0);
}

// pack filter-e with its index in the low 9 mantissa bits (|perturb| << bf16 noise;
// candidate SET is all that matters — exact fp32 re-rank decides final order)
__device__ __forceinline__ float packe(float e, int j) {
  return __uint_as_float((__float_as_uint(e) & 0xFFFFFE00u) | (unsigned)j);
}

// sorted-ascending insert via min/max propagation (2 inst/stage)
__device__ __forceinline__ void ins8(float (&b)[8], float v) {
  if (v < b[7]) {
#pragma unroll
    for (int p = 0; p < 8; ++p) {
      float lo = fminf(b[p], v);
      v = fmaxf(b[p], v);
      b[p] = lo;
    }
  }
}
__device__ __forceinline__ void ins12(float (&b)[NCAND], float v) {
  if (v < b[NCAND-1]) {
#pragma unroll
    for (int p = 0; p < NCAND; ++p) {
      float lo = fminf(b[p], v);
      v = fmaxf(b[p], v);
      b[p] = lo;
    }
  }
}

// T14 split Wt staging: issue the 8 strided loads EARLY, write LATE.
__device__ __forceinline__ void ld8(const float* W, float (&wf)[8], int tid) {
  const int col = tid >> 3, ks = (tid & 7) * 8;
  const float* wp = W + col;
#pragma unroll
  for (int i = 0; i < 8; ++i) wf[i] = wp[(ks + i) * NF];
}
__device__ __forceinline__ void wt_write(const float (&wf)[8], unsigned short* wt, int tid) {
  const int col = tid >> 3, ks = (tid & 7) * 8;
  unsigned d[4];
#pragma unroll
  for (int i = 0; i < 4; ++i)
    d[i] = f2bf(wf[2*i]) | (f2bf(wf[2*i+1]) << 16);
  *(uint4*)&wt[col*SBF + ks] = make_uint4(d[0], d[1], d[2], d[3]);
}

// Multi-tile filter: one wave processes NTILE output tiles simultaneously.
// B-fragments and sq vector are SHARED across tiles; the NTILE independent
// insert chains interleave -> hides the serial min/max latency.
template<int NTILE>
__device__ __forceinline__ void filter_tiles(const unsigned short* hbf,
                                             const float* ldsf,
                                             unsigned short* cand,
                                             const int (&tts)[NTILE],
                                             int lane, int c, int qq) {
  v8s A0[NTILE], A1[NTILE];
  float d8[NTILE][8];
  int i0[NTILE];
#pragma unroll
  for (int k = 0; k < NTILE; ++k) {
    i0[k] = tts[k] * 16;
    A0[k] = bfrag(hbf, i0[k] + c, qq*8);
    A1[k] = bfrag(hbf, i0[k] + c, 32 + qq*8);
#pragma unroll
    for (int m = 0; m < 8; ++m) d8[k][m] = BIG;
  }
#pragma unroll 1
  for (int jt = 0; jt < 32; ++jt) {
    const int j0 = jt * 16;
    v8s B0 = bfrag(hbf, j0 + c, qq*8);
    v8s B1 = bfrag(hbf, j0 + c, 32 + qq*8);
    float4 sv = *(const float4*)&ldsf[SQO + j0 + qq*4];
    const int jb = j0 + qq*4;
#pragma unroll
    for (int k = 0; k < NTILE; ++k) {
      v4f acc = {0.f, 0.f, 0.f, 0.f};
      acc = __builtin_amdgcn_mfma_f32_16x16x32_bf16(B0, A0[k], acc, 0, 0, 0);
      acc = __builtin_amdgcn_mfma_f32_16x16x32_bf16(B1, A1[k], acc, 0, 0, 0);
      float e0 = fmaf(-2.f, acc[0], sv.x);
      float e1 = fmaf(-2.f, acc[1], sv.y);
      float e2 = fmaf(-2.f, acc[2], sv.z);
      float e3 = fmaf(-2.f, acc[3], sv.w);
      if (jt == tts[k]) {               // self-exclusion tile (wave-uniform)
        const int myrow = i0[k] + c;
        if (jb     == myrow) e0 = BIG;
        if (jb + 1 == myrow) e1 = BIG;
        if (jb + 2 == myrow) e2 = BIG;
        if (jb + 3 == myrow) e3 = BIG;
      }
      ins8(d8[k], packe(e0, jb));
      ins8(d8[k], packe(e1, jb+1));
      ins8(d8[k], packe(e2, jb+2));
      ins8(d8[k], packe(e3, jb+3));
    }
  }
  // merge the 4 qq-lanes per row: 2 butterfly stages, capacity 12 (per tile)
#pragma unroll
  for (int k = 0; k < NTILE; ++k) {
    float cd[NCAND];
#pragma unroll
    for (int m = 0; m < 8; ++m) cd[m] = d8[k][m];
#pragma unroll
    for (int m = 8; m < NCAND; ++m) cd[m] = BIG;
    {
      float pd[8];
#pragma unroll
      for (int s = 0; s < 8; ++s) pd[s] = __shfl_xor(cd[s], 16);
#pragma unroll
      for (int s = 0; s < 8; ++s) ins12(cd, pd[s]);
    }
    {
      float pd[NCAND];
#pragma unroll
      for (int s = 0; s < NCAND; ++s) pd[s] = __shfl_xor(cd[s], 32);
#pragma unroll
      for (int s = 0; s < NCAND; ++s) ins12(cd, pd[s]);
    }
    if (lane < 16) {
#pragma unroll
      for (int s = 0; s < NCAND; ++s)
        cand[(i0[k] + lane)*NCAND + s] =
          (unsigned short)(__float_as_uint(cd[s]) & 0x1FFu);
    }
  }
}

__global__ __launch_bounds__(NT) void fused_gnn(Params P) {
  extern __shared__ float lds[];
  unsigned short* hbf  = (unsigned short*)lds;
  unsigned short* pbf  = (unsigned short*)&lds[PBF];
  unsigned short* wt   = (unsigned short*)&lds[WTO];
  unsigned short* cand = (unsigned short*)&lds[CANDO];
  unsigned short* nbrs = (unsigned short*)&lds[NBRO];
  const int tid  = threadIdx.x;
  const int g    = blockIdx.x;
  const int rA   = tid;                  // row ownership for tid<512
  const int lane = tid & 63;
  const int w    = tid >> 6;             // wave 0..11
  const int c    = lane & 15;
  const int qq   = lane >> 4;            // 0..3

  const float* xgp = P.x + (size_t)g * NNODE * NF;
  const float4* xg = (const float4*)xgp;

  // ---- stage x[g] as bf16 into hbf ----
#pragma unroll 1
  for (int i = tid; i < NNODE*NF/4; i += NT) {
    float4 v = xg[i];
    int row = i >> 4, k4 = i & 15;
    unsigned lo = f2bf(v.x) | (f2bf(v.y) << 16);
    unsigned hi = f2bf(v.z) | (f2bf(v.w) << 16);
    *(uint2*)&hbf[row*SBF + 4*k4] = make_uint2(lo, hi);
  }
  __syncthreads();

  // ---- filter sq from bf16 values (b128 row reads) ----
  if (tid < 512) {
    const uint4* xr = (const uint4*)(hbf + rA*SBF);
    float s = 0.f;
#pragma unroll
    for (int k = 0; k < 8; ++k) {
      uint4 u = xr[k];
      float f;
      f = bflo(u.x); s = fmaf(f, f, s); f = bfhi(u.x); s = fmaf(f, f, s);
      f = bflo(u.y); s = fmaf(f, f, s); f = bfhi(u.y); s = fmaf(f, f, s);
      f = bflo(u.z); s = fmaf(f, f, s); f = bfhi(u.z); s = fmaf(f, f, s);
      f = bflo(u.w); s = fmaf(f, f, s); f = bfhi(u.w); s = fmaf(f, f, s);
    }
    lds[SQO + rA] = s;
  }
  __syncthreads();

  // ==== kNN filter: MFMA Gram, multi-tile per wave ====
  // W1 loads issued BEFORE the filter -> ~500cy L2 latency hides under it.
  float wf[8];
  if (tid < 512) ld8(P.W1, wf, tid);
  // tile cover: w<8 -> {w, w+8, w+16} (0..23); w>=8 -> {w+16, w+20} (24..31)
  if (w < 8) {
    int tts[3] = {w, w + 8, w + 16};
    filter_tiles<3>(hbf, lds, cand, tts, lane, c, qq);
  } else {
    int tts[2] = {w + 16, w + 20};
    filter_tiles<2>(hbf, lds, cand, tts, lane, c, qq);
  }
  if (tid < 512) wt_write(wf, wt, tid);   // wt <- W1 (loads long since landed)
  __syncthreads();   // filter done; SQO reusable; wt=W1 visible

  // ==== exact fp32 refine sq (waves 0-7) ∥ L0 frag pre-read (waves 8-11) ====
  float4 xr16[16];
  v8s LB0[4], LB1[4];
  float lbr[4], lar[4];
  if (tid < 512) {
    const float4* xrow = (const float4*)(xgp + rA*NF);
#pragma unroll
    for (int k4 = 0; k4 < 16; ++k4) xr16[k4] = xrow[k4];
    float s0 = 0.f;
#pragma unroll
    for (int k4 = 0; k4 < 16; ++k4) {
      float4 a = xr16[k4];
      s0 = fmaf(a.x,a.x,s0); s0 = fmaf(a.y,a.y,s0); s0 = fmaf(a.z,a.z,s0); s0 = fmaf(a.w,a.w,s0);
    }
    lds[SQO + rA] = s0;
  } else {
    // waves 8-11: pre-read L0 B-frags (wt=W1, stable across the next barrier)
#pragma unroll
    for (int n = 0; n < 4; ++n) {
      LB0[n] = bfrag(wt, n*16 + c, qq*8);
      LB1[n] = bfrag(wt, n*16 + c, 32 + qq*8);
      lbr[n] = P.b1[n*16 + c];
      lar[n] = P.a1[n*16 + c];
    }
  }
  __syncthreads();   // exact sq published

  // ==== SPLIT: refine (waves 0-7) ∥ L0 dense GEMM (waves 8-11) ====
  // Disjoint: refine reads global x/cand/SQO, writes nbrs; L0 reads hbf/wt(regs),
  // writes hbf in place (disjoint tile rows). wt(W1) reads completed pre-barrier,
  // so the refine tail's wt_write(W2) cannot race.
  if (tid < 512) {
    float nd[6]; int ni[6];
#pragma unroll
    for (int m = 0; m < 6; ++m) { nd[m] = BIG; ni[m] = 0x7fffffff; }
    int cnd[NCAND];
#pragma unroll
    for (int s = 0; s < NCAND; ++s) cnd[s] = cand[rA*NCAND + s];

#pragma unroll 2
    for (int s = 0; s < NCAND; ++s) {
      int j = cnd[s];
      const float4* xj = (const float4*)(xgp + j*NF);
      float4 aa = {0.f, 0.f, 0.f, 0.f};
#pragma unroll
      for (int k4 = 0; k4 < 16; ++k4) {
        float4 v = xj[k4];
        aa.x = fmaf(xr16[k4].x, v.x, aa.x); aa.y = fmaf(xr16[k4].y, v.y, aa.y);
        aa.z = fmaf(xr16[k4].z, v.z, aa.z); aa.w = fmaf(xr16[k4].w, v.w, aa.w);
      }
      float e = fmaf(-2.f, (aa.x+aa.y)+(aa.z+aa.w), lds[SQO + j]);
      if (e < nd[5] || (e == nd[5] && j < ni[5])) {
#pragma unroll
        for (int pp = 0; pp < 6; ++pp) {
          bool lt = (e < nd[pp]) || (e == nd[pp] && j < ni[pp]);
          float tb2 = nd[pp]; int ti = ni[pp];
          nd[pp] = lt ? e : tb2;  ni[pp] = lt ? j : ti;
          e      = lt ? tb2 : e;  j      = lt ? ti : j;
        }
      }
    }
#pragma unroll
    for (int m = 0; m < 6; ++m) nbrs[rA*KNN + m] = (unsigned short)ni[m];
    // pipeline tail: wt <- W2 (L1), preload Wc0 (L2)
    ld8(P.W2, wf, tid);
    wt_write(wf, wt, tid);
    ld8(P.Wc0, wf, tid);
  } else {
    // L0 dense on waves 8-11: 8 tiles each, in-place h = prelu(x@W1+b1)
#pragma unroll 1
    for (int tt = w - 8; tt < 32; tt += 4) {
      const int i0 = tt * 16;
      v8s A0 = bfrag(hbf, i0 + c, qq*8);
      v8s A1 = bfrag(hbf, i0 + c, 32 + qq*8);
#pragma unroll
      for (int n = 0; n < 4; ++n) {
        v4f acc = {0.f, 0.f, 0.f, 0.f};
        acc = __builtin_amdgcn_mfma_f32_16x16x32_bf16(A0, LB0[n], acc, 0, 0, 0);
        acc = __builtin_amdgcn_mfma_f32_16x16x32_bf16(A1, LB1[n], acc, 0, 0, 0);
#pragma unroll
        for (int r = 0; r < 4; ++r) {
          float v = acc[r] + lbr[n];
          v = v >= 0.f ? v : lar[n]*v;
          hbf[(i0 + qq*4 + r)*SBF + n*16 + c] = (unsigned short)f2bf(v);
        }
      }
    }
  }
  __syncthreads();   // join: nbrs + h(L0) + wt(W2) all ready

  // ==== layers 1..6: bf16 MFMA GEMMs, 2 barriers/layer, pipelined Wt ====
#pragma unroll 1
  for (int L = 1; L < 7; ++L) {
    const bool isconv = (L >= 2 && L <= 5);
    const float* bl = L==1?P.b2 : L==2?P.bc0 : L==3?P.bc1 :
                      L==4?P.bc2 : L==5?P.bc3 : P.b3;
    const float* al = L==1?P.a2 : P.a3;   // read only at L==1, L==6

    // B fragments + bias from current wt (written before the last barrier)
    v8s B0[4], B1[4];
#pragma unroll
    for (int n = 0; n < 4; ++n) {
      B0[n] = bfrag(wt, n*16 + c, qq*8);
      B1[n] = bfrag(wt, n*16 + c, 32 + qq*8);
    }
    float br[4], ar[4];
    if (!isconv) {
#pragma unroll
      for (int n = 0; n < 4; ++n) { br[n] = bl[n*16 + c]; ar[n] = al[n*16 + c]; }
    }
    __syncthreads();                     // B(L): all frags secured; wt reusable

    if (tid < 512) {
      wt_write(wf, wt, tid);             // wt <- W(L+1) (regs loaded during L-1)
      if (L < 6) {
        const float* Wn2 = L==1?P.Wc1 : L==2?P.Wc2 : L==3?P.Wc3 :
                           L==4?P.W3 : P.W4;   // W(L+2)
        ld8(Wn2, wf, tid);               // latency hides under this layer's MFMA
      }
    }

#pragma unroll 1
    for (int tt = w; tt < 32; tt += NW) {
      const int i0 = tt * 16;
      v8s A0 = bfrag(hbf, i0 + c, qq*8);
      v8s A1 = bfrag(hbf, i0 + c, 32 + qq*8);
#pragma unroll
      for (int n = 0; n < 4; ++n) {
        v4f acc = {0.f, 0.f, 0.f, 0.f};
        acc = __builtin_amdgcn_mfma_f32_16x16x32_bf16(A0, B0[n], acc, 0, 0, 0);
        acc = __builtin_amdgcn_mfma_f32_16x16x32_bf16(A1, B1[n], acc, 0, 0, 0);
        if (isconv) {
#pragma unroll
          for (int r = 0; r < 4; ++r)
            pbf[(i0 + qq*4 + r)*SBF + n*16 + c] = (unsigned short)f2bf(acc[r]);
        } else {
#pragma unroll
          for (int r = 0; r < 4; ++r) {
            float v = acc[r] + br[n];
            v = v >= 0.f ? v : ar[n]*v;
            hbf[(i0 + qq*4 + r)*SBF + n*16 + c] = (unsigned short)f2bf(v);
          }
        }
      }
    }
    __syncthreads();                     // C(L): p/h stable + wt(L+1) ready

    if (isconv) {
      // wave-cooperative gather: 8 lanes serve one row; bank classes
      // (nbr+s) mod 8 exactly balanced for any nbr values.
      // Per-feat accumulation order: own, +6*b, nbr0..nbr5.
      const int s = tid & 7;                 // b128 chunk (8 feats)
      const float* bls = bl + 8*s;
      float4 bv0 = *(const float4*)(bls);
      float4 bv1 = *(const float4*)(bls + 4);
#pragma unroll 1
      for (int r = tid >> 3; r < NNODE; r += NT/8) {
        // nbr list as 3 x u32 (12B, always 4B-aligned): halves index reads
        const unsigned* nb32 = (const unsigned*)&nbrs[r*KNN];
        unsigned n01 = nb32[0], n23 = nb32[1], n45 = nb32[2];
        uint4 own = *(const uint4*)&hbf[r*SBF + 8*s];
        v2f a0 = up2(own.x), a1 = up2(own.y), a2 = up2(own.z), a3 = up2(own.w);
        v2f t;
        t.x = bv0.x; t.y = bv0.y; a0 += 6.f*t;
        t.x = bv0.z; t.y = bv0.w; a1 += 6.f*t;
        t.x = bv1.x; t.y = bv1.y; a2 += 6.f*t;
        t.x = bv1.z; t.y = bv1.w; a3 += 6.f*t;
        int nbr_[6];
        nbr_[0] = n01 & 0xffff; nbr_[1] = n01 >> 16;
        nbr_[2] = n23 & 0xffff; nbr_[3] = n23 >> 16;
        nbr_[4] = n45 & 0xffff; nbr_[5] = n45 >> 16;
#pragma unroll
        for (int mm = 0; mm < KNN; ++mm) {
          uint4 p = *(const uint4*)&pbf[nbr_[mm]*SBF + 8*s];
          a0 += up2(p.x); a1 += up2(p.y); a2 += up2(p.z); a3 += up2(p.w);
        }
        uint4 o;
        o.x = f2bf(a0.x) | (f2bf(a0.y) << 16);
        o.y = f2bf(a1.x) | (f2bf(a1.y) << 16);
        o.z = f2bf(a2.x) | (f2bf(a2.y) << 16);
        o.w = f2bf(a3.x) | (f2bf(a3.y) << 16);
        *(uint4*)&hbf[r*SBF + 8*s] = o;
      }
      // writes guarded by next layer's B(L+1) barrier before any hbf read
    }
  }

  // ==== L7 peeled: MFMA + bias/PReLU + REGISTER pooling ====
  // wt holds W4 (L6's wt_write, guarded by C(6)). No B(7) barrier needed.
  {
    v8s B0[4], B1[4];
#pragma unroll
    for (int n = 0; n < 4; ++n) {
      B0[n] = bfrag(wt, n*16 + c, qq*8);
      B1[n] = bfrag(wt, n*16 + c, 32 + qq*8);
    }
    float br[4], ar[4];
#pragma unroll
    for (int n = 0; n < 4; ++n) { br[n] = P.b4[n*16 + c]; ar[n] = P.a4[n*16 + c]; }

    float ps[4] = {0.f, 0.f, 0.f, 0.f};   // pool partial for col n*16+c
#pragma unroll 1
    for (int tt = w; tt < 32; tt += NW) {
      const int i0 = tt * 16;
      v8s A0 = bfrag(hbf, i0 + c, qq*8);
      v8s A1 = bfrag(hbf, i0 + c, 32 + qq*8);
#pragma unroll
      for (int n = 0; n < 4; ++n) {
        v4f acc = {0.f, 0.f, 0.f, 0.f};
        acc = __builtin_amdgcn_mfma_f32_16x16x32_bf16(A0, B0[n], acc, 0, 0, 0);
        acc = __builtin_amdgcn_mfma_f32_16x16x32_bf16(A1, B1[n], acc, 0, 0, 0);
#pragma unroll
        for (int r = 0; r < 4; ++r) {
          float v = acc[r] + br[n];
          v = v >= 0.f ? v : ar[n]*v;
          ps[n] += v;                    // sum over this tile's 4 qq-rows
        }
      }
    }
    // sum the 4 qq-groups (rows) per column: col index c invariant under ^16/^32
#pragma unroll
    for (int n = 0; n < 4; ++n) {
      ps[n] += __shfl_xor(ps[n], 16);
      ps[n] += __shfl_xor(ps[n], 32);
    }
    if (lane < 16) {
#pragma unroll
      for (int n = 0; n < 4; ++n) lds[POOLP + w*64 + n*16 + c] = ps[n];
    }
  }
  __syncthreads();   // all wave partials published

  if (tid < 64) {
    // 12 partials folded with two independent chains (latency-bound phase)
    float p0 = 0.f, p1 = 0.f;
#pragma unroll
    for (int cc = 0; cc < NW; cc += 2) {
      p0 += lds[POOLP + cc*64 + tid];
      p1 += lds[POOLP + (cc+1)*64 + tid];
    }
    lds[POOLED + tid] = p0 + p1;
  }
  __syncthreads();

  // ---- head MLP (fp32, dual-accumulator chains) ----
  if (tid < 256) {
    float a0 = P.bh1[tid], a1 = 0.f;
#pragma unroll 4
    for (int k = 0; k < 64; k += 2) {
      a0 = fmaf(lds[POOLED+k],   P.Wh1[k*256 + tid],     a0);
      a1 = fmaf(lds[POOLED+k+1], P.Wh1[(k+1)*256 + tid], a1);
    }
    float acc = a0 + a1;
    lds[Y1OFF + tid] = acc >= 0.f ? acc : 0.2f*acc;
  }
  __syncthreads();
  // Wh2 (256x256): split-k x2 over 512 threads, partials in POOLP scratch
  if (tid < 512) {
    int o = tid & 255, hh = tid >> 8;
    float a0 = hh ? 0.f : P.bh2[o], a1 = 0.f;
    const int k0 = hh * 128;
#pragma unroll 4
    for (int k = k0; k < k0 + 128; k += 2) {
      a0 = fmaf(lds[Y1OFF+k],   P.Wh2[k*256 + o],     a0);
      a1 = fmaf(lds[Y1OFF+k+1], P.Wh2[(k+1)*256 + o], a1);
    }
    lds[POOLP + hh*256 + o] = a0 + a1;
  }
  __syncthreads();
  if (tid < 256) {
    float acc = lds[POOLP + tid] + lds[POOLP + 256 + tid];
    lds[Y2OFF + tid] = acc >= 0.f ? acc : 0.2f*acc;
  }
  __syncthreads();
  // Wh3 (256x64): split-k x4 over 256 threads
  if (tid < 256) {
    int o = tid & 63, hh = tid >> 6;
    float a0 = 0.f, a1 = 0.f;
    const int k0 = hh * 64;
#pragma unroll 4
    for (int k = k0; k < k0 + 64; k += 2) {
      a0 = fmaf(lds[Y2OFF+k],   P.Wh3[k*64 + o],     a0);
      a1 = fmaf(lds[Y2OFF+k+1], P.Wh3[(k+1)*64 + o], a1);
    }
    lds[POOLP + hh*64 + o] = a0 + a1;
  }
  __syncthreads();
  // y3 + Wh4 dot: fused in wave 0 (shuffle reduce, no extra barrier)
  if (tid < 64) {
    float acc = P.bh3[tid] + lds[POOLP + tid] + lds[POOLP + 64 + tid]
              + lds[POOLP + 128 + tid] + lds[POOLP + 192 + tid];
    float y3 = acc >= 0.f ? acc : 0.2f*acc;
    float v = y3 * P.Wh4[tid];
#pragma unroll
    for (int off = 32; off >= 1; off >>= 1) v += __shfl_down(v, off);
    if (tid == 0) P.out[g] = v + P.bh4[0];
  }
}

extern "C" void kernel_launch(void* const* d_in, const int* in_sizes, int n_in,
                              void* d_out, int out_size, void* d_ws, size_t ws_size,
                              hipStream_t stream) {
  Params P;
  P.x   = (const float*)d_in[0];
  P.W1  = (const float*)d_in[1];  P.b1  = (const float*)d_in[2];  P.a1 = (const float*)d_in[3];
  P.W2  = (const float*)d_in[4];  P.b2  = (const float*)d_in[5];  P.a2 = (const float*)d_in[6];
  P.Wc0 = (const float*)d_in[7];  P.bc0 = (const float*)d_in[8];
  P.Wc1 = (const float*)d_in[9];  P.bc1 = (const float*)d_in[10];
  P.Wc2 = (const float*)d_in[11]; P.bc2 = (const float*)d_in[12];
  P.Wc3 = (const float*)d_in[13]; P.bc3 = (const float*)d_in[14];
  P.W3  = (const float*)d_in[15]; P.b3  = (const float*)d_in[16]; P.a3 = (const float*)d_in[17];
  P.W4  = (const float*)d_in[18]; P.b4  = (const float*)d_in[19]; P.a4 = (const float*)d_in[20];
  P.Wh1 = (const float*)d_in[21]; P.bh1 = (const float*)d_in[22];
  P.Wh2 = (const float*)d_in[23]; P.bh2 = (const float*)d_in[24];
  P.Wh3 = (const float*)d_in[25]; P.bh3 = (const float*)d_in[26];
  P.Wh4 = (const float*)d_in[27]; P.bh4 = (const float*)d_in[28];
  P.out = (float*)d_out;

  (void)hipFuncSetAttribute(reinterpret_cast<const void*>(fused_gnn),
                            hipFuncAttributeMaxDynamicSharedMemorySize, LDS_BYTES);

  fused_gnn<<<NGRAPH, NT, LDS_BYTES, stream>>>(P);
}

// Round 15
// 280.921 us; speedup vs baseline: 1.2433x; 1.0216x over previous
//
#include <hip/hip_runtime.h>

#define NGRAPH 256
#define NNODE  512
#define KNN    6
#define NCAND  12
#define NF     64
#define SBF    72                 // bf16 row stride in shorts (144 B, 16B-aligned)
#define NT     768                // 12 waves (R4/R8-proven best; NT=1024 regressed: R7)
#define NW     12                 // waves per block
// LDS layout (float indices):
#define PBF    18432              // hbf = 512*72 shorts = 73728 B at [0,PBF)
                                  // pbf = 512*72 shorts at [PBF, 36864)
#define CANDO  PBF                // cand: 512*12 ushort = 3072 floats (dead before convs)
#define SQO    (PBF + 3072)       // 512 floats (bf16 sq, then exact sq; dead before convs)
#define WTO    36864              // Wt bf16: 64*72 shorts = 2304 floats
#define NBRO   39168              // nbr lists: 512*6 ushort = 3072 shorts = 1536 FLOATS
#define LDS_FLOATS 40704          // 39168 + 1536
#define LDS_BYTES  (LDS_FLOATS*4) // 162816 B <= 163840 B (160 KiB)
// pool/head scratch (pbf region, dead after last conv gather):
#define POOLP  PBF                // 12 waves x 64 pool partials; also Wh2/Wh3 split-k scratch
#define POOLED (PBF + 1024)
#define Y1OFF  (PBF + 1088)
#define Y2OFF  (PBF + 1344)
#define BIG 1e30f

typedef float v4f __attribute__((ext_vector_type(4)));
typedef float v2f __attribute__((ext_vector_type(2)));
typedef short v8s __attribute__((ext_vector_type(8)));

struct Params {
  const float *x;
  const float *W1,*b1,*a1, *W2,*b2,*a2;
  const float *Wc0,*bc0, *Wc1,*bc1, *Wc2,*bc2, *Wc3,*bc3;
  const float *W3,*b3,*a3, *W4,*b4,*a4;
  const float *Wh1,*bh1, *Wh2,*bh2, *Wh3,*bh3, *Wh4,*bh4;
  float *out;
};

// HW packed f32->bf16 (RNE, same rounding as the old 4-op f2bf): 1 VALU op
// replaces ~9 (2x f2bf + or/shift). T12 recipe, gfx950-verified (m214v22).
__device__ __forceinline__ unsigned cvtpk(float a, float b) {
  unsigned r;
  asm("v_cvt_pk_bf16_f32 %0, %1, %2" : "=v"(r) : "v"(a), "v"(b));
  return r;
}
__device__ __forceinline__ unsigned short cvt1(float a) {
  return (unsigned short)cvtpk(a, a);
}
__device__ __forceinline__ float bflo(unsigned u) {
  union { unsigned u; float f; } c; c.u = u << 16; return c.f;
}
__device__ __forceinline__ float bfhi(unsigned u) {
  union { unsigned u; float f; } c; c.u = u & 0xffff0000u; return c.f;
}
// bf16 pair -> packed float2 (enables v_pk_add_f32 accumulation)
__device__ __forceinline__ v2f up2(unsigned u) {
  v2f r; r.x = bflo(u); r.y = bfhi(u); return r;
}

__device__ __forceinline__ v8s bfrag(const unsigned short* base, int row, int c0) {
  return *(const v8s*)(base + row*SBF + c0);
}

// pack filter-e with its index in the low 9 mantissa bits (|perturb| << bf16 noise;
// candidate SET is all that matters — exact fp32 re-rank decides final order)
__device__ __forceinline__ float packe(float e, int j) {
  return __uint_as_float((__float_as_uint(e) & 0xFFFFFE00u) | (unsigned)j);
}

// sorted-ascending insert via min/max propagation (2 inst/stage)
__device__ __forceinline__ void ins8(float (&b)[8], float v) {
  if (v < b[7]) {
#pragma unroll
    for (int p = 0; p < 8; ++p) {
      float lo = fminf(b[p], v);
      v = fmaxf(b[p], v);
      b[p] = lo;
    }
  }
}
__device__ __forceinline__ void ins12(float (&b)[NCAND], float v) {
  if (v < b[NCAND-1]) {
#pragma unroll
    for (int p = 0; p < NCAND; ++p) {
      float lo = fminf(b[p], v);
      v = fmaxf(b[p], v);
      b[p] = lo;
    }
  }
}

// T14 split Wt staging: issue the 8 strided loads EARLY, write LATE.
__device__ __forceinline__ void ld8(const float* W, float (&wf)[8], int tid) {
  const int col = tid >> 3, ks = (tid & 7) * 8;
  const float* wp = W + col;
#pragma unroll
  for (int i = 0; i < 8; ++i) wf[i] = wp[(ks + i) * NF];
}
__device__ __forceinline__ void wt_write(const float (&wf)[8], unsigned short* wt, int tid) {
  const int col = tid >> 3, ks = (tid & 7) * 8;
  unsigned d[4];
#pragma unroll
  for (int i = 0; i < 4; ++i)
    d[i] = cvtpk(wf[2*i], wf[2*i+1]);
  *(uint4*)&wt[col*SBF + ks] = make_uint4(d[0], d[1], d[2], d[3]);
}

// Multi-tile filter: one wave processes NTILE output tiles simultaneously.
// B-fragments and sq vector are SHARED across tiles; the NTILE independent
// insert chains interleave -> hides the serial min/max latency.
template<int NTILE>
__device__ __forceinline__ void filter_tiles(const unsigned short* hbf,
                                             const float* ldsf,
                                             unsigned short* cand,
                                             const int (&tts)[NTILE],
                                             int lane, int c, int qq) {
  v8s A0[NTILE], A1[NTILE];
  float d8[NTILE][8];
  int i0[NTILE];
#pragma unroll
  for (int k = 0; k < NTILE; ++k) {
    i0[k] = tts[k] * 16;
    A0[k] = bfrag(hbf, i0[k] + c, qq*8);
    A1[k] = bfrag(hbf, i0[k] + c, 32 + qq*8);
#pragma unroll
    for (int m = 0; m < 8; ++m) d8[k][m] = BIG;
  }
#pragma unroll 1
  for (int jt = 0; jt < 32; ++jt) {
    const int j0 = jt * 16;
    v8s B0 = bfrag(hbf, j0 + c, qq*8);
    v8s B1 = bfrag(hbf, j0 + c, 32 + qq*8);
    float4 sv = *(const float4*)&ldsf[SQO + j0 + qq*4];
    const int jb = j0 + qq*4;
#pragma unroll
    for (int k = 0; k < NTILE; ++k) {
      v4f acc = {0.f, 0.f, 0.f, 0.f};
      acc = __builtin_amdgcn_mfma_f32_16x16x32_bf16(B0, A0[k], acc, 0, 0, 0);
      acc = __builtin_amdgcn_mfma_f32_16x16x32_bf16(B1, A1[k], acc, 0, 0, 0);
      float e0 = fmaf(-2.f, acc[0], sv.x);
      float e1 = fmaf(-2.f, acc[1], sv.y);
      float e2 = fmaf(-2.f, acc[2], sv.z);
      float e3 = fmaf(-2.f, acc[3], sv.w);
      if (jt == tts[k]) {               // self-exclusion tile (wave-uniform)
        const int myrow = i0[k] + c;
        if (jb     == myrow) e0 = BIG;
        if (jb + 1 == myrow) e1 = BIG;
        if (jb + 2 == myrow) e2 = BIG;
        if (jb + 3 == myrow) e3 = BIG;
      }
      ins8(d8[k], packe(e0, jb));
      ins8(d8[k], packe(e1, jb+1));
      ins8(d8[k], packe(e2, jb+2));
      ins8(d8[k], packe(e3, jb+3));
    }
  }
  // merge the 4 qq-lanes per row: 2 butterfly stages, capacity 12 (per tile)
#pragma unroll
  for (int k = 0; k < NTILE; ++k) {
    float cd[NCAND];
#pragma unroll
    for (int m = 0; m < 8; ++m) cd[m] = d8[k][m];
#pragma unroll
    for (int m = 8; m < NCAND; ++m) cd[m] = BIG;
    {
      float pd[8];
#pragma unroll
      for (int s = 0; s < 8; ++s) pd[s] = __shfl_xor(cd[s], 16);
#pragma unroll
      for (int s = 0; s < 8; ++s) ins12(cd, pd[s]);
    }
    {
      float pd[NCAND];
#pragma unroll
      for (int s = 0; s < NCAND; ++s) pd[s] = __shfl_xor(cd[s], 32);
#pragma unroll
      for (int s = 0; s < NCAND; ++s) ins12(cd, pd[s]);
    }
    if (lane < 16) {
#pragma unroll
      for (int s = 0; s < NCAND; ++s)
        cand[(i0[k] + lane)*NCAND + s] =
          (unsigned short)(__float_as_uint(cd[s]) & 0x1FFu);
    }
  }
}

__global__ __launch_bounds__(NT) void fused_gnn(Params P) {
  extern __shared__ float lds[];
  unsigned short* hbf  = (unsigned short*)lds;
  unsigned short* pbf  = (unsigned short*)&lds[PBF];
  unsigned short* wt   = (unsigned short*)&lds[WTO];
  unsigned short* cand = (unsigned short*)&lds[CANDO];
  unsigned short* nbrs = (unsigned short*)&lds[NBRO];
  const int tid  = threadIdx.x;
  const int g    = blockIdx.x;
  const int rA   = tid;                  // row ownership for tid<512
  const int lane = tid & 63;
  const int w    = tid >> 6;             // wave 0..11
  const int c    = lane & 15;
  const int qq   = lane >> 4;            // 0..3

  const float* xgp = P.x + (size_t)g * NNODE * NF;
  const float4* xg = (const float4*)xgp;

  // ---- stage x[g] as bf16 into hbf (HW cvt_pk) ----
#pragma unroll 1
  for (int i = tid; i < NNODE*NF/4; i += NT) {
    float4 v = xg[i];
    int row = i >> 4, k4 = i & 15;
    *(uint2*)&hbf[row*SBF + 4*k4] = make_uint2(cvtpk(v.x, v.y), cvtpk(v.z, v.w));
  }
  __syncthreads();

  // ---- filter sq from bf16 values (b128 row reads) ----
  if (tid < 512) {
    const uint4* xr = (const uint4*)(hbf + rA*SBF);
    float s = 0.f;
#pragma unroll
    for (int k = 0; k < 8; ++k) {
      uint4 u = xr[k];
      float f;
      f = bflo(u.x); s = fmaf(f, f, s); f = bfhi(u.x); s = fmaf(f, f, s);
      f = bflo(u.y); s = fmaf(f, f, s); f = bfhi(u.y); s = fmaf(f, f, s);
      f = bflo(u.z); s = fmaf(f, f, s); f = bfhi(u.z); s = fmaf(f, f, s);
      f = bflo(u.w); s = fmaf(f, f, s); f = bfhi(u.w); s = fmaf(f, f, s);
    }
    lds[SQO + rA] = s;
  }
  __syncthreads();

  // ==== kNN filter: MFMA Gram, multi-tile per wave ====
  // W1 loads issued BEFORE the filter -> ~500cy L2 latency hides under it.
  float wf[8];
  if (tid < 512) ld8(P.W1, wf, tid);
  // tile cover: w<8 -> {w, w+8, w+16} (0..23); w>=8 -> {w+16, w+20} (24..31)
  if (w < 8) {
    int tts[3] = {w, w + 8, w + 16};
    filter_tiles<3>(hbf, lds, cand, tts, lane, c, qq);
  } else {
    int tts[2] = {w + 16, w + 20};
    filter_tiles<2>(hbf, lds, cand, tts, lane, c, qq);
  }
  if (tid < 512) wt_write(wf, wt, tid);   // wt <- W1 (loads long since landed)
  __syncthreads();   // filter done; SQO reusable; wt=W1 visible

  // ==== exact fp32 refine sq (waves 0-7) ∥ L0 frag pre-read (waves 8-11) ====
  float4 xr16[16];
  v8s LB0[4], LB1[4];
  float lbr[4], lar[4];
  if (tid < 512) {
    const float4* xrow = (const float4*)(xgp + rA*NF);
#pragma unroll
    for (int k4 = 0; k4 < 16; ++k4) xr16[k4] = xrow[k4];
    float s0 = 0.f;
#pragma unroll
    for (int k4 = 0; k4 < 16; ++k4) {
      float4 a = xr16[k4];
      s0 = fmaf(a.x,a.x,s0); s0 = fmaf(a.y,a.y,s0); s0 = fmaf(a.z,a.z,s0); s0 = fmaf(a.w,a.w,s0);
    }
    lds[SQO + rA] = s0;
  } else {
    // waves 8-11: pre-read L0 B-frags (wt=W1, stable across the next barrier)
#pragma unroll
    for (int n = 0; n < 4; ++n) {
      LB0[n] = bfrag(wt, n*16 + c, qq*8);
      LB1[n] = bfrag(wt, n*16 + c, 32 + qq*8);
      lbr[n] = P.b1[n*16 + c];
      lar[n] = P.a1[n*16 + c];
    }
  }
  __syncthreads();   // exact sq published

  // ==== SPLIT: refine (waves 0-7) ∥ L0 dense GEMM (waves 8-11) ====
  // Disjoint: refine reads global x/cand/SQO, writes nbrs; L0 reads hbf/wt(regs),
  // writes hbf in place (disjoint tile rows). wt(W1) reads completed pre-barrier,
  // so the refine tail's wt_write(W2) cannot race.
  if (tid < 512) {
    float nd[6]; int ni[6];
#pragma unroll
    for (int m = 0; m < 6; ++m) { nd[m] = BIG; ni[m] = 0x7fffffff; }
    int cnd[NCAND];
#pragma unroll
    for (int s = 0; s < NCAND; ++s) cnd[s] = cand[rA*NCAND + s];

#pragma unroll 2
    for (int s = 0; s < NCAND; ++s) {
      int j = cnd[s];
      const float4* xj = (const float4*)(xgp + j*NF);
      float4 aa = {0.f, 0.f, 0.f, 0.f};
#pragma unroll
      for (int k4 = 0; k4 < 16; ++k4) {
        float4 v = xj[k4];
        aa.x = fmaf(xr16[k4].x, v.x, aa.x); aa.y = fmaf(xr16[k4].y, v.y, aa.y);
        aa.z = fmaf(xr16[k4].z, v.z, aa.z); aa.w = fmaf(xr16[k4].w, v.w, aa.w);
      }
      float e = fmaf(-2.f, (aa.x+aa.y)+(aa.z+aa.w), lds[SQO + j]);
      if (e < nd[5] || (e == nd[5] && j < ni[5])) {
#pragma unroll
        for (int pp = 0; pp < 6; ++pp) {
          bool lt = (e < nd[pp]) || (e == nd[pp] && j < ni[pp]);
          float tb2 = nd[pp]; int ti = ni[pp];
          nd[pp] = lt ? e : tb2;  ni[pp] = lt ? j : ti;
          e      = lt ? tb2 : e;  j      = lt ? ti : j;
        }
      }
    }
#pragma unroll
    for (int m = 0; m < 6; ++m) nbrs[rA*KNN + m] = (unsigned short)ni[m];
    // pipeline tail: wt <- W2 (L1), preload Wc0 (L2)
    ld8(P.W2, wf, tid);
    wt_write(wf, wt, tid);
    ld8(P.Wc0, wf, tid);
  } else {
    // L0 dense on waves 8-11: 8 tiles each, in-place h = prelu(x@W1+b1)
#pragma unroll 1
    for (int tt = w - 8; tt < 32; tt += 4) {
      const int i0 = tt * 16;
      v8s A0 = bfrag(hbf, i0 + c, qq*8);
      v8s A1 = bfrag(hbf, i0 + c, 32 + qq*8);
#pragma unroll
      for (int n = 0; n < 4; ++n) {
        v4f acc = {0.f, 0.f, 0.f, 0.f};
        acc = __builtin_amdgcn_mfma_f32_16x16x32_bf16(A0, LB0[n], acc, 0, 0, 0);
        acc = __builtin_amdgcn_mfma_f32_16x16x32_bf16(A1, LB1[n], acc, 0, 0, 0);
#pragma unroll
        for (int r = 0; r < 4; ++r) {
          float v = acc[r] + lbr[n];
          v = v >= 0.f ? v : lar[n]*v;
          hbf[(i0 + qq*4 + r)*SBF + n*16 + c] = cvt1(v);
        }
      }
    }
  }
  __syncthreads();   // join: nbrs + h(L0) + wt(W2) all ready

  // ==== layers 1..6: bf16 MFMA GEMMs, 2 barriers/layer, pipelined Wt ====
#pragma unroll 1
  for (int L = 1; L < 7; ++L) {
    const bool isconv = (L >= 2 && L <= 5);
    const float* bl = L==1?P.b2 : L==2?P.bc0 : L==3?P.bc1 :
                      L==4?P.bc2 : L==5?P.bc3 : P.b3;
    const float* al = L==1?P.a2 : P.a3;   // read only at L==1, L==6

    // B fragments + bias from current wt (written before the last barrier)
    v8s B0[4], B1[4];
#pragma unroll
    for (int n = 0; n < 4; ++n) {
      B0[n] = bfrag(wt, n*16 + c, qq*8);
      B1[n] = bfrag(wt, n*16 + c, 32 + qq*8);
    }
    float br[4], ar[4];
    if (!isconv) {
#pragma unroll
      for (int n = 0; n < 4; ++n) { br[n] = bl[n*16 + c]; ar[n] = al[n*16 + c]; }
    }
    __syncthreads();                     // B(L): all frags secured; wt reusable

    if (tid < 512) {
      wt_write(wf, wt, tid);             // wt <- W(L+1) (regs loaded during L-1)
      if (L < 6) {
        const float* Wn2 = L==1?P.Wc1 : L==2?P.Wc2 : L==3?P.Wc3 :
                           L==4?P.W3 : P.W4;   // W(L+2)
        ld8(Wn2, wf, tid);               // latency hides under this layer's MFMA
      }
    }

#pragma unroll 1
    for (int tt = w; tt < 32; tt += NW) {
      const int i0 = tt * 16;
      v8s A0 = bfrag(hbf, i0 + c, qq*8);
      v8s A1 = bfrag(hbf, i0 + c, 32 + qq*8);
#pragma unroll
      for (int n = 0; n < 4; ++n) {
        v4f acc = {0.f, 0.f, 0.f, 0.f};
        acc = __builtin_amdgcn_mfma_f32_16x16x32_bf16(A0, B0[n], acc, 0, 0, 0);
        acc = __builtin_amdgcn_mfma_f32_16x16x32_bf16(A1, B1[n], acc, 0, 0, 0);
        if (isconv) {
#pragma unroll
          for (int r = 0; r < 4; ++r)
            pbf[(i0 + qq*4 + r)*SBF + n*16 + c] = cvt1(acc[r]);
        } else {
#pragma unroll
          for (int r = 0; r < 4; ++r) {
            float v = acc[r] + br[n];
            v = v >= 0.f ? v : ar[n]*v;
            hbf[(i0 + qq*4 + r)*SBF + n*16 + c] = cvt1(v);
          }
        }
      }
    }
    __syncthreads();                     // C(L): p/h stable + wt(L+1) ready

    if (isconv) {
      // wave-cooperative gather: 8 lanes serve one row; bank classes
      // (nbr+s) mod 8 exactly balanced for any nbr values.
      // Per-feat accumulation order: own, +6*b, nbr0..nbr5.
      const int s = tid & 7;                 // b128 chunk (8 feats)
      const float* bls = bl + 8*s;
      float4 bv0 = *(const float4*)(bls);
      float4 bv1 = *(const float4*)(bls + 4);
#pragma unroll 1
      for (int r = tid >> 3; r < NNODE; r += NT/8) {
        // nbr list as 3 x u32 (12B, always 4B-aligned): halves index reads
        const unsigned* nb32 = (const unsigned*)&nbrs[r*KNN];
        unsigned n01 = nb32[0], n23 = nb32[1], n45 = nb32[2];
        uint4 own = *(const uint4*)&hbf[r*SBF + 8*s];
        v2f a0 = up2(own.x), a1 = up2(own.y), a2 = up2(own.z), a3 = up2(own.w);
        v2f t;
        t.x = bv0.x; t.y = bv0.y; a0 += 6.f*t;
        t.x = bv0.z; t.y = bv0.w; a1 += 6.f*t;
        t.x = bv1.x; t.y = bv1.y; a2 += 6.f*t;
        t.x = bv1.z; t.y = bv1.w; a3 += 6.f*t;
        int nbr_[6];
        nbr_[0] = n01 & 0xffff; nbr_[1] = n01 >> 16;
        nbr_[2] = n23 & 0xffff; nbr_[3] = n23 >> 16;
        nbr_[4] = n45 & 0xffff; nbr_[5] = n45 >> 16;
#pragma unroll
        for (int mm = 0; mm < KNN; ++mm) {
          uint4 p = *(const uint4*)&pbf[nbr_[mm]*SBF + 8*s];
          a0 += up2(p.x); a1 += up2(p.y); a2 += up2(p.z); a3 += up2(p.w);
        }
        uint4 o;
        o.x = cvtpk(a0.x, a0.y);
        o.y = cvtpk(a1.x, a1.y);
        o.z = cvtpk(a2.x, a2.y);
        o.w = cvtpk(a3.x, a3.y);
        *(uint4*)&hbf[r*SBF + 8*s] = o;
      }
      // writes guarded by next layer's B(L+1) barrier before any hbf read
    }
  }

  // ==== L7 peeled: MFMA + bias/PReLU + REGISTER pooling ====
  // wt holds W4 (L6's wt_write, guarded by C(6)). No B(7) barrier needed.
  {
    v8s B0[4], B1[4];
#pragma unroll
    for (int n = 0; n < 4; ++n) {
      B0[n] = bfrag(wt, n*16 + c, qq*8);
      B1[n] = bfrag(wt, n*16 + c, 32 + qq*8);
    }
    float br[4], ar[4];
#pragma unroll
    for (int n = 0; n < 4; ++n) { br[n] = P.b4[n*16 + c]; ar[n] = P.a4[n*16 + c]; }

    float ps[4] = {0.f, 0.f, 0.f, 0.f};   // pool partial for col n*16+c
#pragma unroll 1
    for (int tt = w; tt < 32; tt += NW) {
      const int i0 = tt * 16;
      v8s A0 = bfrag(hbf, i0 + c, qq*8);
      v8s A1 = bfrag(hbf, i0 + c, 32 + qq*8);
#pragma unroll
      for (int n = 0; n < 4; ++n) {
        v4f acc = {0.f, 0.f, 0.f, 0.f};
        acc = __builtin_amdgcn_mfma_f32_16x16x32_bf16(A0, B0[n], acc, 0, 0, 0);
        acc = __builtin_amdgcn_mfma_f32_16x16x32_bf16(A1, B1[n], acc, 0, 0, 0);
#pragma unroll
        for (int r = 0; r < 4; ++r) {
          float v = acc[r] + br[n];
          v = v >= 0.f ? v : ar[n]*v;
          ps[n] += v;                    // sum over this tile's 4 qq-rows
        }
      }
    }
    // sum the 4 qq-groups (rows) per column: col index c invariant under ^16/^32
#pragma unroll
    for (int n = 0; n < 4; ++n) {
      ps[n] += __shfl_xor(ps[n], 16);
      ps[n] += __shfl_xor(ps[n], 32);
    }
    if (lane < 16) {
#pragma unroll
      for (int n = 0; n < 4; ++n) lds[POOLP + w*64 + n*16 + c] = ps[n];
    }
  }
  __syncthreads();   // all wave partials published

  if (tid < 64) {
    // 12 partials folded with two independent chains (latency-bound phase)
    float p0 = 0.f, p1 = 0.f;
#pragma unroll
    for (int cc = 0; cc < NW; cc += 2) {
      p0 += lds[POOLP + cc*64 + tid];
      p1 += lds[POOLP + (cc+1)*64 + tid];
    }
    lds[POOLED + tid] = p0 + p1;
  }
  __syncthreads();

  // ---- head MLP (fp32, dual-accumulator chains) ----
  if (tid < 256) {
    float a0 = P.bh1[tid], a1 = 0.f;
#pragma unroll 4
    for (int k = 0; k < 64; k += 2) {
      a0 = fmaf(lds[POOLED+k],   P.Wh1[k*256 + tid],     a0);
      a1 = fmaf(lds[POOLED+k+1], P.Wh1[(k+1)*256 + tid], a1);
    }
    float acc = a0 + a1;
    lds[Y1OFF + tid] = acc >= 0.f ? acc : 0.2f*acc;
  }
  __syncthreads();
  // Wh2 (256x256): split-k x2 over 512 threads, partials in POOLP scratch
  if (tid < 512) {
    int o = tid & 255, hh = tid >> 8;
    float a0 = hh ? 0.f : P.bh2[o], a1 = 0.f;
    const int k0 = hh * 128;
#pragma unroll 4
    for (int k = k0; k < k0 + 128; k += 2) {
      a0 = fmaf(lds[Y1OFF+k],   P.Wh2[k*256 + o],     a0);
      a1 = fmaf(lds[Y1OFF+k+1], P.Wh2[(k+1)*256 + o], a1);
    }
    lds[POOLP + hh*256 + o] = a0 + a1;
  }
  __syncthreads();
  if (tid < 256) {
    float acc = lds[POOLP + tid] + lds[POOLP + 256 + tid];
    lds[Y2OFF + tid] = acc >= 0.f ? acc : 0.2f*acc;
  }
  __syncthreads();
  // Wh3 (256x64): split-k x4 over 256 threads
  if (tid < 256) {
    int o = tid & 63, hh = tid >> 6;
    float a0 = 0.f, a1 = 0.f;
    const int k0 = hh * 64;
#pragma unroll 4
    for (int k = k0; k < k0 + 64; k += 2) {
      a0 = fmaf(lds[Y2OFF+k],   P.Wh3[k*64 + o],     a0);
      a1 = fmaf(lds[Y2OFF+k+1], P.Wh3[(k+1)*64 + o], a1);
    }
    lds[POOLP + hh*64 + o] = a0 + a1;
  }
  __syncthreads();
  // y3 + Wh4 dot: fused in wave 0 (shuffle reduce, no extra barrier)
  if (tid < 64) {
    float acc = P.bh3[tid] + lds[POOLP + tid] + lds[POOLP + 64 + tid]
              + lds[POOLP + 128 + tid] + lds[POOLP + 192 + tid];
    float y3 = acc >= 0.f ? acc : 0.2f*acc;
    float v = y3 * P.Wh4[tid];
#pragma unroll
    for (int off = 32; off >= 1; off >>= 1) v += __shfl_down(v, off);
    if (tid == 0) P.out[g] = v + P.bh4[0];
  }
}

extern "C" void kernel_launch(void* const* d_in, const int* in_sizes, int n_in,
                              void* d_out, int out_size, void* d_ws, size_t ws_size,
                              hipStream_t stream) {
  Params P;
  P.x   = (const float*)d_in[0];
  P.W1  = (const float*)d_in[1];  P.b1  = (const float*)d_in[2];  P.a1 = (const float*)d_in[3];
  P.W2  = (const float*)d_in[4];  P.b2  = (const float*)d_in[5];  P.a2 = (const float*)d_in[6];
  P.Wc0 = (const float*)d_in[7];  P.bc0 = (const float*)d_in[8];
  P.Wc1 = (const float*)d_in[9];  P.bc1 = (const float*)d_in[10];
  P.Wc2 = (const float*)d_in[11]; P.bc2 = (const float*)d_in[12];
  P.Wc3 = (const float*)d_in[13]; P.bc3 = (const float*)d_in[14];
  P.W3  = (const float*)d_in[15]; P.b3  = (const float*)d_in[16]; P.a3 = (const float*)d_in[17];
  P.W4  = (const float*)d_in[18]; P.b4  = (const float*)d_in[19]; P.a4 = (const float*)d_in[20];
  P.Wh1 = (const float*)d_in[21]; P.bh1 = (const float*)d_in[22];
  P.Wh2 = (const float*)d_in[23]; P.bh2 = (const float*)d_in[24];
  P.Wh3 = (const float*)d_in[25]; P.bh3 = (const float*)d_in[26];
  P.Wh4 = (const float*)d_in[27]; P.bh4 = (const float*)d_in[28];
  P.out = (float*)d_out;

  (void)hipFuncSetAttribute(reinterpret_cast<const void*>(fused_gnn),
                            hipFuncAttributeMaxDynamicSharedMemorySize, LDS_BYTES);

  fused_gnn<<<NGRAPH, NT, LDS_BYTES, stream>>>(P);
}